// Round 5
// baseline (5092.936 us; speedup 1.0000x reference)
//
#include <hip/hip_runtime.h>
#include <cmath>
#include <stdint.h>

#define H_DIM 2048
#define I_DIM 4096
#define N_DIM 16
#define R_DIM 128
#define K_CONV 4
#define L_DIM 8192
#define LC 2048                 // chunk length
#define NCHUNK (L_DIM / LC)
#define SEG 32                  // scan segments per chunk
#define TSEG (LC / SEG)         // 64 steps per segment
#define IN_DIM (I_DIM * N_DIM)  // 65536 recurrences

typedef _Float16 f16x8 __attribute__((ext_vector_type(8)));
typedef float    f32x4 __attribute__((ext_vector_type(4)));

// LDS element offset for [row][32] f16 tiles, 16B chunks XOR-swizzled so that
// 16-consecutive-row reads/writes cover banks uniformly.
__device__ __forceinline__ int ldsoff(int row, int chunk) {
    return row * 32 + ((chunk ^ ((row >> 1) & 3)) << 3);
}

// ---------------------------------------------------------------------------
// Split-f16 MFMA GEMM with PRE-SPLIT transposed B:
//   C[M,N] = A[M,K] @ B[K,N],  B given as BTh/BTl f16 [N][K] (hi/lo of fp32).
// A: fp32 [M][K] (APACKED=false, split in registers) or u32 hi|lo packed
//    (APACKED=true, from scan's z-pack).
// Block tile 128x256, BK=32, 4 waves (2m x 2n), wave tile 64x128.
// EPI: 0 none; 1 softplus(x + bias[col]).
// Requires M%128==0, N%256==0, K%32==0.
// ---------------------------------------------------------------------------
template <int EPI, bool APACKED>
__global__ __launch_bounds__(256, 2) void gemm_hl(
    const void* __restrict__ Av, int lda,
    const _Float16* __restrict__ BTh, const _Float16* __restrict__ BTl,
    float* __restrict__ C, int ldc,
    int M, int N, int Kd,
    const float* __restrict__ bias)
{
    __shared__ __align__(16) _Float16 Ah[128 * 32];
    __shared__ __align__(16) _Float16 Al[128 * 32];
    __shared__ __align__(16) _Float16 Bh[256 * 32];
    __shared__ __align__(16) _Float16 Bl[256 * 32];

    const int tid = threadIdx.x;
    const int m0 = blockIdx.x * 128;   // m fastest: co-resident blocks share B
    const int n0 = blockIdx.y * 256;

    const int l = tid & 63, w = tid >> 6;
    const int wm = w & 1, wn = w >> 1;
    const int lr = l & 15, lg = l >> 4;

    // A-stage: 2 lanes/row, 16 elems each
    const int ar = tid >> 1, ah = tid & 1;
    // B-stage: 4 lanes/row, 4 row-groups of 64
    const int br = tid >> 2, bc = tid & 3;

    f32x4 acc[4][8];
#pragma unroll
    for (int a = 0; a < 4; ++a)
#pragma unroll
        for (int b = 0; b < 8; ++b) acc[a][b] = (f32x4){0.f, 0.f, 0.f, 0.f};

    // staging registers
    f16x8 sah[2], sal[2];
    f16x8 sbh[4], sbl[4];

    auto load_regs = [&](int k0) {
        if (!APACKED) {
            const float* Ap = (const float*)Av + (size_t)(m0 + ar) * lda + k0 + ah * 16;
            float x[16];
            *(float4*)&x[0]  = *(const float4*)(Ap + 0);
            *(float4*)&x[4]  = *(const float4*)(Ap + 4);
            *(float4*)&x[8]  = *(const float4*)(Ap + 8);
            *(float4*)&x[12] = *(const float4*)(Ap + 12);
#pragma unroll
            for (int c2 = 0; c2 < 2; ++c2)
#pragma unroll
                for (int j = 0; j < 8; ++j) {
                    const float xv = x[c2 * 8 + j];
                    const _Float16 h = (_Float16)xv;
                    sah[c2][j] = h;
                    sal[c2][j] = (_Float16)(xv - (float)h);
                }
        } else {
            const uint32_t* Ap = (const uint32_t*)Av + (size_t)(m0 + ar) * lda + k0 + ah * 16;
            uint32_t x[16];
            *(uint4*)&x[0]  = *(const uint4*)(Ap + 0);
            *(uint4*)&x[4]  = *(const uint4*)(Ap + 4);
            *(uint4*)&x[8]  = *(const uint4*)(Ap + 8);
            *(uint4*)&x[12] = *(const uint4*)(Ap + 12);
#pragma unroll
            for (int c2 = 0; c2 < 2; ++c2)
#pragma unroll
                for (int j = 0; j < 8; ++j) {
                    const uint32_t wv = x[c2 * 8 + j];
                    sah[c2][j] = __builtin_bit_cast(_Float16, (unsigned short)(wv >> 16));
                    sal[c2][j] = __builtin_bit_cast(_Float16, (unsigned short)(wv & 0xffffu));
                }
        }
#pragma unroll
        for (int g = 0; g < 4; ++g) {
            const size_t off = (size_t)(n0 + g * 64 + br) * Kd + k0 + bc * 8;
            sbh[g] = *(const f16x8*)(BTh + off);
            sbl[g] = *(const f16x8*)(BTl + off);
        }
    };

    load_regs(0);

    for (int k0 = 0; k0 < Kd; k0 += 32) {
        __syncthreads();  // previous iteration's fragment reads complete
#pragma unroll
        for (int c2 = 0; c2 < 2; ++c2) {
            const int off = ldsoff(ar, ah * 2 + c2);
            *(f16x8*)&Ah[off] = sah[c2];
            *(f16x8*)&Al[off] = sal[c2];
        }
#pragma unroll
        for (int g = 0; g < 4; ++g) {
            const int off = ldsoff(g * 64 + br, bc);
            *(f16x8*)&Bh[off] = sbh[g];
            *(f16x8*)&Bl[off] = sbl[g];
        }
        __syncthreads();

        if (k0 + 32 < Kd) load_regs(k0 + 32);  // prefetch overlaps MFMA

        f16x8 fah[4], fal[4];
#pragma unroll
        for (int mt = 0; mt < 4; ++mt) {
            const int off = ldsoff(wm * 64 + mt * 16 + lr, lg);
            fah[mt] = *(const f16x8*)&Ah[off];
            fal[mt] = *(const f16x8*)&Al[off];
        }
#pragma unroll
        for (int half = 0; half < 2; ++half) {
            f16x8 fbh[4], fbl[4];
#pragma unroll
            for (int nt = 0; nt < 4; ++nt) {
                const int off = ldsoff(wn * 128 + (half * 4 + nt) * 16 + lr, lg);
                fbh[nt] = *(const f16x8*)&Bh[off];
                fbl[nt] = *(const f16x8*)&Bl[off];
            }
#pragma unroll
            for (int mt = 0; mt < 4; ++mt)
#pragma unroll
                for (int nt = 0; nt < 4; ++nt) {
                    f32x4& a = acc[mt][half * 4 + nt];
                    a = __builtin_amdgcn_mfma_f32_16x16x32_f16(fah[mt], fbh[nt], a, 0, 0, 0);
                    a = __builtin_amdgcn_mfma_f32_16x16x32_f16(fah[mt], fbl[nt], a, 0, 0, 0);
                    a = __builtin_amdgcn_mfma_f32_16x16x32_f16(fal[mt], fbh[nt], a, 0, 0, 0);
                }
        }
    }

    // epilogue
#pragma unroll
    for (int mt = 0; mt < 4; ++mt) {
        const int row = m0 + wm * 64 + mt * 16 + lg * 4;
#pragma unroll
        for (int nt = 0; nt < 8; ++nt) {
            const int col = n0 + wn * 128 + nt * 16 + lr;
#pragma unroll
            for (int j = 0; j < 4; ++j) {
                float v = acc[mt][nt][j];
                if (EPI == 1) {
                    v += bias[col];
                    v = (v > 20.f) ? v : log1pf(expf(v));
                }
                C[(size_t)(row + j) * ldc + col] = v;
            }
        }
    }
}

// ---------------------------------------------------------------------------
// Weight pack: W [Kd][Nd] fp32 -> Th/Tl [Nd][Kd] f16 (hi/lo). Once per launch.
// ---------------------------------------------------------------------------
__global__ __launch_bounds__(256) void packT_kernel(
    const float* __restrict__ W, _Float16* __restrict__ Th,
    _Float16* __restrict__ Tl, int Kd, int Nd)
{
    __shared__ float t[32][33];
    const int tx = threadIdx.x & 31, ty = threadIdx.x >> 5;
    const int n0 = blockIdx.x * 32, k0 = blockIdx.y * 32;
#pragma unroll
    for (int r = 0; r < 4; ++r)
        t[ty * 4 + r][tx] = W[(size_t)(k0 + ty * 4 + r) * Nd + n0 + tx];
    __syncthreads();
#pragma unroll
    for (int r = 0; r < 4; ++r) {
        const float v = t[tx][ty * 4 + r];
        const _Float16 h = (_Float16)v;
        const size_t o = (size_t)(n0 + ty * 4 + r) * Kd + k0 + tx;
        Th[o] = h;
        Tl[o] = (_Float16)(v - (float)h);
    }
}

// ---------------------------------------------------------------------------
// fp32 tiled GEMM (GEMM2, N=160, split-K atomics).
// ---------------------------------------------------------------------------
template <int EPI, bool ATOMIC>
__global__ __launch_bounds__(256) void gemm_f32(
    const float* __restrict__ A, int lda,
    const float* __restrict__ B, int ldb,
    float* __restrict__ C, int ldc,
    int M, int N, int Kd, int ksplit,
    const float* __restrict__ bias)
{
    constexpr int BM = 128, BN = 128, BK = 16;
    __shared__ __align__(16) float As[BK][BM + 4];
    __shared__ __align__(16) float Bs[BK][BN + 4];

    const int m0 = blockIdx.y * BM;
    const int n0 = blockIdx.x * BN;
    const int tid = threadIdx.x;
    const int ty = tid >> 4;
    const int tx = tid & 15;

    const int arow0 = tid >> 2;
    const int ac4   = (tid & 3) * 4;
    const int brow0 = tid >> 5;
    const int bc4   = (tid & 31) * 4;

    float acc[8][8];
#pragma unroll
    for (int mm = 0; mm < 8; ++mm)
#pragma unroll
        for (int nn = 0; nn < 8; ++nn) acc[mm][nn] = 0.f;

    const float4 z4 = {0.f, 0.f, 0.f, 0.f};

    const int kbeg = blockIdx.z * ksplit;
    const int kend = (kbeg + ksplit < Kd) ? (kbeg + ksplit) : Kd;

    for (int k0 = kbeg; k0 < kend; k0 += BK) {
        float4 a0 = *(const float4*)(A + (size_t)(m0 + arow0) * lda + k0 + ac4);
        float4 a1 = *(const float4*)(A + (size_t)(m0 + arow0 + 64) * lda + k0 + ac4);
        const int bcol = n0 + bc4;
        const bool bok = (bcol < N);
        float4 b0 = bok ? *(const float4*)(B + (size_t)(k0 + brow0) * ldb + bcol) : z4;
        float4 b1 = bok ? *(const float4*)(B + (size_t)(k0 + brow0 + 8) * ldb + bcol) : z4;

        __syncthreads();
        As[ac4 + 0][arow0] = a0.x;
        As[ac4 + 1][arow0] = a0.y;
        As[ac4 + 2][arow0] = a0.z;
        As[ac4 + 3][arow0] = a0.w;
        As[ac4 + 0][arow0 + 64] = a1.x;
        As[ac4 + 1][arow0 + 64] = a1.y;
        As[ac4 + 2][arow0 + 64] = a1.z;
        As[ac4 + 3][arow0 + 64] = a1.w;
        *(float4*)&Bs[brow0][bc4] = b0;
        *(float4*)&Bs[brow0 + 8][bc4] = b1;
        __syncthreads();

#pragma unroll
        for (int kk = 0; kk < BK; ++kk) {
            float4 av0 = *(const float4*)&As[kk][ty * 8];
            float4 av1 = *(const float4*)&As[kk][ty * 8 + 4];
            float4 bv0 = *(const float4*)&Bs[kk][tx * 8];
            float4 bv1 = *(const float4*)&Bs[kk][tx * 8 + 4];
            float a[8] = {av0.x, av0.y, av0.z, av0.w, av1.x, av1.y, av1.z, av1.w};
            float b[8] = {bv0.x, bv0.y, bv0.z, bv0.w, bv1.x, bv1.y, bv1.z, bv1.w};
#pragma unroll
            for (int mm = 0; mm < 8; ++mm)
#pragma unroll
                for (int nn = 0; nn < 8; ++nn)
                    acc[mm][nn] = fmaf(a[mm], b[nn], acc[mm][nn]);
        }
    }

#pragma unroll
    for (int mm = 0; mm < 8; ++mm) {
        const int row = m0 + ty * 8 + mm;
        float* Crow = C + (size_t)row * ldc + n0 + tx * 8;
#pragma unroll
        for (int nn = 0; nn < 8; ++nn) {
            const int col = n0 + tx * 8 + nn;
            if (col < N) {
                float v = acc[mm][nn];
                if (EPI == 1) {
                    v += bias[col];
                    v = (v > 20.f) ? v : log1pf(expf(v));
                }
                if (ATOMIC) atomicAdd(&Crow[nn], v);
                else        Crow[nn] = v;
            }
        }
    }
}

__global__ __launch_bounds__(256) void zero_kernel(float* __restrict__ p, int n)
{
    const int idx = blockIdx.x * 256 + threadIdx.x;
    if (idx < n) p[idx] = 0.f;
}

__global__ __launch_bounds__(256) void save_tail_kernel(
    const float* __restrict__ proj, float* __restrict__ xtail)
{
    const int idx = blockIdx.x * 256 + threadIdx.x;
    if (idx >= 3 * I_DIM) return;
    const int r = idx >> 12;
    const int i = idx & (I_DIM - 1);
    xtail[idx] = proj[(size_t)(LC - 3 + r) * (2 * I_DIM) + i];
}

__global__ __launch_bounds__(256) void conv_silu_kernel(
    const float* __restrict__ proj,
    const float* __restrict__ xtail,
    const float* __restrict__ w,
    const float* __restrict__ b,
    float* __restrict__ xconv,
    int first)
{
    const int total = LC * I_DIM;
    const int stride = gridDim.x * blockDim.x;
    for (int idx = blockIdx.x * blockDim.x + threadIdx.x; idx < total; idx += stride) {
        const int t = idx >> 12;
        const int i = idx & (I_DIM - 1);
        float s = b[i];
#pragma unroll
        for (int k = 0; k < 4; ++k) {
            const int tt = t - 3 + k;
            float xv;
            if (tt >= 0)          xv = proj[(size_t)tt * (2 * I_DIM) + i];
            else if (!first)      xv = xtail[(size_t)(tt + 3) * I_DIM + i];
            else                  xv = 0.f;
            s = fmaf(w[i * 4 + k], xv, s);
        }
        xconv[idx] = s / (1.f + expf(-s));
    }
}

__global__ __launch_bounds__(256) void scan_part1(
    const float* __restrict__ delta,
    const float* __restrict__ ssm,
    const float* __restrict__ xc,
    const float* __restrict__ A_log,
    float* __restrict__ aprod,
    float* __restrict__ hend)
{
    const int tid = threadIdx.x;
    const int n = tid & 15;
    const int il = tid >> 4;
    const int i = blockIdx.x * 16 + il;
    const int seg = blockIdx.y;

    const float Ai = -expf(A_log[(size_t)i * N_DIM + n]);
    float h = 0.f, ap = 1.f;
    const int t0 = seg * TSEG;
#pragma unroll 4
    for (int t = t0; t < t0 + TSEG; ++t) {
        const float d  = delta[(size_t)t * (2 * I_DIM) + i];
        const float u  = xc[(size_t)t * I_DIM + i];
        const float Bt = ssm[t * 160 + 128 + n];
        const float a  = expf(d * Ai);
        h = fmaf(h, a, (d * u) * Bt);
        ap *= a;
    }
    const int idx = seg * IN_DIM + i * N_DIM + n;
    aprod[idx] = ap;
    hend[idx]  = h;
}

__global__ __launch_bounds__(256) void scan_part2(
    const float* __restrict__ aprod,
    float* __restrict__ hend,
    float* __restrict__ hstate,
    int first)
{
    const int gid = blockIdx.x * 256 + threadIdx.x;
    float h = first ? 0.f : hstate[gid];
    for (int s = 0; s < SEG; ++s) {
        const int idx = s * IN_DIM + gid;
        const float ap = aprod[idx];
        const float he = hend[idx];
        hend[idx] = h;
        h = fmaf(ap, h, he);
    }
    hstate[gid] = h;
}

// Phase 3: re-run segment from exact h_start; write z PACKED (hi<<16|lo f16)
// into proj's delta slot (read-before-write within the same wave iteration).
__global__ __launch_bounds__(256) void scan_part3(
    const float* __restrict__ delta,   // proj x-half, ld 2I
    const float* __restrict__ gate,    // proj gate-half, ld 2I
    const float* __restrict__ ssm,
    const float* __restrict__ xc,      // u
    uint32_t* __restrict__ zout,       // proj x-half as u32, ld 2I
    const float* __restrict__ A_log,
    const float* __restrict__ Dp,
    const float* __restrict__ hstart)
{
    const int tid = threadIdx.x;
    const int n = tid & 15;
    const int il = tid >> 4;
    const int i = blockIdx.x * 16 + il;
    const int seg = blockIdx.y;

    const float Ai = -expf(A_log[(size_t)i * N_DIM + n]);
    const float Di = Dp[i];
    float h = hstart[seg * IN_DIM + i * N_DIM + n];
    const int t0 = seg * TSEG;
    for (int t = t0; t < t0 + TSEG; ++t) {
        const float d  = delta[(size_t)t * (2 * I_DIM) + i];
        const float u  = xc[(size_t)t * I_DIM + i];
        const float Bt = ssm[t * 160 + 128 + n];
        const float Ct = ssm[t * 160 + 144 + n];
        const float a  = expf(d * Ai);
        h = fmaf(h, a, (d * u) * Bt);
        float p = h * Ct;
        p += __shfl_xor(p, 1);
        p += __shfl_xor(p, 2);
        p += __shfl_xor(p, 4);
        p += __shfl_xor(p, 8);
        if (n == 0) {
            const float g  = gate[(size_t)t * (2 * I_DIM) + i];
            const float sg = g / (1.f + expf(-g));
            const float zv = (p + u * Di) * sg;
            const _Float16 zh = (_Float16)zv;
            const _Float16 zl = (_Float16)(zv - (float)zh);
            const uint32_t pz =
                ((uint32_t)__builtin_bit_cast(unsigned short, zh) << 16) |
                (uint32_t)__builtin_bit_cast(unsigned short, zl);
            zout[(size_t)t * (2 * I_DIM) + i] = pz;
        }
    }
}

// ---------------------------------------------------------------------------
extern "C" void kernel_launch(void* const* d_in, const int* in_sizes, int n_in,
                              void* d_out, int out_size, void* d_ws, size_t ws_size,
                              hipStream_t stream)
{
    const float* hs      = (const float*)d_in[0];
    const float* W_in    = (const float*)d_in[1];
    const float* conv_w  = (const float*)d_in[2];
    const float* conv_b  = (const float*)d_in[3];
    const float* W_x     = (const float*)d_in[4];
    const float* W_dt    = (const float*)d_in[5];
    const float* dt_bias = (const float*)d_in[6];
    const float* A_log   = (const float*)d_in[7];
    const float* Dp      = (const float*)d_in[8];
    const float* W_out   = (const float*)d_in[9];
    float* out = (float*)d_out;

    // workspace layout
    char* p = (char*)d_ws;
    auto alloc = [&](size_t bytes) {
        char* r = p;
        p += (bytes + 255) & ~(size_t)255;
        return r;
    };
    float* proj   = (float*)alloc((size_t)LC * 2 * I_DIM * 4);
    float* xconv  = (float*)alloc((size_t)LC * I_DIM * 4);
    float* ssm    = (float*)alloc((size_t)LC * 160 * 4);
    float* xtail  = (float*)alloc((size_t)3 * I_DIM * 4);
    float* hstate = (float*)alloc((size_t)IN_DIM * 4);
    _Float16* WinTh  = (_Float16*)alloc((size_t)2 * I_DIM * H_DIM * 2);
    _Float16* WinTl  = (_Float16*)alloc((size_t)2 * I_DIM * H_DIM * 2);
    _Float16* WoutTh = (_Float16*)alloc((size_t)H_DIM * I_DIM * 2);
    _Float16* WoutTl = (_Float16*)alloc((size_t)H_DIM * I_DIM * 2);
    _Float16* WdtTh  = (_Float16*)alloc((size_t)I_DIM * R_DIM * 2);
    _Float16* WdtTl  = (_Float16*)alloc((size_t)I_DIM * R_DIM * 2);

    const dim3 blk(256);
    const int NSSM = R_DIM + 2 * N_DIM;  // 160

    // ---- pack weights (once per launch) ----
    packT_kernel<<<dim3(2 * I_DIM / 32, H_DIM / 32), blk, 0, stream>>>(
        W_in, WinTh, WinTl, H_DIM, 2 * I_DIM);
    packT_kernel<<<dim3(H_DIM / 32, I_DIM / 32), blk, 0, stream>>>(
        W_out, WoutTh, WoutTl, I_DIM, H_DIM);
    packT_kernel<<<dim3(I_DIM / 32, R_DIM / 32), blk, 0, stream>>>(
        W_dt, WdtTh, WdtTl, R_DIM, I_DIM);

    for (int c = 0; c < NCHUNK; ++c) {
        const int t0 = c * LC;
        const int first = (c == 0) ? 1 : 0;
        const float* hs_c = hs + (size_t)t0 * H_DIM;
        float* out_c = out + (size_t)t0 * H_DIM;
        float* aprod = out_c;                 // scan scratch in out region
        float* hend  = out_c + (size_t)SEG * IN_DIM;

        // 1) proj = hs_c @ W_in
        gemm_hl<0, false><<<dim3(LC / 128, 2 * I_DIM / 256), blk, 0, stream>>>(
            hs_c, H_DIM, WinTh, WinTl, proj, 2 * I_DIM,
            LC, 2 * I_DIM, H_DIM, nullptr);

        // 2) xconv = silu(dwconv(x_pre) + b)
        conv_silu_kernel<<<dim3(4096), blk, 0, stream>>>(
            proj, xtail, conv_w, conv_b, xconv, first);

        // 3) save conv tail for next chunk
        save_tail_kernel<<<dim3((3 * I_DIM + 255) / 256), blk, 0, stream>>>(proj, xtail);

        // 4) ssm = xconv @ W_x  (fp32 split-K x8)
        zero_kernel<<<dim3((LC * NSSM + 255) / 256), blk, 0, stream>>>(ssm, LC * NSSM);
        gemm_f32<0, true><<<dim3(2, LC / 128, 8), blk, 0, stream>>>(
            xconv, I_DIM, W_x, NSSM, ssm, NSSM, LC, NSSM,
            I_DIM, I_DIM / 8, nullptr);

        // 5) delta = softplus(ssm[:, :R] @ W_dt + dt_bias) -> proj[:, :I]
        gemm_hl<1, false><<<dim3(LC / 128, I_DIM / 256), blk, 0, stream>>>(
            ssm, NSSM, WdtTh, WdtTl, proj, 2 * I_DIM,
            LC, I_DIM, R_DIM, dt_bias);

        // 6) segment-parallel scan; z packed into proj's delta slot
        scan_part1<<<dim3(I_DIM / 16, SEG), blk, 0, stream>>>(
            proj, ssm, xconv, A_log, aprod, hend);
        scan_part2<<<dim3(IN_DIM / 256), blk, 0, stream>>>(
            aprod, hend, hstate, first);
        scan_part3<<<dim3(I_DIM / 16, SEG), blk, 0, stream>>>(
            proj, proj + I_DIM, ssm, xconv, (uint32_t*)proj, A_log, Dp, hend);

        // 7) out_c = z @ W_out  (A = packed z in proj)
        gemm_hl<0, true><<<dim3(LC / 128, H_DIM / 256), blk, 0, stream>>>(
            proj, 2 * I_DIM, WoutTh, WoutTl, out_c, H_DIM,
            LC, H_DIM, I_DIM, nullptr);
    }
}

// Round 6
// 3478.777 us; speedup vs baseline: 1.4640x; 1.4640x over previous
//
#include <hip/hip_runtime.h>
#include <cmath>
#include <stdint.h>

#define H_DIM 2048
#define I_DIM 4096
#define N_DIM 16
#define R_DIM 128
#define K_CONV 4
#define L_DIM 8192
#define LC 2048                 // chunk length
#define NCHUNK (L_DIM / LC)
#define SEG 32                  // scan segments per chunk
#define TSEG (LC / SEG)         // 64 steps per segment
#define IN_DIM (I_DIM * N_DIM)  // 65536 recurrences

typedef _Float16 f16x8 __attribute__((ext_vector_type(8)));
typedef float    f32x4 __attribute__((ext_vector_type(4)));

// direct HBM->LDS, 16B per lane; LDS base must be wave-uniform (HW adds lane*16)
__device__ __forceinline__ void gl_lds(const _Float16* g, _Float16* lbase, int lane) {
#if __has_builtin(__builtin_amdgcn_global_load_lds)
    __builtin_amdgcn_global_load_lds(
        (const __attribute__((address_space(1))) void*)g,
        (__attribute__((address_space(3))) void*)lbase, 16, 0, 0);
#else
    *(f16x8*)&lbase[lane * 8] = *(const f16x8*)g;
#endif
}

// ---------------------------------------------------------------------------
// Panel-format split-f16 MFMA GEMM.
//   C[M,N] (+)= A[M,K] @ B[K,N]
// B pre-split+packed: panels [N/16][K/32][512] f16 (slot (c*16+r)*8+j holds
// B[kp*32+c*8+j][np*16+r]); staged via global_load_lds, lane-ordered ->
// conflict-free ds_read_b128 at lane*16.
// A: AK=0 fp32 [M][K] (split in regs) | AK=1 u32 rows packed (hi16|lo16).
// Block 128x128, BK=32, 4 waves (2x2), wave tile 64x64; 3 MFMA per hi/lo pair.
// EPI: 0 none; 1 softplus(x+bias[col]). Ncap>0 guards stores to col<Ncap.
// Split-K via blockIdx.y * kchunk (ATOMIC accumulate; zero C first).
// ---------------------------------------------------------------------------
template <int EPI, int AK, bool ATOMIC>
__global__ __launch_bounds__(256, 2) void gemm_p(
    const void* __restrict__ Av, int lda,
    const _Float16* __restrict__ Bph, const _Float16* __restrict__ Bpl,
    float* __restrict__ C, int ldc,
    int Kd, int Ncap, int gm, int kchunk,
    const float* __restrict__ bias)
{
    __shared__ __align__(16) _Float16 Ah[4096];
    __shared__ __align__(16) _Float16 Al[4096];
    __shared__ __align__(16) _Float16 Bh[4096];
    __shared__ __align__(16) _Float16 Bl[4096];

    const int tid = threadIdx.x;
    // bijective XCD swizzle (gridDim.x % 8 == 0), m-fastest within chunk
    int bid = blockIdx.x;
    const int q = gridDim.x >> 3;
    bid = (bid & 7) * q + (bid >> 3);
    const int m0 = (bid % gm) * 128;
    const int n0 = (bid / gm) * 128;

    const int kbeg = blockIdx.y * kchunk;
    const int kend = (kbeg + kchunk < Kd) ? (kbeg + kchunk) : Kd;

    const int w = tid >> 6, l = tid & 63;
    const int wm = w & 1, wn = w >> 1;
    const int lr = l & 15, lg = l >> 4;

    // A staging coords: thread -> row ar, k-half ah (16 fp32)
    const int ar = tid >> 1, ah = tid & 1;
    const int aw0 = (ar >> 4) * 512 + (((ah * 2 + 0) * 16 + (ar & 15)) * 8);
    const int aw1 = (ar >> 4) * 512 + (((ah * 2 + 1) * 16 + (ar & 15)) * 8);

    const int KP = Kd >> 5;          // B k-panel count
    const int np0 = n0 >> 4;

    f32x4 acc[4][4];
#pragma unroll
    for (int a = 0; a < 4; ++a)
#pragma unroll
        for (int b = 0; b < 4; ++b) acc[a][b] = (f32x4){0.f, 0.f, 0.f, 0.f};

    f16x8 sah[2], sal[2];

    auto loadA = [&](int k0) {
        if (AK == 0) {
            const float* Ap = (const float*)Av + (size_t)(m0 + ar) * lda + k0 + ah * 16;
            float x[16];
            *(float4*)&x[0]  = *(const float4*)(Ap + 0);
            *(float4*)&x[4]  = *(const float4*)(Ap + 4);
            *(float4*)&x[8]  = *(const float4*)(Ap + 8);
            *(float4*)&x[12] = *(const float4*)(Ap + 12);
#pragma unroll
            for (int c2 = 0; c2 < 2; ++c2)
#pragma unroll
                for (int j = 0; j < 8; ++j) {
                    const float xv = x[c2 * 8 + j];
                    const _Float16 h = (_Float16)xv;
                    sah[c2][j] = h;
                    sal[c2][j] = (_Float16)(xv - (float)h);
                }
        } else {
            const uint32_t* Ap = (const uint32_t*)Av + (size_t)(m0 + ar) * lda + k0 + ah * 16;
            uint32_t x[16];
            *(uint4*)&x[0]  = *(const uint4*)(Ap + 0);
            *(uint4*)&x[4]  = *(const uint4*)(Ap + 4);
            *(uint4*)&x[8]  = *(const uint4*)(Ap + 8);
            *(uint4*)&x[12] = *(const uint4*)(Ap + 12);
#pragma unroll
            for (int c2 = 0; c2 < 2; ++c2)
#pragma unroll
                for (int j = 0; j < 8; ++j) {
                    const uint32_t wv = x[c2 * 8 + j];
                    sah[c2][j] = __builtin_bit_cast(_Float16, (unsigned short)(wv >> 16));
                    sal[c2][j] = __builtin_bit_cast(_Float16, (unsigned short)(wv & 0xffffu));
                }
        }
    };

    loadA(kbeg);

    for (int k0 = kbeg; k0 < kend; k0 += 32) {
        __syncthreads();  // previous iteration's fragment reads complete
        *(f16x8*)&Ah[aw0] = sah[0];
        *(f16x8*)&Ah[aw1] = sah[1];
        *(f16x8*)&Al[aw0] = sal[0];
        *(f16x8*)&Al[aw1] = sal[1];
        {
            const int kp = k0 >> 5;
#pragma unroll
            for (int qq = 0; qq < 2; ++qq) {
                const int st = 2 * w + qq;
                const size_t goff = ((size_t)(np0 + st) * KP + kp) * 512 + (size_t)l * 8;
                gl_lds(Bph + goff, &Bh[st * 512], l);
                gl_lds(Bpl + goff, &Bl[st * 512], l);
            }
        }
        __syncthreads();  // drains lgkm (A writes) + vmcnt (B gload_lds)

        if (k0 + 32 < kend) loadA(k0 + 32);  // prefetch overlaps MFMA

        f16x8 fah[4], fal[4], fbh[4], fbl[4];
#pragma unroll
        for (int t = 0; t < 4; ++t) {
            fah[t] = *(const f16x8*)&Ah[(wm * 4 + t) * 512 + l * 8];
            fal[t] = *(const f16x8*)&Al[(wm * 4 + t) * 512 + l * 8];
            fbh[t] = *(const f16x8*)&Bh[(wn * 4 + t) * 512 + l * 8];
            fbl[t] = *(const f16x8*)&Bl[(wn * 4 + t) * 512 + l * 8];
        }
#pragma unroll
        for (int mt = 0; mt < 4; ++mt)
#pragma unroll
            for (int nt = 0; nt < 4; ++nt) {
                f32x4& a = acc[mt][nt];
                a = __builtin_amdgcn_mfma_f32_16x16x32_f16(fah[mt], fbh[nt], a, 0, 0, 0);
                a = __builtin_amdgcn_mfma_f32_16x16x32_f16(fah[mt], fbl[nt], a, 0, 0, 0);
                a = __builtin_amdgcn_mfma_f32_16x16x32_f16(fal[mt], fbh[nt], a, 0, 0, 0);
            }
    }

    // epilogue
#pragma unroll
    for (int mt = 0; mt < 4; ++mt) {
        const int row = m0 + wm * 64 + mt * 16 + lg * 4;
#pragma unroll
        for (int nt = 0; nt < 4; ++nt) {
            const int col = n0 + wn * 64 + nt * 16 + lr;
            if (Ncap == 0 || col < Ncap) {
#pragma unroll
                for (int j = 0; j < 4; ++j) {
                    float v = acc[mt][nt][j];
                    if (EPI == 1) {
                        v += bias[col];
                        v = (v > 20.f) ? v : log1pf(expf(v));
                    }
                    if (ATOMIC) atomicAdd(&C[(size_t)(row + j) * ldc + col], v);
                    else        C[(size_t)(row + j) * ldc + col] = v;
                }
            }
        }
    }
}

// ---------------------------------------------------------------------------
// Pack W [Kd][Nd] fp32 -> hi/lo f16 panels [Nd/16][Kd/32][512].
// slot (c*16+r)*8+j of panel (np,kp) = W[kp*32+c*8+j][np*16+r]. 128 threads.
// ---------------------------------------------------------------------------
__global__ __launch_bounds__(128) void pack_bp(
    const float* __restrict__ W, _Float16* __restrict__ Ph,
    _Float16* __restrict__ Pl, int Kd, int Nd)
{
    __shared__ float t[32][33];
    const int tid = threadIdx.x;
    const int n0 = blockIdx.x * 32, k0 = blockIdx.y * 32;
#pragma unroll
    for (int h = 0; h < 2; ++h) {
        const int qd = tid + h * 128;
        const int kk = qd >> 3, qq = qd & 7;
        *(float4*)&t[kk][qq * 4] = *(const float4*)(W + (size_t)(k0 + kk) * Nd + n0 + qq * 4);
    }
    __syncthreads();
    const int c = tid >> 5, nn = tid & 31;
    const int np = (n0 + nn) >> 4;
    const int r  = nn & 15;
    const int kp = k0 >> 5;
    const size_t base = ((size_t)np * (Kd >> 5) + kp) * 512 + (c * 16 + r) * 8;
    f16x8 vh, vl;
#pragma unroll
    for (int j = 0; j < 8; ++j) {
        const float v = t[c * 8 + j][nn];
        const _Float16 h = (_Float16)v;
        vh[j] = h;
        vl[j] = (_Float16)(v - (float)h);
    }
    *(f16x8*)&Ph[base] = vh;
    *(f16x8*)&Pl[base] = vl;
}

__global__ __launch_bounds__(256) void zero_kernel(float* __restrict__ p, int n)
{
    const int idx = blockIdx.x * 256 + threadIdx.x;
    if (idx < n) p[idx] = 0.f;
}

__global__ __launch_bounds__(256) void save_tail_kernel(
    const float* __restrict__ proj, float* __restrict__ xtail)
{
    const int idx = blockIdx.x * 256 + threadIdx.x;
    if (idx >= 3 * I_DIM) return;
    const int r = idx >> 12;
    const int i = idx & (I_DIM - 1);
    xtail[idx] = proj[(size_t)(LC - 3 + r) * (2 * I_DIM) + i];
}

__global__ __launch_bounds__(256) void conv_silu_kernel(
    const float* __restrict__ proj,
    const float* __restrict__ xtail,
    const float* __restrict__ w,
    const float* __restrict__ b,
    float* __restrict__ xconv,
    int first)
{
    const int total = LC * I_DIM;
    const int stride = gridDim.x * blockDim.x;
    for (int idx = blockIdx.x * blockDim.x + threadIdx.x; idx < total; idx += stride) {
        const int t = idx >> 12;
        const int i = idx & (I_DIM - 1);
        float s = b[i];
#pragma unroll
        for (int k = 0; k < 4; ++k) {
            const int tt = t - 3 + k;
            float xv;
            if (tt >= 0)          xv = proj[(size_t)tt * (2 * I_DIM) + i];
            else if (!first)      xv = xtail[(size_t)(tt + 3) * I_DIM + i];
            else                  xv = 0.f;
            s = fmaf(w[i * 4 + k], xv, s);
        }
        xconv[idx] = s / (1.f + expf(-s));
    }
}

__global__ __launch_bounds__(256) void scan_part1(
    const float* __restrict__ delta,
    const float* __restrict__ ssm,
    const float* __restrict__ xc,
    const float* __restrict__ A_log,
    float* __restrict__ aprod,
    float* __restrict__ hend)
{
    const int tid = threadIdx.x;
    const int n = tid & 15;
    const int il = tid >> 4;
    const int i = blockIdx.x * 16 + il;
    const int seg = blockIdx.y;

    const float Ai = -expf(A_log[(size_t)i * N_DIM + n]);
    float h = 0.f, ap = 1.f;
    const int t0 = seg * TSEG;
#pragma unroll 4
    for (int t = t0; t < t0 + TSEG; ++t) {
        const float d  = delta[(size_t)t * (2 * I_DIM) + i];
        const float u  = xc[(size_t)t * I_DIM + i];
        const float Bt = ssm[t * 160 + 128 + n];
        const float a  = expf(d * Ai);
        h = fmaf(h, a, (d * u) * Bt);
        ap *= a;
    }
    const int idx = seg * IN_DIM + i * N_DIM + n;
    aprod[idx] = ap;
    hend[idx]  = h;
}

__global__ __launch_bounds__(256) void scan_part2(
    const float* __restrict__ aprod,
    float* __restrict__ hend,
    float* __restrict__ hstate,
    int first)
{
    const int gid = blockIdx.x * 256 + threadIdx.x;
    float h = first ? 0.f : hstate[gid];
    for (int s = 0; s < SEG; ++s) {
        const int idx = s * IN_DIM + gid;
        const float ap = aprod[idx];
        const float he = hend[idx];
        hend[idx] = h;
        h = fmaf(ap, h, he);
    }
    hstate[gid] = h;
}

// Phase 3: re-run segment from exact h_start; write z PACKED (hi16|lo16 f16)
// into proj's delta slot (read-before-write within the same thread iteration).
__global__ __launch_bounds__(256) void scan_part3(
    const float* __restrict__ delta,
    const float* __restrict__ gate,
    const float* __restrict__ ssm,
    const float* __restrict__ xc,
    uint32_t* __restrict__ zout,
    const float* __restrict__ A_log,
    const float* __restrict__ Dp,
    const float* __restrict__ hstart)
{
    const int tid = threadIdx.x;
    const int n = tid & 15;
    const int il = tid >> 4;
    const int i = blockIdx.x * 16 + il;
    const int seg = blockIdx.y;

    const float Ai = -expf(A_log[(size_t)i * N_DIM + n]);
    const float Di = Dp[i];
    float h = hstart[seg * IN_DIM + i * N_DIM + n];
    const int t0 = seg * TSEG;
    for (int t = t0; t < t0 + TSEG; ++t) {
        const float d  = delta[(size_t)t * (2 * I_DIM) + i];
        const float u  = xc[(size_t)t * I_DIM + i];
        const float Bt = ssm[t * 160 + 128 + n];
        const float Ct = ssm[t * 160 + 144 + n];
        const float a  = expf(d * Ai);
        h = fmaf(h, a, (d * u) * Bt);
        float p = h * Ct;
        p += __shfl_xor(p, 1);
        p += __shfl_xor(p, 2);
        p += __shfl_xor(p, 4);
        p += __shfl_xor(p, 8);
        if (n == 0) {
            const float g  = gate[(size_t)t * (2 * I_DIM) + i];
            const float sg = g / (1.f + expf(-g));
            const float zv = (p + u * Di) * sg;
            const _Float16 zh = (_Float16)zv;
            const _Float16 zl = (_Float16)(zv - (float)zh);
            const uint32_t pz =
                ((uint32_t)__builtin_bit_cast(unsigned short, zh) << 16) |
                (uint32_t)__builtin_bit_cast(unsigned short, zl);
            zout[(size_t)t * (2 * I_DIM) + i] = pz;
        }
    }
}

// ---------------------------------------------------------------------------
extern "C" void kernel_launch(void* const* d_in, const int* in_sizes, int n_in,
                              void* d_out, int out_size, void* d_ws, size_t ws_size,
                              hipStream_t stream)
{
    const float* hs      = (const float*)d_in[0];
    const float* W_in    = (const float*)d_in[1];
    const float* conv_w  = (const float*)d_in[2];
    const float* conv_b  = (const float*)d_in[3];
    const float* W_x     = (const float*)d_in[4];
    const float* W_dt    = (const float*)d_in[5];
    const float* dt_bias = (const float*)d_in[6];
    const float* A_log   = (const float*)d_in[7];
    const float* Dp      = (const float*)d_in[8];
    const float* W_out   = (const float*)d_in[9];
    float* out = (float*)d_out;

    // workspace layout (~200 MB)
    char* p = (char*)d_ws;
    auto alloc = [&](size_t bytes) {
        char* r = p;
        p += (bytes + 255) & ~(size_t)255;
        return r;
    };
    float* proj   = (float*)alloc((size_t)LC * 2 * I_DIM * 4);   // 64 MB
    float* xconv  = (float*)alloc((size_t)LC * I_DIM * 4);       // 32 MB
    float* ssm    = (float*)alloc((size_t)LC * 160 * 4);
    float* xtail  = (float*)alloc((size_t)3 * I_DIM * 4);
    float* hstate = (float*)alloc((size_t)IN_DIM * 4);
    _Float16* WinPh  = (_Float16*)alloc((size_t)2 * I_DIM * H_DIM * 2);  // 32 MB
    _Float16* WinPl  = (_Float16*)alloc((size_t)2 * I_DIM * H_DIM * 2);
    _Float16* WoutPh = (_Float16*)alloc((size_t)H_DIM * I_DIM * 2);      // 16 MB
    _Float16* WoutPl = (_Float16*)alloc((size_t)H_DIM * I_DIM * 2);
    _Float16* WdtPh  = (_Float16*)alloc((size_t)I_DIM * R_DIM * 2);
    _Float16* WdtPl  = (_Float16*)alloc((size_t)I_DIM * R_DIM * 2);
    _Float16* WxPh   = (_Float16*)alloc((size_t)256 * I_DIM * 2);  // padded to 16 panels
    _Float16* WxPl   = (_Float16*)alloc((size_t)256 * I_DIM * 2);

    const dim3 blk(256);
    const int NSSM = R_DIM + 2 * N_DIM;  // 160

    // ---- pack weights into panel format (once per launch) ----
    pack_bp<<<dim3(2 * I_DIM / 32, H_DIM / 32), dim3(128), 0, stream>>>(
        W_in, WinPh, WinPl, H_DIM, 2 * I_DIM);
    pack_bp<<<dim3(H_DIM / 32, I_DIM / 32), dim3(128), 0, stream>>>(
        W_out, WoutPh, WoutPl, I_DIM, H_DIM);
    pack_bp<<<dim3(I_DIM / 32, R_DIM / 32), dim3(128), 0, stream>>>(
        W_dt, WdtPh, WdtPl, R_DIM, I_DIM);
    pack_bp<<<dim3(NSSM / 32, I_DIM / 32), dim3(128), 0, stream>>>(
        W_x, WxPh, WxPl, I_DIM, NSSM);

    for (int c = 0; c < NCHUNK; ++c) {
        const int t0 = c * LC;
        const int first = (c == 0) ? 1 : 0;
        const float* hs_c = hs + (size_t)t0 * H_DIM;
        float* out_c = out + (size_t)t0 * H_DIM;
        float* aprod = out_c;                 // scan scratch in out region
        float* hend  = out_c + (size_t)SEG * IN_DIM;

        // 1) proj = hs_c @ W_in   (M=2048, N=8192, K=2048) -> 1024 blocks
        gemm_p<0, 0, false><<<dim3(1024, 1), blk, 0, stream>>>(
            hs_c, H_DIM, WinPh, WinPl, proj, 2 * I_DIM,
            H_DIM, 0, LC / 128, H_DIM, nullptr);

        // 2) xconv = silu(dwconv(x_pre) + b)
        conv_silu_kernel<<<dim3(4096), blk, 0, stream>>>(
            proj, xtail, conv_w, conv_b, xconv, first);

        // 3) save conv tail for next chunk
        save_tail_kernel<<<dim3((3 * I_DIM + 255) / 256), blk, 0, stream>>>(proj, xtail);

        // 4) ssm = xconv @ W_x  (N=160 padded->256, split-K x4, atomics)
        zero_kernel<<<dim3((LC * NSSM + 255) / 256), blk, 0, stream>>>(ssm, LC * NSSM);
        gemm_p<0, 0, true><<<dim3(32, 4), blk, 0, stream>>>(
            xconv, I_DIM, WxPh, WxPl, ssm, NSSM,
            I_DIM, NSSM, LC / 128, I_DIM / 4, nullptr);

        // 5) delta = softplus(ssm[:, :R] @ W_dt + dt_bias) -> proj[:, :I]
        gemm_p<1, 0, false><<<dim3(512, 1), blk, 0, stream>>>(
            ssm, NSSM, WdtPh, WdtPl, proj, 2 * I_DIM,
            R_DIM, 0, LC / 128, R_DIM, dt_bias);

        // 6) segment-parallel scan; z packed u32 into proj's delta slot
        scan_part1<<<dim3(I_DIM / 16, SEG), blk, 0, stream>>>(
            proj, ssm, xconv, A_log, aprod, hend);
        scan_part2<<<dim3(IN_DIM / 256), blk, 0, stream>>>(
            aprod, hend, hstate, first);
        scan_part3<<<dim3(I_DIM / 16, SEG), blk, 0, stream>>>(
            proj, proj + I_DIM, ssm, xconv, (uint32_t*)proj, A_log, Dp, hend);

        // 7) out_c = z @ W_out  (M=2048, N=2048, K=4096) -> 256 blocks
        gemm_p<0, 1, false><<<dim3(256, 1), blk, 0, stream>>>(
            proj, 2 * I_DIM, WoutPh, WoutPl, out_c, H_DIM,
            I_DIM, 0, LC / 128, I_DIM, nullptr);
    }
}

// Round 7
// 2765.178 us; speedup vs baseline: 1.8418x; 1.2581x over previous
//
#include <hip/hip_runtime.h>
#include <cmath>
#include <stdint.h>

#define H_DIM 2048
#define I_DIM 4096
#define N_DIM 16
#define R_DIM 128
#define K_CONV 4
#define L_DIM 8192
#define LC 2048                 // chunk length
#define NCHUNK (L_DIM / LC)
#define SEG 32                  // scan segments per chunk
#define TSEG (LC / SEG)         // 64 steps per segment
#define IN_DIM (I_DIM * N_DIM)  // 65536 recurrences

typedef _Float16 f16x8 __attribute__((ext_vector_type(8)));
typedef float    f32x4 __attribute__((ext_vector_type(4)));

// direct HBM->LDS, 16B per lane; LDS base must be wave-uniform (HW adds lane*16)
__device__ __forceinline__ void gl_lds(const _Float16* g, _Float16* lbase, int lane) {
#if __has_builtin(__builtin_amdgcn_global_load_lds)
    __builtin_amdgcn_global_load_lds(
        (const __attribute__((address_space(1))) void*)g,
        (__attribute__((address_space(3))) void*)lbase, 16, 0, 0);
#else
    *(f16x8*)&lbase[lane * 8] = *(const f16x8*)g;
#endif
}

// ---------------------------------------------------------------------------
// Panel-format split-f16 MFMA GEMM (unchanged from round 6).
// ---------------------------------------------------------------------------
template <int EPI, int AK, bool ATOMIC>
__global__ __launch_bounds__(256, 2) void gemm_p(
    const void* __restrict__ Av, int lda,
    const _Float16* __restrict__ Bph, const _Float16* __restrict__ Bpl,
    float* __restrict__ C, int ldc,
    int Kd, int Ncap, int gm, int kchunk,
    const float* __restrict__ bias)
{
    __shared__ __align__(16) _Float16 Ah[4096];
    __shared__ __align__(16) _Float16 Al[4096];
    __shared__ __align__(16) _Float16 Bh[4096];
    __shared__ __align__(16) _Float16 Bl[4096];

    const int tid = threadIdx.x;
    int bid = blockIdx.x;
    const int q = gridDim.x >> 3;
    bid = (bid & 7) * q + (bid >> 3);
    const int m0 = (bid % gm) * 128;
    const int n0 = (bid / gm) * 128;

    const int kbeg = blockIdx.y * kchunk;
    const int kend = (kbeg + kchunk < Kd) ? (kbeg + kchunk) : Kd;

    const int w = tid >> 6, l = tid & 63;
    const int wm = w & 1, wn = w >> 1;
    const int lr = l & 15, lg = l >> 4;

    const int ar = tid >> 1, ah = tid & 1;
    const int aw0 = (ar >> 4) * 512 + (((ah * 2 + 0) * 16 + (ar & 15)) * 8);
    const int aw1 = (ar >> 4) * 512 + (((ah * 2 + 1) * 16 + (ar & 15)) * 8);

    const int KP = Kd >> 5;
    const int np0 = n0 >> 4;

    f32x4 acc[4][4];
#pragma unroll
    for (int a = 0; a < 4; ++a)
#pragma unroll
        for (int b = 0; b < 4; ++b) acc[a][b] = (f32x4){0.f, 0.f, 0.f, 0.f};

    f16x8 sah[2], sal[2];

    auto loadA = [&](int k0) {
        if (AK == 0) {
            const float* Ap = (const float*)Av + (size_t)(m0 + ar) * lda + k0 + ah * 16;
            float x[16];
            *(float4*)&x[0]  = *(const float4*)(Ap + 0);
            *(float4*)&x[4]  = *(const float4*)(Ap + 4);
            *(float4*)&x[8]  = *(const float4*)(Ap + 8);
            *(float4*)&x[12] = *(const float4*)(Ap + 12);
#pragma unroll
            for (int c2 = 0; c2 < 2; ++c2)
#pragma unroll
                for (int j = 0; j < 8; ++j) {
                    const float xv = x[c2 * 8 + j];
                    const _Float16 h = (_Float16)xv;
                    sah[c2][j] = h;
                    sal[c2][j] = (_Float16)(xv - (float)h);
                }
        } else {
            const uint32_t* Ap = (const uint32_t*)Av + (size_t)(m0 + ar) * lda + k0 + ah * 16;
            uint32_t x[16];
            *(uint4*)&x[0]  = *(const uint4*)(Ap + 0);
            *(uint4*)&x[4]  = *(const uint4*)(Ap + 4);
            *(uint4*)&x[8]  = *(const uint4*)(Ap + 8);
            *(uint4*)&x[12] = *(const uint4*)(Ap + 12);
#pragma unroll
            for (int c2 = 0; c2 < 2; ++c2)
#pragma unroll
                for (int j = 0; j < 8; ++j) {
                    const uint32_t wv = x[c2 * 8 + j];
                    sah[c2][j] = __builtin_bit_cast(_Float16, (unsigned short)(wv >> 16));
                    sal[c2][j] = __builtin_bit_cast(_Float16, (unsigned short)(wv & 0xffffu));
                }
        }
    };

    loadA(kbeg);

    for (int k0 = kbeg; k0 < kend; k0 += 32) {
        __syncthreads();
        *(f16x8*)&Ah[aw0] = sah[0];
        *(f16x8*)&Ah[aw1] = sah[1];
        *(f16x8*)&Al[aw0] = sal[0];
        *(f16x8*)&Al[aw1] = sal[1];
        {
            const int kp = k0 >> 5;
#pragma unroll
            for (int qq = 0; qq < 2; ++qq) {
                const int st = 2 * w + qq;
                const size_t goff = ((size_t)(np0 + st) * KP + kp) * 512 + (size_t)l * 8;
                gl_lds(Bph + goff, &Bh[st * 512], l);
                gl_lds(Bpl + goff, &Bl[st * 512], l);
            }
        }
        __syncthreads();

        if (k0 + 32 < kend) loadA(k0 + 32);

        f16x8 fah[4], fal[4], fbh[4], fbl[4];
#pragma unroll
        for (int t = 0; t < 4; ++t) {
            fah[t] = *(const f16x8*)&Ah[(wm * 4 + t) * 512 + l * 8];
            fal[t] = *(const f16x8*)&Al[(wm * 4 + t) * 512 + l * 8];
            fbh[t] = *(const f16x8*)&Bh[(wn * 4 + t) * 512 + l * 8];
            fbl[t] = *(const f16x8*)&Bl[(wn * 4 + t) * 512 + l * 8];
        }
#pragma unroll
        for (int mt = 0; mt < 4; ++mt)
#pragma unroll
            for (int nt = 0; nt < 4; ++nt) {
                f32x4& a = acc[mt][nt];
                a = __builtin_amdgcn_mfma_f32_16x16x32_f16(fah[mt], fbh[nt], a, 0, 0, 0);
                a = __builtin_amdgcn_mfma_f32_16x16x32_f16(fah[mt], fbl[nt], a, 0, 0, 0);
                a = __builtin_amdgcn_mfma_f32_16x16x32_f16(fal[mt], fbh[nt], a, 0, 0, 0);
            }
    }

#pragma unroll
    for (int mt = 0; mt < 4; ++mt) {
        const int row = m0 + wm * 64 + mt * 16 + lg * 4;
#pragma unroll
        for (int nt = 0; nt < 4; ++nt) {
            const int col = n0 + wn * 64 + nt * 16 + lr;
            if (Ncap == 0 || col < Ncap) {
#pragma unroll
                for (int j = 0; j < 4; ++j) {
                    float v = acc[mt][nt][j];
                    if (EPI == 1) {
                        v += bias[col];
                        v = (v > 20.f) ? v : log1pf(expf(v));
                    }
                    if (ATOMIC) atomicAdd(&C[(size_t)(row + j) * ldc + col], v);
                    else        C[(size_t)(row + j) * ldc + col] = v;
                }
            }
        }
    }
}

// ---------------------------------------------------------------------------
// Pack W [Kd][Nd] fp32 -> hi/lo f16 panels [Nd/16][Kd/32][512].
// ---------------------------------------------------------------------------
__global__ __launch_bounds__(128) void pack_bp(
    const float* __restrict__ W, _Float16* __restrict__ Ph,
    _Float16* __restrict__ Pl, int Kd, int Nd)
{
    __shared__ float t[32][33];
    const int tid = threadIdx.x;
    const int n0 = blockIdx.x * 32, k0 = blockIdx.y * 32;
#pragma unroll
    for (int h = 0; h < 2; ++h) {
        const int qd = tid + h * 128;
        const int kk = qd >> 3, qq = qd & 7;
        *(float4*)&t[kk][qq * 4] = *(const float4*)(W + (size_t)(k0 + kk) * Nd + n0 + qq * 4);
    }
    __syncthreads();
    const int c = tid >> 5, nn = tid & 31;
    const int np = (n0 + nn) >> 4;
    const int r  = nn & 15;
    const int kp = k0 >> 5;
    const size_t base = ((size_t)np * (Kd >> 5) + kp) * 512 + (c * 16 + r) * 8;
    f16x8 vh, vl;
#pragma unroll
    for (int j = 0; j < 8; ++j) {
        const float v = t[c * 8 + j][nn];
        const _Float16 h = (_Float16)v;
        vh[j] = h;
        vl[j] = (_Float16)(v - (float)h);
    }
    *(f16x8*)&Ph[base] = vh;
    *(f16x8*)&Pl[base] = vl;
}

__global__ __launch_bounds__(256) void zero_kernel(float* __restrict__ p, int n)
{
    const int idx = blockIdx.x * 256 + threadIdx.x;
    if (idx < n) p[idx] = 0.f;
}

__global__ __launch_bounds__(256) void save_tail_kernel(
    const float* __restrict__ proj, float* __restrict__ xtail)
{
    const int idx = blockIdx.x * 256 + threadIdx.x;
    if (idx >= 3 * I_DIM) return;
    const int r = idx >> 12;
    const int i = idx & (I_DIM - 1);
    xtail[idx] = proj[(size_t)(LC - 3 + r) * (2 * I_DIM) + i];
}

__global__ __launch_bounds__(256) void conv_silu_kernel(
    const float* __restrict__ proj,
    const float* __restrict__ xtail,
    const float* __restrict__ w,
    const float* __restrict__ b,
    float* __restrict__ xconv,
    int first)
{
    const int total = LC * I_DIM;
    const int stride = gridDim.x * blockDim.x;
    for (int idx = blockIdx.x * blockDim.x + threadIdx.x; idx < total; idx += stride) {
        const int t = idx >> 12;
        const int i = idx & (I_DIM - 1);
        float s = b[i];
#pragma unroll
        for (int k = 0; k < 4; ++k) {
            const int tt = t - 3 + k;
            float xv;
            if (tt >= 0)          xv = proj[(size_t)tt * (2 * I_DIM) + i];
            else if (!first)      xv = xtail[(size_t)(tt + 3) * I_DIM + i];
            else                  xv = 0.f;
            s = fmaf(w[i * 4 + k], xv, s);
        }
        xconv[idx] = s / (1.f + expf(-s));
    }
}

// ---------------------------------------------------------------------------
// Segment-parallel scan, transposed mapping: 2 lanes per channel i, each
// holding 8 of the 16 n-states in registers. B/C staged in LDS (broadcast).
// Per-(i,n) arithmetic identical to prior rounds -> bit-identical results.
// Block: 256 threads = 128 channels. Grid: (I/128, SEG).
// ---------------------------------------------------------------------------
__global__ __launch_bounds__(256) void scan_part1(
    const float* __restrict__ delta,  // ld 2I
    const float* __restrict__ ssm,    // LC x 160 (B at 128)
    const float* __restrict__ xc,     // LC x I (u)
    const float* __restrict__ A_log,
    float* __restrict__ aprod,        // [SEG][I][N]
    float* __restrict__ hend)         // [SEG][I][N]
{
    __shared__ float Bs[TSEG][16];
    const int tid = threadIdx.x;
    const int i = blockIdx.x * 128 + (tid >> 1);
    const int half = tid & 1;
    const int seg = blockIdx.y;
    const int t0 = seg * TSEG;

    // stage B tile: TSEG x 16 floats (1024), 256 threads -> 1 float4 each
    {
        const int tt = tid >> 2, c = (tid & 3) * 4;
        *(float4*)&Bs[tt][c] = *(const float4*)&ssm[(size_t)(t0 + tt) * 160 + 128 + c];
    }
    __syncthreads();

    float Ai[8], h[8], ap[8];
    {
        const float4 a0 = *(const float4*)&A_log[(size_t)i * 16 + half * 8];
        const float4 a1 = *(const float4*)&A_log[(size_t)i * 16 + half * 8 + 4];
        const float al[8] = {a0.x, a0.y, a0.z, a0.w, a1.x, a1.y, a1.z, a1.w};
#pragma unroll
        for (int n = 0; n < 8; ++n) { Ai[n] = -expf(al[n]); h[n] = 0.f; ap[n] = 1.f; }
    }

    float d = delta[(size_t)t0 * (2 * I_DIM) + i];
    float u = xc[(size_t)t0 * I_DIM + i];
    for (int t = 0; t < TSEG; ++t) {
        float dn = 0.f, un = 0.f;
        if (t + 1 < TSEG) {
            dn = delta[(size_t)(t0 + t + 1) * (2 * I_DIM) + i];
            un = xc[(size_t)(t0 + t + 1) * I_DIM + i];
        }
        const float du = d * u;
#pragma unroll
        for (int n = 0; n < 8; ++n) {
            const float a = expf(d * Ai[n]);
            h[n] = fmaf(h[n], a, du * Bs[t][half * 8 + n]);
            ap[n] *= a;
        }
        d = dn; u = un;
    }

    const size_t base = (size_t)seg * IN_DIM + (size_t)i * 16 + half * 8;
#pragma unroll
    for (int qq = 0; qq < 2; ++qq) {
        float4 va = {ap[qq * 4 + 0], ap[qq * 4 + 1], ap[qq * 4 + 2], ap[qq * 4 + 3]};
        float4 vh = {h[qq * 4 + 0], h[qq * 4 + 1], h[qq * 4 + 2], h[qq * 4 + 3]};
        *(float4*)&aprod[base + qq * 4] = va;
        *(float4*)&hend[base + qq * 4]  = vh;
    }
}

// Phase 2: chain segment summaries; hend[] becomes h_start[] in place.
__global__ __launch_bounds__(256) void scan_part2(
    const float* __restrict__ aprod,
    float* __restrict__ hend,
    float* __restrict__ hstate,
    int first)
{
    const int gid = blockIdx.x * 256 + threadIdx.x;
    float h = first ? 0.f : hstate[gid];
    for (int s = 0; s < SEG; ++s) {
        const int idx = s * IN_DIM + gid;
        const float ap = aprod[idx];
        const float he = hend[idx];
        hend[idx] = h;
        h = fmaf(ap, h, he);
    }
    hstate[gid] = h;
}

// Phase 3: re-run segment from exact h_start; y via in-register C-dot +
// one shfl_xor(1); write z PACKED (hi16|lo16 f16) into proj's delta slot.
__global__ __launch_bounds__(256) void scan_part3(
    const float* __restrict__ delta,   // ld 2I
    const float* __restrict__ gate,    // ld 2I
    const float* __restrict__ ssm,     // LC x 160 (B at 128, C at 144)
    const float* __restrict__ xc,      // u
    uint32_t* __restrict__ zout,       // proj x-half as u32, ld 2I
    const float* __restrict__ A_log,
    const float* __restrict__ Dp,
    const float* __restrict__ hstart)  // [SEG][I][N]
{
    __shared__ float BCs[TSEG][32];
    const int tid = threadIdx.x;
    const int i = blockIdx.x * 128 + (tid >> 1);
    const int half = tid & 1;
    const int seg = blockIdx.y;
    const int t0 = seg * TSEG;

    // stage B|C tile: TSEG x 32 floats (2048), 256 threads -> 2 float4 each
    {
        const int tt = tid >> 2, c = (tid & 3) * 8;
        *(float4*)&BCs[tt][c]     = *(const float4*)&ssm[(size_t)(t0 + tt) * 160 + 128 + c];
        *(float4*)&BCs[tt][c + 4] = *(const float4*)&ssm[(size_t)(t0 + tt) * 160 + 132 + c];
    }
    __syncthreads();

    float Ai[8], h[8];
    {
        const float4 a0 = *(const float4*)&A_log[(size_t)i * 16 + half * 8];
        const float4 a1 = *(const float4*)&A_log[(size_t)i * 16 + half * 8 + 4];
        const float al[8] = {a0.x, a0.y, a0.z, a0.w, a1.x, a1.y, a1.z, a1.w};
#pragma unroll
        for (int n = 0; n < 8; ++n) Ai[n] = -expf(al[n]);
        const size_t base = (size_t)seg * IN_DIM + (size_t)i * 16 + half * 8;
        const float4 h0 = *(const float4*)&hstart[base];
        const float4 h1 = *(const float4*)&hstart[base + 4];
        h[0] = h0.x; h[1] = h0.y; h[2] = h0.z; h[3] = h0.w;
        h[4] = h1.x; h[5] = h1.y; h[6] = h1.z; h[7] = h1.w;
    }
    const float Di = Dp[i];

    float d = delta[(size_t)t0 * (2 * I_DIM) + i];
    float u = xc[(size_t)t0 * I_DIM + i];
    float g = gate[(size_t)t0 * (2 * I_DIM) + i];
    for (int t = 0; t < TSEG; ++t) {
        float dn = 0.f, un = 0.f, gn = 0.f;
        if (t + 1 < TSEG) {
            dn = delta[(size_t)(t0 + t + 1) * (2 * I_DIM) + i];
            un = xc[(size_t)(t0 + t + 1) * I_DIM + i];
            gn = gate[(size_t)(t0 + t + 1) * (2 * I_DIM) + i];
        }
        const float du = d * u;
        float y = 0.f;
#pragma unroll
        for (int n = 0; n < 8; ++n) {
            const float a = expf(d * Ai[n]);
            h[n] = fmaf(h[n], a, du * BCs[t][half * 8 + n]);
            y = fmaf(h[n], BCs[t][16 + half * 8 + n], y);
        }
        y += __shfl_xor(y, 1);
        if (half == 0) {
            const float sg = g / (1.f + expf(-g));
            const float zv = (y + u * Di) * sg;
            const _Float16 zh = (_Float16)zv;
            const _Float16 zl = (_Float16)(zv - (float)zh);
            const uint32_t pz =
                ((uint32_t)__builtin_bit_cast(unsigned short, zh) << 16) |
                (uint32_t)__builtin_bit_cast(unsigned short, zl);
            zout[(size_t)(t0 + t) * (2 * I_DIM) + i] = pz;
        }
        d = dn; u = un; g = gn;
    }
}

// ---------------------------------------------------------------------------
extern "C" void kernel_launch(void* const* d_in, const int* in_sizes, int n_in,
                              void* d_out, int out_size, void* d_ws, size_t ws_size,
                              hipStream_t stream)
{
    const float* hs      = (const float*)d_in[0];
    const float* W_in    = (const float*)d_in[1];
    const float* conv_w  = (const float*)d_in[2];
    const float* conv_b  = (const float*)d_in[3];
    const float* W_x     = (const float*)d_in[4];
    const float* W_dt    = (const float*)d_in[5];
    const float* dt_bias = (const float*)d_in[6];
    const float* A_log   = (const float*)d_in[7];
    const float* Dp      = (const float*)d_in[8];
    const float* W_out   = (const float*)d_in[9];
    float* out = (float*)d_out;

    // workspace layout (~200 MB)
    char* p = (char*)d_ws;
    auto alloc = [&](size_t bytes) {
        char* r = p;
        p += (bytes + 255) & ~(size_t)255;
        return r;
    };
    float* proj   = (float*)alloc((size_t)LC * 2 * I_DIM * 4);   // 64 MB
    float* xconv  = (float*)alloc((size_t)LC * I_DIM * 4);       // 32 MB
    float* ssm    = (float*)alloc((size_t)LC * 160 * 4);
    float* xtail  = (float*)alloc((size_t)3 * I_DIM * 4);
    float* hstate = (float*)alloc((size_t)IN_DIM * 4);
    _Float16* WinPh  = (_Float16*)alloc((size_t)2 * I_DIM * H_DIM * 2);  // 32 MB
    _Float16* WinPl  = (_Float16*)alloc((size_t)2 * I_DIM * H_DIM * 2);
    _Float16* WoutPh = (_Float16*)alloc((size_t)H_DIM * I_DIM * 2);      // 16 MB
    _Float16* WoutPl = (_Float16*)alloc((size_t)H_DIM * I_DIM * 2);
    _Float16* WdtPh  = (_Float16*)alloc((size_t)I_DIM * R_DIM * 2);
    _Float16* WdtPl  = (_Float16*)alloc((size_t)I_DIM * R_DIM * 2);
    _Float16* WxPh   = (_Float16*)alloc((size_t)256 * I_DIM * 2);
    _Float16* WxPl   = (_Float16*)alloc((size_t)256 * I_DIM * 2);

    const dim3 blk(256);
    const int NSSM = R_DIM + 2 * N_DIM;  // 160

    // ---- pack weights into panel format (once per launch) ----
    pack_bp<<<dim3(2 * I_DIM / 32, H_DIM / 32), dim3(128), 0, stream>>>(
        W_in, WinPh, WinPl, H_DIM, 2 * I_DIM);
    pack_bp<<<dim3(H_DIM / 32, I_DIM / 32), dim3(128), 0, stream>>>(
        W_out, WoutPh, WoutPl, I_DIM, H_DIM);
    pack_bp<<<dim3(I_DIM / 32, R_DIM / 32), dim3(128), 0, stream>>>(
        W_dt, WdtPh, WdtPl, R_DIM, I_DIM);
    pack_bp<<<dim3(NSSM / 32, I_DIM / 32), dim3(128), 0, stream>>>(
        W_x, WxPh, WxPl, I_DIM, NSSM);

    for (int c = 0; c < NCHUNK; ++c) {
        const int t0 = c * LC;
        const int first = (c == 0) ? 1 : 0;
        const float* hs_c = hs + (size_t)t0 * H_DIM;
        float* out_c = out + (size_t)t0 * H_DIM;
        float* aprod = out_c;                 // scan scratch in out region
        float* hend  = out_c + (size_t)SEG * IN_DIM;

        // 1) proj = hs_c @ W_in   (M=2048, N=8192, K=2048) -> 1024 blocks
        gemm_p<0, 0, false><<<dim3(1024, 1), blk, 0, stream>>>(
            hs_c, H_DIM, WinPh, WinPl, proj, 2 * I_DIM,
            H_DIM, 0, LC / 128, H_DIM, nullptr);

        // 2) xconv = silu(dwconv(x_pre) + b)
        conv_silu_kernel<<<dim3(4096), blk, 0, stream>>>(
            proj, xtail, conv_w, conv_b, xconv, first);

        // 3) save conv tail for next chunk
        save_tail_kernel<<<dim3((3 * I_DIM + 255) / 256), blk, 0, stream>>>(proj, xtail);

        // 4) ssm = xconv @ W_x  (N=160 padded->256, split-K x4, atomics)
        zero_kernel<<<dim3((LC * NSSM + 255) / 256), blk, 0, stream>>>(ssm, LC * NSSM);
        gemm_p<0, 0, true><<<dim3(32, 4), blk, 0, stream>>>(
            xconv, I_DIM, WxPh, WxPl, ssm, NSSM,
            I_DIM, NSSM, LC / 128, I_DIM / 4, nullptr);

        // 5) delta = softplus(ssm[:, :R] @ W_dt + dt_bias) -> proj[:, :I]
        gemm_p<1, 0, false><<<dim3(512, 1), blk, 0, stream>>>(
            ssm, NSSM, WdtPh, WdtPl, proj, 2 * I_DIM,
            R_DIM, 0, LC / 128, R_DIM, dt_bias);

        // 6) segment-parallel scan; z packed u32 into proj's delta slot
        scan_part1<<<dim3(I_DIM / 128, SEG), blk, 0, stream>>>(
            proj, ssm, xconv, A_log, aprod, hend);
        scan_part2<<<dim3(IN_DIM / 256), blk, 0, stream>>>(
            aprod, hend, hstate, first);
        scan_part3<<<dim3(I_DIM / 128, SEG), blk, 0, stream>>>(
            proj, proj + I_DIM, ssm, xconv, (uint32_t*)proj, A_log, Dp, hend);

        // 7) out_c = z @ W_out  (M=2048, N=2048, K=4096) -> 256 blocks
        gemm_p<0, 1, false><<<dim3(256, 1), blk, 0, stream>>>(
            proj, 2 * I_DIM, WoutPh, WoutPl, out_c, H_DIM,
            I_DIM, 0, LC / 128, I_DIM, nullptr);
    }
}

// Round 8
// 2212.166 us; speedup vs baseline: 2.3022x; 1.2500x over previous
//
#include <hip/hip_runtime.h>
#include <cmath>
#include <stdint.h>

#define H_DIM 2048
#define I_DIM 4096
#define N_DIM 16
#define R_DIM 128
#define K_CONV 4
#define L_DIM 8192
#define LC 2048                 // chunk length
#define NCHUNK (L_DIM / LC)
#define SEG 32                  // scan segments per chunk
#define TSEG (LC / SEG)         // 64 steps per segment
#define IN_DIM (I_DIM * N_DIM)  // 65536 recurrences

typedef _Float16 f16x8 __attribute__((ext_vector_type(8)));
typedef float    f32x4 __attribute__((ext_vector_type(4)));

// direct HBM->LDS, 16B per lane; LDS base must be wave-uniform (HW adds lane*16)
__device__ __forceinline__ void gl_lds(const _Float16* g, _Float16* lbase, int lane) {
#if __has_builtin(__builtin_amdgcn_global_load_lds)
    __builtin_amdgcn_global_load_lds(
        (const __attribute__((address_space(1))) void*)g,
        (__attribute__((address_space(3))) void*)lbase, 16, 0, 0);
#else
    *(f16x8*)&lbase[lane * 8] = *(const f16x8*)g;
#endif
}

// ---------------------------------------------------------------------------
// Panel-format split-f16 MFMA GEMM, double-buffered (2-phase pipeline).
//   C[M,N] (+)= A[M,K] @ B[K,N]
// B pre-split+packed panels [N/16][K/32][512]; staged via global_load_lds.
// A: AK=0 fp32 [M][K] reg-split | AK=1 u32 packed rows | AK=2 pre-split
//    panels [M/16][K/32][512] staged via global_load_lds (no VALU staging).
// Block 128x128, BK=32, 4 waves (2x2), wave tile 64x64; 3 MFMA per hi/lo.
// EPI: 0 none; 1 softplus(x+bias[col]). Ncap>0 guards stores to col<Ncap.
// Split-K via blockIdx.y * kchunk (ATOMIC accumulate; zero C first).
// ---------------------------------------------------------------------------
template <int EPI, int AK, bool ATOMIC>
__global__ __launch_bounds__(256, 2) void gemm_p(
    const void* __restrict__ Av, int lda,
    const _Float16* __restrict__ Aph, const _Float16* __restrict__ Apl,
    const _Float16* __restrict__ Bph, const _Float16* __restrict__ Bpl,
    float* __restrict__ C, int ldc,
    int Kd, int Ncap, int gm, int kchunk,
    const float* __restrict__ bias)
{
    __shared__ __align__(16) _Float16 Sh[2][4][4096];  // [buf][Ah,Al,Bh,Bl]

    const int tid = threadIdx.x;
    int bid = blockIdx.x;
    const int q = gridDim.x >> 3;        // grids are multiples of 8
    bid = (bid & 7) * q + (bid >> 3);    // bijective XCD swizzle
    const int m0 = (bid % gm) * 128;
    const int n0 = (bid / gm) * 128;

    const int kbeg = blockIdx.y * kchunk;
    const int kend = (kbeg + kchunk < Kd) ? (kbeg + kchunk) : Kd;

    const int w = tid >> 6, l = tid & 63;
    const int wm = w & 1, wn = w >> 1;
    const int lr = l & 15, lg = l >> 4;

    // reg-path A staging coords
    const int ar = tid >> 1, ah = tid & 1;
    const int aw0 = (ar >> 4) * 512 + (((ah * 2) * 16 + (ar & 15)) * 8);
    const int aw1 = aw0 + 128;

    const int KP = Kd >> 5;
    const int np0 = n0 >> 4;
    const int mp0 = m0 >> 4;

    f32x4 acc[4][4];
#pragma unroll
    for (int a = 0; a < 4; ++a)
#pragma unroll
        for (int b = 0; b < 4; ++b) acc[a][b] = (f32x4){0.f, 0.f, 0.f, 0.f};

    float    xf[16];
    uint32_t xu[16];
    f16x8 sah[2], sal[2];

    auto issueA = [&](int k0) {  // vm loads into raw regs (no cvt yet)
        if (AK == 0) {
            const float* Ap = (const float*)Av + (size_t)(m0 + ar) * lda + k0 + ah * 16;
            *(float4*)&xf[0]  = *(const float4*)(Ap + 0);
            *(float4*)&xf[4]  = *(const float4*)(Ap + 4);
            *(float4*)&xf[8]  = *(const float4*)(Ap + 8);
            *(float4*)&xf[12] = *(const float4*)(Ap + 12);
        } else if (AK == 1) {
            const uint32_t* Ap = (const uint32_t*)Av + (size_t)(m0 + ar) * lda + k0 + ah * 16;
            *(uint4*)&xu[0]  = *(const uint4*)(Ap + 0);
            *(uint4*)&xu[4]  = *(const uint4*)(Ap + 4);
            *(uint4*)&xu[8]  = *(const uint4*)(Ap + 8);
            *(uint4*)&xu[12] = *(const uint4*)(Ap + 12);
        }
    };
    auto cvtA = [&]() {
        if (AK == 0) {
#pragma unroll
            for (int c2 = 0; c2 < 2; ++c2)
#pragma unroll
                for (int j = 0; j < 8; ++j) {
                    const float xv = xf[c2 * 8 + j];
                    const _Float16 h = (_Float16)xv;
                    sah[c2][j] = h;
                    sal[c2][j] = (_Float16)(xv - (float)h);
                }
        } else if (AK == 1) {
#pragma unroll
            for (int c2 = 0; c2 < 2; ++c2)
#pragma unroll
                for (int j = 0; j < 8; ++j) {
                    const uint32_t wv = xu[c2 * 8 + j];
                    sah[c2][j] = __builtin_bit_cast(_Float16, (unsigned short)(wv >> 16));
                    sal[c2][j] = __builtin_bit_cast(_Float16, (unsigned short)(wv & 0xffffu));
                }
        }
    };
    auto writeA = [&](int p) {
        *(f16x8*)&Sh[p][0][aw0] = sah[0];
        *(f16x8*)&Sh[p][0][aw1] = sah[1];
        *(f16x8*)&Sh[p][1][aw0] = sal[0];
        *(f16x8*)&Sh[p][1][aw1] = sal[1];
    };
    auto stageGL = [&](int k0, int p) {  // gl_lds staging (B always; A if AK==2)
        const int kp = k0 >> 5;
        if (AK == 2) {
#pragma unroll
            for (int s = 0; s < 2; ++s) {
                const int st = w + s * 4;
                const size_t ga = ((size_t)(mp0 + st) * KP + kp) * 512 + (size_t)l * 8;
                gl_lds(Aph + ga, &Sh[p][0][st * 512], l);
                gl_lds(Apl + ga, &Sh[p][1][st * 512], l);
            }
        }
#pragma unroll
        for (int qq = 0; qq < 2; ++qq) {
            const int st = 2 * w + qq;
            const size_t go = ((size_t)(np0 + st) * KP + kp) * 512 + (size_t)l * 8;
            gl_lds(Bph + go, &Sh[p][2][st * 512], l);
            gl_lds(Bpl + go, &Sh[p][3][st * 512], l);
        }
    };

    // prologue: stage tile 0 into buf 0
    if (AK != 2) { issueA(kbeg); cvtA(); writeA(0); }
    stageGL(kbeg, 0);
    __syncthreads();

    int p = 0;
    for (int k0 = kbeg; k0 < kend; k0 += 32) {
        const bool more = (k0 + 32 < kend);
        if (more) {                      // issue next-tile staging FIRST
            if (AK != 2) issueA(k0 + 32);
            stageGL(k0 + 32, p ^ 1);
        }

        f16x8 fah[4], fal[4], fbh[4], fbl[4];
#pragma unroll
        for (int t = 0; t < 4; ++t) {
            fah[t] = *(const f16x8*)&Sh[p][0][(wm * 4 + t) * 512 + l * 8];
            fal[t] = *(const f16x8*)&Sh[p][1][(wm * 4 + t) * 512 + l * 8];
            fbh[t] = *(const f16x8*)&Sh[p][2][(wn * 4 + t) * 512 + l * 8];
            fbl[t] = *(const f16x8*)&Sh[p][3][(wn * 4 + t) * 512 + l * 8];
        }
#pragma unroll
        for (int mt = 0; mt < 4; ++mt)
#pragma unroll
            for (int nt = 0; nt < 4; ++nt) {
                f32x4& a = acc[mt][nt];
                a = __builtin_amdgcn_mfma_f32_16x16x32_f16(fah[mt], fbh[nt], a, 0, 0, 0);
                a = __builtin_amdgcn_mfma_f32_16x16x32_f16(fah[mt], fbl[nt], a, 0, 0, 0);
                a = __builtin_amdgcn_mfma_f32_16x16x32_f16(fal[mt], fbh[nt], a, 0, 0, 0);
            }

        if (more && AK != 2) { cvtA(); writeA(p ^ 1); }  // late write (vm wait here)
        __syncthreads();   // compiler: vmcnt(0)+lgkmcnt(0) — hidden by MFMA above
        p ^= 1;
    }

    // epilogue
#pragma unroll
    for (int mt = 0; mt < 4; ++mt) {
        const int row = m0 + wm * 64 + mt * 16 + lg * 4;
#pragma unroll
        for (int nt = 0; nt < 4; ++nt) {
            const int col = n0 + wn * 64 + nt * 16 + lr;
            if (Ncap == 0 || col < Ncap) {
#pragma unroll
                for (int j = 0; j < 4; ++j) {
                    float v = acc[mt][nt][j];
                    if (EPI == 1) {
                        v += bias[col];
                        v = (v > 20.f) ? v : log1pf(expf(v));
                    }
                    if (ATOMIC) atomicAdd(&C[(size_t)(row + j) * ldc + col], v);
                    else        C[(size_t)(row + j) * ldc + col] = v;
                }
            }
        }
    }
}

// ---------------------------------------------------------------------------
// Pack W [Kd][Nd] fp32 -> hi/lo f16 B-panels [Nd/16][Kd/32][512].
// ---------------------------------------------------------------------------
__global__ __launch_bounds__(128) void pack_bp(
    const float* __restrict__ W, _Float16* __restrict__ Ph,
    _Float16* __restrict__ Pl, int Kd, int Nd)
{
    __shared__ float t[32][33];
    const int tid = threadIdx.x;
    const int n0 = blockIdx.x * 32, k0 = blockIdx.y * 32;
#pragma unroll
    for (int h = 0; h < 2; ++h) {
        const int qd = tid + h * 128;
        const int kk = qd >> 3, qq = qd & 7;
        *(float4*)&t[kk][qq * 4] = *(const float4*)(W + (size_t)(k0 + kk) * Nd + n0 + qq * 4);
    }
    __syncthreads();
    const int c = tid >> 5, nn = tid & 31;
    const int np = (n0 + nn) >> 4;
    const int r  = nn & 15;
    const int kp = k0 >> 5;
    const size_t base = ((size_t)np * (Kd >> 5) + kp) * 512 + (c * 16 + r) * 8;
    f16x8 vh, vl;
#pragma unroll
    for (int j = 0; j < 8; ++j) {
        const float v = t[c * 8 + j][nn];
        const _Float16 h = (_Float16)v;
        vh[j] = h;
        vl[j] = (_Float16)(v - (float)h);
    }
    *(f16x8*)&Ph[base] = vh;
    *(f16x8*)&Pl[base] = vl;
}

// ---------------------------------------------------------------------------
// Pack A fp32 [M][K] row-major -> hi/lo A-panels [M/16][K/32][512].
// grid (M/16, K/128), 256 threads: r = tid>>4, c8 = tid&15 (k-octet).
// ---------------------------------------------------------------------------
__global__ __launch_bounds__(256) void pack_ap(
    const float* __restrict__ A, int lda,
    _Float16* __restrict__ Ph, _Float16* __restrict__ Pl, int Kd)
{
    const int tid = threadIdx.x;
    const int mp = blockIdx.x;
    const int r = tid >> 4, c8 = tid & 15;
    const int k0 = blockIdx.y * 128 + c8 * 8;
    const float* Ap = A + (size_t)(mp * 16 + r) * lda + k0;
    const float4 v0 = *(const float4*)Ap;
    const float4 v1 = *(const float4*)(Ap + 4);
    const float x[8] = {v0.x, v0.y, v0.z, v0.w, v1.x, v1.y, v1.z, v1.w};
    f16x8 vh, vl;
#pragma unroll
    for (int j = 0; j < 8; ++j) {
        const _Float16 h = (_Float16)x[j];
        vh[j] = h;
        vl[j] = (_Float16)(x[j] - (float)h);
    }
    const int kp = k0 >> 5;
    const int c  = (k0 >> 3) & 3;
    const size_t base = ((size_t)mp * (Kd >> 5) + kp) * 512 + (c * 16 + r) * 8;
    *(f16x8*)&Ph[base] = vh;
    *(f16x8*)&Pl[base] = vl;
}

__global__ __launch_bounds__(256) void zero_kernel(float* __restrict__ p, int n)
{
    const int idx = blockIdx.x * 256 + threadIdx.x;
    if (idx < n) p[idx] = 0.f;
}

// ---------------------------------------------------------------------------
// Causal depthwise conv (K=4) + bias + silu, vectorized: each thread handles
// 4 channels x 8 timesteps via an 11-row float4 register window. The last
// 3 x-rows are saved to xtail_out (double-buffered) for the next chunk.
// grid: (LC/8) * (I/4) / 256 = 1024 blocks.
// ---------------------------------------------------------------------------
__global__ __launch_bounds__(256) void conv_silu_kernel(
    const float* __restrict__ proj,      // x-half, ld 2I
    const float* __restrict__ xtail_in,  // 3 x I
    float* __restrict__ xtail_out,       // 3 x I
    const float* __restrict__ w,         // I x 4
    const float* __restrict__ b,         // I
    float* __restrict__ xconv,           // LC x I
    int first)
{
    const int gid = blockIdx.x * 256 + threadIdx.x;
    const int i4 = gid & (I_DIM / 4 - 1);
    const int t8 = gid >> 10;
    const int i = i4 * 4;
    const int tt0 = t8 * 8;

    const float4 w0 = *(const float4*)(w + (size_t)(i + 0) * 4);
    const float4 w1 = *(const float4*)(w + (size_t)(i + 1) * 4);
    const float4 w2 = *(const float4*)(w + (size_t)(i + 2) * 4);
    const float4 w3 = *(const float4*)(w + (size_t)(i + 3) * 4);
    const float4 bb = *(const float4*)(b + i);

    float4 r[11];
    if (tt0 >= 3) {
#pragma unroll
        for (int s = 0; s < 11; ++s)
            r[s] = *(const float4*)(proj + (size_t)(tt0 - 3 + s) * (2 * I_DIM) + i);
    } else {  // tt0 == 0
#pragma unroll
        for (int s = 0; s < 3; ++s)
            r[s] = first ? make_float4(0.f, 0.f, 0.f, 0.f)
                         : *(const float4*)(xtail_in + (size_t)s * I_DIM + i);
#pragma unroll
        for (int s = 3; s < 11; ++s)
            r[s] = *(const float4*)(proj + (size_t)(tt0 - 3 + s) * (2 * I_DIM) + i);
    }

#pragma unroll
    for (int s = 0; s < 8; ++s) {
        float4 y = bb;
        y.x = fmaf(w0.x, r[s].x, y.x); y.x = fmaf(w0.y, r[s+1].x, y.x);
        y.x = fmaf(w0.z, r[s+2].x, y.x); y.x = fmaf(w0.w, r[s+3].x, y.x);
        y.y = fmaf(w1.x, r[s].y, y.y); y.y = fmaf(w1.y, r[s+1].y, y.y);
        y.y = fmaf(w1.z, r[s+2].y, y.y); y.y = fmaf(w1.w, r[s+3].y, y.y);
        y.z = fmaf(w2.x, r[s].z, y.z); y.z = fmaf(w2.y, r[s+1].z, y.z);
        y.z = fmaf(w2.z, r[s+2].z, y.z); y.z = fmaf(w2.w, r[s+3].z, y.z);
        y.w = fmaf(w3.x, r[s].w, y.w); y.w = fmaf(w3.y, r[s+1].w, y.w);
        y.w = fmaf(w3.z, r[s+2].w, y.w); y.w = fmaf(w3.w, r[s+3].w, y.w);
        y.x = y.x / (1.f + expf(-y.x));
        y.y = y.y / (1.f + expf(-y.y));
        y.z = y.z / (1.f + expf(-y.z));
        y.w = y.w / (1.f + expf(-y.w));
        *(float4*)(xconv + (size_t)(tt0 + s) * I_DIM + i) = y;
    }

    if (tt0 == LC - 8) {   // fused tail save (rows LC-3..LC-1 = r[8..10])
#pragma unroll
        for (int qq = 0; qq < 3; ++qq)
            *(float4*)(xtail_out + (size_t)qq * I_DIM + i) = r[8 + qq];
    }
}

// ---------------------------------------------------------------------------
// Segment-parallel scan (unchanged from round 7).
// ---------------------------------------------------------------------------
__global__ __launch_bounds__(256) void scan_part1(
    const float* __restrict__ delta,
    const float* __restrict__ ssm,
    const float* __restrict__ xc,
    const float* __restrict__ A_log,
    float* __restrict__ aprod,
    float* __restrict__ hend)
{
    __shared__ float Bs[TSEG][16];
    const int tid = threadIdx.x;
    const int i = blockIdx.x * 128 + (tid >> 1);
    const int half = tid & 1;
    const int seg = blockIdx.y;
    const int t0 = seg * TSEG;

    {
        const int tt = tid >> 2, c = (tid & 3) * 4;
        *(float4*)&Bs[tt][c] = *(const float4*)&ssm[(size_t)(t0 + tt) * 160 + 128 + c];
    }
    __syncthreads();

    float Ai[8], h[8], ap[8];
    {
        const float4 a0 = *(const float4*)&A_log[(size_t)i * 16 + half * 8];
        const float4 a1 = *(const float4*)&A_log[(size_t)i * 16 + half * 8 + 4];
        const float al[8] = {a0.x, a0.y, a0.z, a0.w, a1.x, a1.y, a1.z, a1.w};
#pragma unroll
        for (int n = 0; n < 8; ++n) { Ai[n] = -expf(al[n]); h[n] = 0.f; ap[n] = 1.f; }
    }

    float d = delta[(size_t)t0 * (2 * I_DIM) + i];
    float u = xc[(size_t)t0 * I_DIM + i];
    for (int t = 0; t < TSEG; ++t) {
        float dn = 0.f, un = 0.f;
        if (t + 1 < TSEG) {
            dn = delta[(size_t)(t0 + t + 1) * (2 * I_DIM) + i];
            un = xc[(size_t)(t0 + t + 1) * I_DIM + i];
        }
        const float du = d * u;
#pragma unroll
        for (int n = 0; n < 8; ++n) {
            const float a = expf(d * Ai[n]);
            h[n] = fmaf(h[n], a, du * Bs[t][half * 8 + n]);
            ap[n] *= a;
        }
        d = dn; u = un;
    }

    const size_t base = (size_t)seg * IN_DIM + (size_t)i * 16 + half * 8;
#pragma unroll
    for (int qq = 0; qq < 2; ++qq) {
        float4 va = {ap[qq * 4 + 0], ap[qq * 4 + 1], ap[qq * 4 + 2], ap[qq * 4 + 3]};
        float4 vh = {h[qq * 4 + 0], h[qq * 4 + 1], h[qq * 4 + 2], h[qq * 4 + 3]};
        *(float4*)&aprod[base + qq * 4] = va;
        *(float4*)&hend[base + qq * 4]  = vh;
    }
}

__global__ __launch_bounds__(256) void scan_part2(
    const float* __restrict__ aprod,
    float* __restrict__ hend,
    float* __restrict__ hstate,
    int first)
{
    const int gid = blockIdx.x * 256 + threadIdx.x;
    float h = first ? 0.f : hstate[gid];
    for (int s = 0; s < SEG; ++s) {
        const int idx = s * IN_DIM + gid;
        const float ap = aprod[idx];
        const float he = hend[idx];
        hend[idx] = h;
        h = fmaf(ap, h, he);
    }
    hstate[gid] = h;
}

__global__ __launch_bounds__(256) void scan_part3(
    const float* __restrict__ delta,
    const float* __restrict__ gate,
    const float* __restrict__ ssm,
    const float* __restrict__ xc,
    uint32_t* __restrict__ zout,
    const float* __restrict__ A_log,
    const float* __restrict__ Dp,
    const float* __restrict__ hstart)
{
    __shared__ float BCs[TSEG][32];
    const int tid = threadIdx.x;
    const int i = blockIdx.x * 128 + (tid >> 1);
    const int half = tid & 1;
    const int seg = blockIdx.y;
    const int t0 = seg * TSEG;

    {
        const int tt = tid >> 2, c = (tid & 3) * 8;
        *(float4*)&BCs[tt][c]     = *(const float4*)&ssm[(size_t)(t0 + tt) * 160 + 128 + c];
        *(float4*)&BCs[tt][c + 4] = *(const float4*)&ssm[(size_t)(t0 + tt) * 160 + 132 + c];
    }
    __syncthreads();

    float Ai[8], h[8];
    {
        const float4 a0 = *(const float4*)&A_log[(size_t)i * 16 + half * 8];
        const float4 a1 = *(const float4*)&A_log[(size_t)i * 16 + half * 8 + 4];
        const float al[8] = {a0.x, a0.y, a0.z, a0.w, a1.x, a1.y, a1.z, a1.w};
#pragma unroll
        for (int n = 0; n < 8; ++n) Ai[n] = -expf(al[n]);
        const size_t base = (size_t)seg * IN_DIM + (size_t)i * 16 + half * 8;
        const float4 h0 = *(const float4*)&hstart[base];
        const float4 h1 = *(const float4*)&hstart[base + 4];
        h[0] = h0.x; h[1] = h0.y; h[2] = h0.z; h[3] = h0.w;
        h[4] = h1.x; h[5] = h1.y; h[6] = h1.z; h[7] = h1.w;
    }
    const float Di = Dp[i];

    float d = delta[(size_t)t0 * (2 * I_DIM) + i];
    float u = xc[(size_t)t0 * I_DIM + i];
    float g = gate[(size_t)t0 * (2 * I_DIM) + i];
    for (int t = 0; t < TSEG; ++t) {
        float dn = 0.f, un = 0.f, gn = 0.f;
        if (t + 1 < TSEG) {
            dn = delta[(size_t)(t0 + t + 1) * (2 * I_DIM) + i];
            un = xc[(size_t)(t0 + t + 1) * I_DIM + i];
            gn = gate[(size_t)(t0 + t + 1) * (2 * I_DIM) + i];
        }
        const float du = d * u;
        float y = 0.f;
#pragma unroll
        for (int n = 0; n < 8; ++n) {
            const float a = expf(d * Ai[n]);
            h[n] = fmaf(h[n], a, du * BCs[t][half * 8 + n]);
            y = fmaf(h[n], BCs[t][16 + half * 8 + n], y);
        }
        y += __shfl_xor(y, 1);
        if (half == 0) {
            const float sg = g / (1.f + expf(-g));
            const float zv = (y + u * Di) * sg;
            const _Float16 zh = (_Float16)zv;
            const _Float16 zl = (_Float16)(zv - (float)zh);
            const uint32_t pz =
                ((uint32_t)__builtin_bit_cast(unsigned short, zh) << 16) |
                (uint32_t)__builtin_bit_cast(unsigned short, zl);
            zout[(size_t)(t0 + t) * (2 * I_DIM) + i] = pz;
        }
        d = dn; u = un; g = gn;
    }
}

// ---------------------------------------------------------------------------
extern "C" void kernel_launch(void* const* d_in, const int* in_sizes, int n_in,
                              void* d_out, int out_size, void* d_ws, size_t ws_size,
                              hipStream_t stream)
{
    const float* hs      = (const float*)d_in[0];
    const float* W_in    = (const float*)d_in[1];
    const float* conv_w  = (const float*)d_in[2];
    const float* conv_b  = (const float*)d_in[3];
    const float* W_x     = (const float*)d_in[4];
    const float* W_dt    = (const float*)d_in[5];
    const float* dt_bias = (const float*)d_in[6];
    const float* A_log   = (const float*)d_in[7];
    const float* Dp      = (const float*)d_in[8];
    const float* W_out   = (const float*)d_in[9];
    float* out = (float*)d_out;

    // workspace layout (~220 MB)
    char* p = (char*)d_ws;
    auto alloc = [&](size_t bytes) {
        char* r = p;
        p += (bytes + 255) & ~(size_t)255;
        return r;
    };
    float* proj   = (float*)alloc((size_t)LC * 2 * I_DIM * 4);   // 64 MB
    float* xconv  = (float*)alloc((size_t)LC * I_DIM * 4);       // 32 MB
    float* ssm    = (float*)alloc((size_t)LC * 160 * 4);
    float* xtail  = (float*)alloc((size_t)2 * 3 * I_DIM * 4);    // double-buffered
    float* hstate = (float*)alloc((size_t)IN_DIM * 4);
    _Float16* WinPh  = (_Float16*)alloc((size_t)2 * I_DIM * H_DIM * 2);  // 32 MB
    _Float16* WinPl  = (_Float16*)alloc((size_t)2 * I_DIM * H_DIM * 2);
    _Float16* WoutPh = (_Float16*)alloc((size_t)H_DIM * I_DIM * 2);      // 16 MB
    _Float16* WoutPl = (_Float16*)alloc((size_t)H_DIM * I_DIM * 2);
    _Float16* WdtPh  = (_Float16*)alloc((size_t)I_DIM * R_DIM * 2);
    _Float16* WdtPl  = (_Float16*)alloc((size_t)I_DIM * R_DIM * 2);
    _Float16* WxPh   = (_Float16*)alloc((size_t)256 * I_DIM * 2);
    _Float16* WxPl   = (_Float16*)alloc((size_t)256 * I_DIM * 2);
    _Float16* hsPh   = (_Float16*)alloc((size_t)LC * H_DIM * 2);  // 8 MB per-chunk A panels
    _Float16* hsPl   = (_Float16*)alloc((size_t)LC * H_DIM * 2);

    const dim3 blk(256);
    const int NSSM = R_DIM + 2 * N_DIM;  // 160

    // ---- pack weights into panel format (once per launch) ----
    pack_bp<<<dim3(2 * I_DIM / 32, H_DIM / 32), dim3(128), 0, stream>>>(
        W_in, WinPh, WinPl, H_DIM, 2 * I_DIM);
    pack_bp<<<dim3(H_DIM / 32, I_DIM / 32), dim3(128), 0, stream>>>(
        W_out, WoutPh, WoutPl, I_DIM, H_DIM);
    pack_bp<<<dim3(I_DIM / 32, R_DIM / 32), dim3(128), 0, stream>>>(
        W_dt, WdtPh, WdtPl, R_DIM, I_DIM);
    pack_bp<<<dim3(NSSM / 32, I_DIM / 32), dim3(128), 0, stream>>>(
        W_x, WxPh, WxPl, I_DIM, NSSM);

    for (int c = 0; c < NCHUNK; ++c) {
        const int t0 = c * LC;
        const int first = (c == 0) ? 1 : 0;
        const float* hs_c = hs + (size_t)t0 * H_DIM;
        float* out_c = out + (size_t)t0 * H_DIM;
        float* aprod = out_c;                 // scan scratch in out region
        float* hend  = out_c + (size_t)SEG * IN_DIM;
        float* xtA = xtail + (size_t)(c & 1) * 3 * I_DIM;        // read
        float* xtB = xtail + (size_t)((c & 1) ^ 1) * 3 * I_DIM;  // write

        // 0) pack hs chunk into A panels (hi/lo)
        pack_ap<<<dim3(LC / 16, H_DIM / 128), blk, 0, stream>>>(
            hs_c, H_DIM, hsPh, hsPl, H_DIM);

        // 1) proj = hs_c @ W_in  (pure gl_lds both sides)
        gemm_p<0, 2, false><<<dim3(1024, 1), blk, 0, stream>>>(
            nullptr, 0, hsPh, hsPl, WinPh, WinPl, proj, 2 * I_DIM,
            H_DIM, 0, LC / 128, H_DIM, nullptr);

        // 2) xconv = silu(dwconv(x_pre) + b); saves tail to xtB
        conv_silu_kernel<<<dim3(1024), blk, 0, stream>>>(
            proj, xtA, xtB, conv_w, conv_b, xconv, first);

        // 3) ssm = xconv @ W_x  (split-K x8, atomics)
        zero_kernel<<<dim3((LC * NSSM + 255) / 256), blk, 0, stream>>>(ssm, LC * NSSM);
        gemm_p<0, 0, true><<<dim3(32, 8), blk, 0, stream>>>(
            xconv, I_DIM, nullptr, nullptr, WxPh, WxPl, ssm, NSSM,
            I_DIM, NSSM, LC / 128, I_DIM / 8, nullptr);

        // 4) delta = softplus(ssm[:, :R] @ W_dt + dt_bias) -> proj[:, :I]
        gemm_p<1, 0, false><<<dim3(512, 1), blk, 0, stream>>>(
            ssm, NSSM, nullptr, nullptr, WdtPh, WdtPl, proj, 2 * I_DIM,
            R_DIM, 0, LC / 128, R_DIM, dt_bias);

        // 5) segment-parallel scan; z packed u32 into proj's delta slot
        scan_part1<<<dim3(I_DIM / 128, SEG), blk, 0, stream>>>(
            proj, ssm, xconv, A_log, aprod, hend);
        scan_part2<<<dim3(IN_DIM / 256), blk, 0, stream>>>(
            aprod, hend, hstate, first);
        scan_part3<<<dim3(I_DIM / 128, SEG), blk, 0, stream>>>(
            proj, proj + I_DIM, ssm, xconv, (uint32_t*)proj, A_log, Dp, hend);

        // 6) out_c = z @ W_out  (A = packed z u32)
        gemm_p<0, 1, false><<<dim3(256, 1), blk, 0, stream>>>(
            proj, 2 * I_DIM, nullptr, nullptr, WoutPh, WoutPl, out_c, H_DIM,
            I_DIM, 0, LC / 128, I_DIM, nullptr);
    }
}

// Round 9
// 1496.008 us; speedup vs baseline: 3.4044x; 1.4787x over previous
//
#include <hip/hip_runtime.h>
#include <cmath>
#include <stdint.h>

#define H_DIM 2048
#define I_DIM 4096
#define N_DIM 16
#define R_DIM 128
#define K_CONV 4
#define L_DIM 8192
#define LC 2048                 // chunk length
#define NCHUNK (L_DIM / LC)
#define SEG 32                  // scan segments per chunk
#define TSEG (LC / SEG)         // 64 steps per segment
#define IN_DIM (I_DIM * N_DIM)  // 65536 recurrences

typedef _Float16 f16x8 __attribute__((ext_vector_type(8)));
typedef float    f32x4 __attribute__((ext_vector_type(4)));

// direct HBM->LDS, 16B per lane; LDS base must be wave-uniform (HW adds lane*16)
__device__ __forceinline__ void gl_lds(const _Float16* g, _Float16* lbase, int lane) {
#if __has_builtin(__builtin_amdgcn_global_load_lds)
    __builtin_amdgcn_global_load_lds(
        (const __attribute__((address_space(1))) void*)g,
        (__attribute__((address_space(3))) void*)lbase, 16, 0, 0);
#else
    *(f16x8*)&lbase[lane * 8] = *(const f16x8*)g;
#endif
}

// ---------------------------------------------------------------------------
// Panel-format split-f16 MFMA GEMM, double-buffered (2-phase pipeline).
//   C[M,N] (+)= A[M,K] @ B[K,N]
// B pre-split+packed panels [N/16][K/32][512]; staged via global_load_lds.
// A: AK=0 fp32 [M][K] reg-split | AK=1 u32 packed rows (hi16|lo16) | AK=2
//    pre-split panels staged via global_load_lds.
// ASPLIT: 1 = A split hi+lo (3 MFMA / pair), 0 = A hi only (2 MFMA / pair;
//    LDS 48 KB -> 3 blocks/CU). B (weights) is ALWAYS split.
// Block 128x128, BK=32, 4 waves (2x2), wave tile 64x64.
// EPI: 0 none; 1 softplus(x+bias[col]). Ncap>0 guards stores to col<Ncap.
// Split-K via blockIdx.y * kchunk (ATOMIC accumulate; zero C first).
// ---------------------------------------------------------------------------
template <int EPI, int AK, int ASPLIT, bool ATOMIC>
__global__ __launch_bounds__(256, ASPLIT ? 2 : 3) void gemm_p(
    const void* __restrict__ Av, int lda,
    const _Float16* __restrict__ Aph, const _Float16* __restrict__ Apl,
    const _Float16* __restrict__ Bph, const _Float16* __restrict__ Bpl,
    float* __restrict__ C, int ldc,
    int Kd, int Ncap, int gm, int kchunk,
    const float* __restrict__ bias)
{
    constexpr int NSLOT = ASPLIT ? 4 : 3;
    constexpr int S_AH = 0;
    constexpr int S_AL = ASPLIT ? 1 : 0;   // unused when !ASPLIT
    constexpr int S_BH = ASPLIT ? 2 : 1;
    constexpr int S_BL = ASPLIT ? 3 : 2;
    __shared__ __align__(16) _Float16 Sh[2][NSLOT][4096];

    const int tid = threadIdx.x;
    int bid = blockIdx.x;
    const int q = gridDim.x >> 3;        // grids are multiples of 8
    bid = (bid & 7) * q + (bid >> 3);    // bijective XCD swizzle
    const int m0 = (bid % gm) * 128;
    const int n0 = (bid / gm) * 128;

    const int kbeg = blockIdx.y * kchunk;
    const int kend = (kbeg + kchunk < Kd) ? (kbeg + kchunk) : Kd;

    const int w = tid >> 6, l = tid & 63;
    const int wm = w & 1, wn = w >> 1;
    const int lr = l & 15, lg = l >> 4;

    // reg-path A staging coords
    const int ar = tid >> 1, ah = tid & 1;
    const int aw0 = (ar >> 4) * 512 + (((ah * 2) * 16 + (ar & 15)) * 8);
    const int aw1 = aw0 + 128;

    const int KP = Kd >> 5;
    const int np0 = n0 >> 4;
    const int mp0 = m0 >> 4;

    f32x4 acc[4][4];
#pragma unroll
    for (int a = 0; a < 4; ++a)
#pragma unroll
        for (int b = 0; b < 4; ++b) acc[a][b] = (f32x4){0.f, 0.f, 0.f, 0.f};

    float    xf[16];
    uint32_t xu[16];
    f16x8 sah[2], sal[2];

    auto issueA = [&](int k0) {  // vm loads into raw regs (no cvt yet)
        if (AK == 0) {
            const float* Ap = (const float*)Av + (size_t)(m0 + ar) * lda + k0 + ah * 16;
            *(float4*)&xf[0]  = *(const float4*)(Ap + 0);
            *(float4*)&xf[4]  = *(const float4*)(Ap + 4);
            *(float4*)&xf[8]  = *(const float4*)(Ap + 8);
            *(float4*)&xf[12] = *(const float4*)(Ap + 12);
        } else if (AK == 1) {
            const uint32_t* Ap = (const uint32_t*)Av + (size_t)(m0 + ar) * lda + k0 + ah * 16;
            *(uint4*)&xu[0]  = *(const uint4*)(Ap + 0);
            *(uint4*)&xu[4]  = *(const uint4*)(Ap + 4);
            *(uint4*)&xu[8]  = *(const uint4*)(Ap + 8);
            *(uint4*)&xu[12] = *(const uint4*)(Ap + 12);
        }
    };
    auto cvtA = [&]() {
        if (AK == 0) {
#pragma unroll
            for (int c2 = 0; c2 < 2; ++c2)
#pragma unroll
                for (int j = 0; j < 8; ++j) {
                    const float xv = xf[c2 * 8 + j];
                    const _Float16 h = (_Float16)xv;
                    sah[c2][j] = h;
                    if (ASPLIT) sal[c2][j] = (_Float16)(xv - (float)h);
                }
        } else if (AK == 1) {
#pragma unroll
            for (int c2 = 0; c2 < 2; ++c2)
#pragma unroll
                for (int j = 0; j < 8; ++j) {
                    const uint32_t wv = xu[c2 * 8 + j];
                    sah[c2][j] = __builtin_bit_cast(_Float16, (unsigned short)(wv >> 16));
                    if (ASPLIT)
                        sal[c2][j] = __builtin_bit_cast(_Float16, (unsigned short)(wv & 0xffffu));
                }
        }
    };
    auto writeA = [&](int p) {
        *(f16x8*)&Sh[p][S_AH][aw0] = sah[0];
        *(f16x8*)&Sh[p][S_AH][aw1] = sah[1];
        if (ASPLIT) {
            *(f16x8*)&Sh[p][S_AL][aw0] = sal[0];
            *(f16x8*)&Sh[p][S_AL][aw1] = sal[1];
        }
    };
    auto stageGL = [&](int k0, int p) {  // gl_lds staging (B always; A if AK==2)
        const int kp = k0 >> 5;
        if (AK == 2) {
#pragma unroll
            for (int s = 0; s < 2; ++s) {
                const int st = w + s * 4;
                const size_t ga = ((size_t)(mp0 + st) * KP + kp) * 512 + (size_t)l * 8;
                gl_lds(Aph + ga, &Sh[p][S_AH][st * 512], l);
                if (ASPLIT) gl_lds(Apl + ga, &Sh[p][S_AL][st * 512], l);
            }
        }
#pragma unroll
        for (int qq = 0; qq < 2; ++qq) {
            const int st = 2 * w + qq;
            const size_t go = ((size_t)(np0 + st) * KP + kp) * 512 + (size_t)l * 8;
            gl_lds(Bph + go, &Sh[p][S_BH][st * 512], l);
            gl_lds(Bpl + go, &Sh[p][S_BL][st * 512], l);
        }
    };

    // prologue: stage tile 0 into buf 0
    if (AK != 2) { issueA(kbeg); cvtA(); writeA(0); }
    stageGL(kbeg, 0);
    __syncthreads();

    int p = 0;
    for (int k0 = kbeg; k0 < kend; k0 += 32) {
        const bool more = (k0 + 32 < kend);
        if (more) {                      // issue next-tile staging FIRST
            if (AK != 2) issueA(k0 + 32);
            stageGL(k0 + 32, p ^ 1);
        }

        f16x8 fah[4], fal[4], fbh[4], fbl[4];
#pragma unroll
        for (int t = 0; t < 4; ++t) {
            fah[t] = *(const f16x8*)&Sh[p][S_AH][(wm * 4 + t) * 512 + l * 8];
            if (ASPLIT) fal[t] = *(const f16x8*)&Sh[p][S_AL][(wm * 4 + t) * 512 + l * 8];
            fbh[t] = *(const f16x8*)&Sh[p][S_BH][(wn * 4 + t) * 512 + l * 8];
            fbl[t] = *(const f16x8*)&Sh[p][S_BL][(wn * 4 + t) * 512 + l * 8];
        }
        __builtin_amdgcn_s_setprio(1);
#pragma unroll
        for (int mt = 0; mt < 4; ++mt)
#pragma unroll
            for (int nt = 0; nt < 4; ++nt) {
                f32x4& a = acc[mt][nt];
                a = __builtin_amdgcn_mfma_f32_16x16x32_f16(fah[mt], fbh[nt], a, 0, 0, 0);
                a = __builtin_amdgcn_mfma_f32_16x16x32_f16(fah[mt], fbl[nt], a, 0, 0, 0);
                if (ASPLIT)
                    a = __builtin_amdgcn_mfma_f32_16x16x32_f16(fal[mt], fbh[nt], a, 0, 0, 0);
            }
        __builtin_amdgcn_s_setprio(0);

        if (more && AK != 2) { cvtA(); writeA(p ^ 1); }  // late write (vm wait here)
        __syncthreads();   // vmcnt(0)+lgkmcnt(0) drain — hidden by MFMA above
        p ^= 1;
    }

    // epilogue
#pragma unroll
    for (int mt = 0; mt < 4; ++mt) {
        const int row = m0 + wm * 64 + mt * 16 + lg * 4;
#pragma unroll
        for (int nt = 0; nt < 4; ++nt) {
            const int col = n0 + wn * 64 + nt * 16 + lr;
            if (Ncap == 0 || col < Ncap) {
#pragma unroll
                for (int j = 0; j < 4; ++j) {
                    float v = acc[mt][nt][j];
                    if (EPI == 1) {
                        v += bias[col];
                        v = (v > 20.f) ? v : __logf(1.f + __expf(v));
                    }
                    if (ATOMIC) atomicAdd(&C[(size_t)(row + j) * ldc + col], v);
                    else        C[(size_t)(row + j) * ldc + col] = v;
                }
            }
        }
    }
}

// ---------------------------------------------------------------------------
// Pack W [Kd][Nd] fp32 -> hi/lo f16 B-panels [Nd/16][Kd/32][512].
// ---------------------------------------------------------------------------
__global__ __launch_bounds__(128) void pack_bp(
    const float* __restrict__ W, _Float16* __restrict__ Ph,
    _Float16* __restrict__ Pl, int Kd, int Nd)
{
    __shared__ float t[32][33];
    const int tid = threadIdx.x;
    const int n0 = blockIdx.x * 32, k0 = blockIdx.y * 32;
#pragma unroll
    for (int h = 0; h < 2; ++h) {
        const int qd = tid + h * 128;
        const int kk = qd >> 3, qq = qd & 7;
        *(float4*)&t[kk][qq * 4] = *(const float4*)(W + (size_t)(k0 + kk) * Nd + n0 + qq * 4);
    }
    __syncthreads();
    const int c = tid >> 5, nn = tid & 31;
    const int np = (n0 + nn) >> 4;
    const int r  = nn & 15;
    const int kp = k0 >> 5;
    const size_t base = ((size_t)np * (Kd >> 5) + kp) * 512 + (c * 16 + r) * 8;
    f16x8 vh, vl;
#pragma unroll
    for (int j = 0; j < 8; ++j) {
        const float v = t[c * 8 + j][nn];
        const _Float16 h = (_Float16)v;
        vh[j] = h;
        vl[j] = (_Float16)(v - (float)h);
    }
    *(f16x8*)&Ph[base] = vh;
    *(f16x8*)&Pl[base] = vl;
}

// ---------------------------------------------------------------------------
// Pack A fp32 [M][K] row-major -> hi f16 A-panels [M/16][K/32][512] (hi only).
// ---------------------------------------------------------------------------
__global__ __launch_bounds__(256) void pack_ap(
    const float* __restrict__ A, int lda,
    _Float16* __restrict__ Ph, int Kd)
{
    const int tid = threadIdx.x;
    const int mp = blockIdx.x;
    const int r = tid >> 4, c8 = tid & 15;
    const int k0 = blockIdx.y * 128 + c8 * 8;
    const float* Ap = A + (size_t)(mp * 16 + r) * lda + k0;
    const float4 v0 = *(const float4*)Ap;
    const float4 v1 = *(const float4*)(Ap + 4);
    const float x[8] = {v0.x, v0.y, v0.z, v0.w, v1.x, v1.y, v1.z, v1.w};
    f16x8 vh;
#pragma unroll
    for (int j = 0; j < 8; ++j) vh[j] = (_Float16)x[j];
    const int kp = k0 >> 5;
    const int c  = (k0 >> 3) & 3;
    const size_t base = ((size_t)mp * (Kd >> 5) + kp) * 512 + (c * 16 + r) * 8;
    *(f16x8*)&Ph[base] = vh;
}

__global__ __launch_bounds__(256) void zero_kernel(float* __restrict__ p, int n)
{
    const int idx = blockIdx.x * 256 + threadIdx.x;
    if (idx < n) p[idx] = 0.f;
}

// ---------------------------------------------------------------------------
// Causal depthwise conv (K=4) + bias + silu, vectorized (4ch x 8t / thread).
// ---------------------------------------------------------------------------
__global__ __launch_bounds__(256) void conv_silu_kernel(
    const float* __restrict__ proj,      // x-half, ld 2I
    const float* __restrict__ xtail_in,  // 3 x I
    float* __restrict__ xtail_out,       // 3 x I
    const float* __restrict__ w,         // I x 4
    const float* __restrict__ b,         // I
    float* __restrict__ xconv,           // LC x I
    int first)
{
    const int gid = blockIdx.x * 256 + threadIdx.x;
    const int i4 = gid & (I_DIM / 4 - 1);
    const int t8 = gid >> 10;
    const int i = i4 * 4;
    const int tt0 = t8 * 8;

    const float4 w0 = *(const float4*)(w + (size_t)(i + 0) * 4);
    const float4 w1 = *(const float4*)(w + (size_t)(i + 1) * 4);
    const float4 w2 = *(const float4*)(w + (size_t)(i + 2) * 4);
    const float4 w3 = *(const float4*)(w + (size_t)(i + 3) * 4);
    const float4 bb = *(const float4*)(b + i);

    float4 r[11];
    if (tt0 >= 3) {
#pragma unroll
        for (int s = 0; s < 11; ++s)
            r[s] = *(const float4*)(proj + (size_t)(tt0 - 3 + s) * (2 * I_DIM) + i);
    } else {  // tt0 == 0
#pragma unroll
        for (int s = 0; s < 3; ++s)
            r[s] = first ? make_float4(0.f, 0.f, 0.f, 0.f)
                         : *(const float4*)(xtail_in + (size_t)s * I_DIM + i);
#pragma unroll
        for (int s = 3; s < 11; ++s)
            r[s] = *(const float4*)(proj + (size_t)(tt0 - 3 + s) * (2 * I_DIM) + i);
    }

#pragma unroll
    for (int s = 0; s < 8; ++s) {
        float4 y = bb;
        y.x = fmaf(w0.x, r[s].x, y.x); y.x = fmaf(w0.y, r[s+1].x, y.x);
        y.x = fmaf(w0.z, r[s+2].x, y.x); y.x = fmaf(w0.w, r[s+3].x, y.x);
        y.y = fmaf(w1.x, r[s].y, y.y); y.y = fmaf(w1.y, r[s+1].y, y.y);
        y.y = fmaf(w1.z, r[s+2].y, y.y); y.y = fmaf(w1.w, r[s+3].y, y.y);
        y.z = fmaf(w2.x, r[s].z, y.z); y.z = fmaf(w2.y, r[s+1].z, y.z);
        y.z = fmaf(w2.z, r[s+2].z, y.z); y.z = fmaf(w2.w, r[s+3].z, y.z);
        y.w = fmaf(w3.x, r[s].w, y.w); y.w = fmaf(w3.y, r[s+1].w, y.w);
        y.w = fmaf(w3.z, r[s+2].w, y.w); y.w = fmaf(w3.w, r[s+3].w, y.w);
        y.x = y.x / (1.f + __expf(-y.x));
        y.y = y.y / (1.f + __expf(-y.y));
        y.z = y.z / (1.f + __expf(-y.z));
        y.w = y.w / (1.f + __expf(-y.w));
        *(float4*)(xconv + (size_t)(tt0 + s) * I_DIM + i) = y;
    }

    if (tt0 == LC - 8) {   // fused tail save (rows LC-3..LC-1 = r[8..10])
#pragma unroll
        for (int qq = 0; qq < 3; ++qq)
            *(float4*)(xtail_out + (size_t)qq * I_DIM + i) = r[8 + qq];
    }
}

// ---------------------------------------------------------------------------
// Segment-parallel scan (fast-exp).
// ---------------------------------------------------------------------------
__global__ __launch_bounds__(256) void scan_part1(
    const float* __restrict__ delta,
    const float* __restrict__ ssm,
    const float* __restrict__ xc,
    const float* __restrict__ A_log,
    float* __restrict__ aprod,
    float* __restrict__ hend)
{
    __shared__ float Bs[TSEG][16];
    const int tid = threadIdx.x;
    const int i = blockIdx.x * 128 + (tid >> 1);
    const int half = tid & 1;
    const int seg = blockIdx.y;
    const int t0 = seg * TSEG;

    {
        const int tt = tid >> 2, c = (tid & 3) * 4;
        *(float4*)&Bs[tt][c] = *(const float4*)&ssm[(size_t)(t0 + tt) * 160 + 128 + c];
    }
    __syncthreads();

    float Ai[8], h[8], ap[8];
    {
        const float4 a0 = *(const float4*)&A_log[(size_t)i * 16 + half * 8];
        const float4 a1 = *(const float4*)&A_log[(size_t)i * 16 + half * 8 + 4];
        const float al[8] = {a0.x, a0.y, a0.z, a0.w, a1.x, a1.y, a1.z, a1.w};
#pragma unroll
        for (int n = 0; n < 8; ++n) { Ai[n] = -expf(al[n]); h[n] = 0.f; ap[n] = 1.f; }
    }

    float d = delta[(size_t)t0 * (2 * I_DIM) + i];
    float u = xc[(size_t)t0 * I_DIM + i];
    for (int t = 0; t < TSEG; ++t) {
        float dn = 0.f, un = 0.f;
        if (t + 1 < TSEG) {
            dn = delta[(size_t)(t0 + t + 1) * (2 * I_DIM) + i];
            un = xc[(size_t)(t0 + t + 1) * I_DIM + i];
        }
        const float du = d * u;
#pragma unroll
        for (int n = 0; n < 8; ++n) {
            const float a = __expf(d * Ai[n]);
            h[n] = fmaf(h[n], a, du * Bs[t][half * 8 + n]);
            ap[n] *= a;
        }
        d = dn; u = un;
    }

    const size_t base = (size_t)seg * IN_DIM + (size_t)i * 16 + half * 8;
#pragma unroll
    for (int qq = 0; qq < 2; ++qq) {
        float4 va = {ap[qq * 4 + 0], ap[qq * 4 + 1], ap[qq * 4 + 2], ap[qq * 4 + 3]};
        float4 vh = {h[qq * 4 + 0], h[qq * 4 + 1], h[qq * 4 + 2], h[qq * 4 + 3]};
        *(float4*)&aprod[base + qq * 4] = va;
        *(float4*)&hend[base + qq * 4]  = vh;
    }
}

__global__ __launch_bounds__(256) void scan_part2(
    const float* __restrict__ aprod,
    float* __restrict__ hend,
    float* __restrict__ hstate,
    int first)
{
    const int gid = blockIdx.x * 256 + threadIdx.x;
    float h = first ? 0.f : hstate[gid];
    for (int s = 0; s < SEG; ++s) {
        const int idx = s * IN_DIM + gid;
        const float ap = aprod[idx];
        const float he = hend[idx];
        hend[idx] = h;
        h = fmaf(ap, h, he);
    }
    hstate[gid] = h;
}

__global__ __launch_bounds__(256) void scan_part3(
    const float* __restrict__ delta,
    const float* __restrict__ gate,
    const float* __restrict__ ssm,
    const float* __restrict__ xc,
    uint32_t* __restrict__ zout,
    const float* __restrict__ A_log,
    const float* __restrict__ Dp,
    const float* __restrict__ hstart)
{
    __shared__ float BCs[TSEG][32];
    const int tid = threadIdx.x;
    const int i = blockIdx.x * 128 + (tid >> 1);
    const int half = tid & 1;
    const int seg = blockIdx.y;
    const int t0 = seg * TSEG;

    {
        const int tt = tid >> 2, c = (tid & 3) * 8;
        *(float4*)&BCs[tt][c]     = *(const float4*)&ssm[(size_t)(t0 + tt) * 160 + 128 + c];
        *(float4*)&BCs[tt][c + 4] = *(const float4*)&ssm[(size_t)(t0 + tt) * 160 + 132 + c];
    }
    __syncthreads();

    float Ai[8], h[8];
    {
        const float4 a0 = *(const float4*)&A_log[(size_t)i * 16 + half * 8];
        const float4 a1 = *(const float4*)&A_log[(size_t)i * 16 + half * 8 + 4];
        const float al[8] = {a0.x, a0.y, a0.z, a0.w, a1.x, a1.y, a1.z, a1.w};
#pragma unroll
        for (int n = 0; n < 8; ++n) Ai[n] = -expf(al[n]);
        const size_t base = (size_t)seg * IN_DIM + (size_t)i * 16 + half * 8;
        const float4 h0 = *(const float4*)&hstart[base];
        const float4 h1 = *(const float4*)&hstart[base + 4];
        h[0] = h0.x; h[1] = h0.y; h[2] = h0.z; h[3] = h0.w;
        h[4] = h1.x; h[5] = h1.y; h[6] = h1.z; h[7] = h1.w;
    }
    const float Di = Dp[i];

    float d = delta[(size_t)t0 * (2 * I_DIM) + i];
    float u = xc[(size_t)t0 * I_DIM + i];
    float g = gate[(size_t)t0 * (2 * I_DIM) + i];
    for (int t = 0; t < TSEG; ++t) {
        float dn = 0.f, un = 0.f, gn = 0.f;
        if (t + 1 < TSEG) {
            dn = delta[(size_t)(t0 + t + 1) * (2 * I_DIM) + i];
            un = xc[(size_t)(t0 + t + 1) * I_DIM + i];
            gn = gate[(size_t)(t0 + t + 1) * (2 * I_DIM) + i];
        }
        const float du = d * u;
        float y = 0.f;
#pragma unroll
        for (int n = 0; n < 8; ++n) {
            const float a = __expf(d * Ai[n]);
            h[n] = fmaf(h[n], a, du * BCs[t][half * 8 + n]);
            y = fmaf(h[n], BCs[t][16 + half * 8 + n], y);
        }
        y += __shfl_xor(y, 1);
        if (half == 0) {
            const float sg = g / (1.f + __expf(-g));
            const float zv = (y + u * Di) * sg;
            const _Float16 zh = (_Float16)zv;
            const _Float16 zl = (_Float16)(zv - (float)zh);
            const uint32_t pz =
                ((uint32_t)__builtin_bit_cast(unsigned short, zh) << 16) |
                (uint32_t)__builtin_bit_cast(unsigned short, zl);
            zout[(size_t)(t0 + t) * (2 * I_DIM) + i] = pz;
        }
        d = dn; u = un; g = gn;
    }
}

// ---------------------------------------------------------------------------
extern "C" void kernel_launch(void* const* d_in, const int* in_sizes, int n_in,
                              void* d_out, int out_size, void* d_ws, size_t ws_size,
                              hipStream_t stream)
{
    const float* hs      = (const float*)d_in[0];
    const float* W_in    = (const float*)d_in[1];
    const float* conv_w  = (const float*)d_in[2];
    const float* conv_b  = (const float*)d_in[3];
    const float* W_x     = (const float*)d_in[4];
    const float* W_dt    = (const float*)d_in[5];
    const float* dt_bias = (const float*)d_in[6];
    const float* A_log   = (const float*)d_in[7];
    const float* Dp      = (const float*)d_in[8];
    const float* W_out   = (const float*)d_in[9];
    float* out = (float*)d_out;

    // workspace layout (~210 MB)
    char* p = (char*)d_ws;
    auto alloc = [&](size_t bytes) {
        char* r = p;
        p += (bytes + 255) & ~(size_t)255;
        return r;
    };
    float* proj   = (float*)alloc((size_t)LC * 2 * I_DIM * 4);   // 64 MB
    float* xconv  = (float*)alloc((size_t)LC * I_DIM * 4);       // 32 MB
    float* ssm    = (float*)alloc((size_t)LC * 160 * 4);
    float* xtail  = (float*)alloc((size_t)2 * 3 * I_DIM * 4);    // double-buffered
    float* hstate = (float*)alloc((size_t)IN_DIM * 4);
    _Float16* WinPh  = (_Float16*)alloc((size_t)2 * I_DIM * H_DIM * 2);  // 32 MB
    _Float16* WinPl  = (_Float16*)alloc((size_t)2 * I_DIM * H_DIM * 2);
    _Float16* WoutPh = (_Float16*)alloc((size_t)H_DIM * I_DIM * 2);      // 16 MB
    _Float16* WoutPl = (_Float16*)alloc((size_t)H_DIM * I_DIM * 2);
    _Float16* WdtPh  = (_Float16*)alloc((size_t)I_DIM * R_DIM * 2);
    _Float16* WdtPl  = (_Float16*)alloc((size_t)I_DIM * R_DIM * 2);
    _Float16* WxPh   = (_Float16*)alloc((size_t)256 * I_DIM * 2);
    _Float16* WxPl   = (_Float16*)alloc((size_t)256 * I_DIM * 2);
    _Float16* hsPh   = (_Float16*)alloc((size_t)LC * H_DIM * 2);  // 8 MB A panels (hi)

    const dim3 blk(256);
    const int NSSM = R_DIM + 2 * N_DIM;  // 160

    // ---- pack weights into panel format (once per launch) ----
    pack_bp<<<dim3(2 * I_DIM / 32, H_DIM / 32), dim3(128), 0, stream>>>(
        W_in, WinPh, WinPl, H_DIM, 2 * I_DIM);
    pack_bp<<<dim3(H_DIM / 32, I_DIM / 32), dim3(128), 0, stream>>>(
        W_out, WoutPh, WoutPl, I_DIM, H_DIM);
    pack_bp<<<dim3(I_DIM / 32, R_DIM / 32), dim3(128), 0, stream>>>(
        W_dt, WdtPh, WdtPl, R_DIM, I_DIM);
    pack_bp<<<dim3(NSSM / 32, I_DIM / 32), dim3(128), 0, stream>>>(
        W_x, WxPh, WxPl, I_DIM, NSSM);

    for (int c = 0; c < NCHUNK; ++c) {
        const int t0 = c * LC;
        const int first = (c == 0) ? 1 : 0;
        const float* hs_c = hs + (size_t)t0 * H_DIM;
        float* out_c = out + (size_t)t0 * H_DIM;
        float* aprod = out_c;                 // scan scratch in out region
        float* hend  = out_c + (size_t)SEG * IN_DIM;
        float* xtA = xtail + (size_t)(c & 1) * 3 * I_DIM;        // read
        float* xtB = xtail + (size_t)((c & 1) ^ 1) * 3 * I_DIM;  // write

        // 0) pack hs chunk into A panels (hi only)
        pack_ap<<<dim3(LC / 16, H_DIM / 128), blk, 0, stream>>>(
            hs_c, H_DIM, hsPh, H_DIM);

        // 1) proj = hs_c @ W_in  (pure gl_lds; A hi-only)
        gemm_p<0, 2, 0, false><<<dim3(1024, 1), blk, 0, stream>>>(
            nullptr, 0, hsPh, nullptr, WinPh, WinPl, proj, 2 * I_DIM,
            H_DIM, 0, LC / 128, H_DIM, nullptr);

        // 2) xconv = silu(dwconv(x_pre) + b); saves tail to xtB
        conv_silu_kernel<<<dim3(1024), blk, 0, stream>>>(
            proj, xtA, xtB, conv_w, conv_b, xconv, first);

        // 3) ssm = xconv @ W_x  (full split, split-K x8, atomics)
        zero_kernel<<<dim3((LC * NSSM + 255) / 256), blk, 0, stream>>>(ssm, LC * NSSM);
        gemm_p<0, 0, 1, true><<<dim3(32, 8), blk, 0, stream>>>(
            xconv, I_DIM, nullptr, nullptr, WxPh, WxPl, ssm, NSSM,
            I_DIM, NSSM, LC / 128, I_DIM / 8, nullptr);

        // 4) delta = softplus(ssm[:, :R] @ W_dt + dt_bias) -> proj[:, :I]
        gemm_p<1, 0, 1, false><<<dim3(512, 1), blk, 0, stream>>>(
            ssm, NSSM, nullptr, nullptr, WdtPh, WdtPl, proj, 2 * I_DIM,
            R_DIM, 0, LC / 128, R_DIM, dt_bias);

        // 5) segment-parallel scan; z packed u32 into proj's delta slot
        scan_part1<<<dim3(I_DIM / 128, SEG), blk, 0, stream>>>(
            proj, ssm, xconv, A_log, aprod, hend);
        scan_part2<<<dim3(IN_DIM / 256), blk, 0, stream>>>(
            aprod, hend, hstate, first);
        scan_part3<<<dim3(I_DIM / 128, SEG), blk, 0, stream>>>(
            proj, proj + I_DIM, ssm, xconv, (uint32_t*)proj, A_log, Dp, hend);

        // 6) out_c = z @ W_out  (A hi-only; split-K x2, atomics)
        zero_kernel<<<dim3((LC * H_DIM + 255) / 256), blk, 0, stream>>>(
            out_c, LC * H_DIM);
        gemm_p<0, 1, 0, true><<<dim3(256, 2), blk, 0, stream>>>(
            proj, 2 * I_DIM, nullptr, nullptr, WoutPh, WoutPl, out_c, H_DIM,
            I_DIM, 0, LC / 128, I_DIM / 2, nullptr);
    }
}

// Round 10
// 1467.454 us; speedup vs baseline: 3.4706x; 1.0195x over previous
//
#include <hip/hip_runtime.h>
#include <cmath>
#include <stdint.h>

#define H_DIM 2048
#define I_DIM 4096
#define N_DIM 16
#define R_DIM 128
#define K_CONV 4
#define L_DIM 8192
#define LC 2048                 // chunk length
#define NCHUNK (L_DIM / LC)
#define SEG 32                  // scan segments per chunk
#define TSEG (LC / SEG)         // 64 steps per segment
#define IN_DIM (I_DIM * N_DIM)  // 65536 recurrences

typedef _Float16 f16x8 __attribute__((ext_vector_type(8)));
typedef float    f32x4 __attribute__((ext_vector_type(4)));

// direct HBM->LDS, 16B per lane; LDS base must be wave-uniform (HW adds lane*16)
__device__ __forceinline__ void gl_lds(const _Float16* g, _Float16* lbase, int lane) {
#if __has_builtin(__builtin_amdgcn_global_load_lds)
    __builtin_amdgcn_global_load_lds(
        (const __attribute__((address_space(1))) void*)g,
        (__attribute__((address_space(3))) void*)lbase, 16, 0, 0);
#else
    *(f16x8*)&lbase[lane * 8] = *(const f16x8*)g;
#endif
}

// ---------------------------------------------------------------------------
// Panel-format split-f16 MFMA GEMM.
// AK=2: BOTH A and B pre-packed panels, pure global_load_lds staging with a
//   3-buffer counted-vmcnt pipeline (stage k+2 in flight across barriers).
//   6 gl_lds/thread/iter -> steady-state s_waitcnt vmcnt(12).
// AK=0/1: A reg-staged (fp32 split / u32-hi), 2-buffer, __syncthreads.
// ASPLIT: 1 = A hi+lo (3 MFMA/pair), 0 = A hi only (2 MFMA/pair).
// EPI: 0 none; 1 softplus(x+bias[col]). Ncap>0 guards stores to col<Ncap.
// Split-K via blockIdx.y * kchunk (ATOMIC accumulate; zero C first).
// ---------------------------------------------------------------------------
template <int EPI, int AK, int ASPLIT, bool ATOMIC>
__global__ __launch_bounds__(256, (AK == 2) ? 2 : (ASPLIT ? 2 : 3)) void gemm_p(
    const void* __restrict__ Av, int lda,
    const _Float16* __restrict__ Aph, const _Float16* __restrict__ Apl,
    const _Float16* __restrict__ Bph, const _Float16* __restrict__ Bpl,
    float* __restrict__ C, int ldc,
    int Kd, int Ncap, int gm, int kchunk,
    const float* __restrict__ bias)
{
    constexpr int NBUF  = (AK == 2) ? 3 : 2;
    constexpr int NSLOT = ASPLIT ? 4 : 3;
    constexpr int S_AH = 0;
    constexpr int S_AL = ASPLIT ? 1 : 0;
    constexpr int S_BH = ASPLIT ? 2 : 1;
    constexpr int S_BL = ASPLIT ? 3 : 2;
    __shared__ __align__(16) _Float16 Sh[NBUF][NSLOT][4096];

    const int tid = threadIdx.x;
    int bid = blockIdx.x;
    const int q = gridDim.x >> 3;        // grids are multiples of 8
    bid = (bid & 7) * q + (bid >> 3);    // bijective XCD swizzle
    const int m0 = (bid % gm) * 128;
    const int n0 = (bid / gm) * 128;

    const int kbeg = blockIdx.y * kchunk;
    const int kend = (kbeg + kchunk < Kd) ? (kbeg + kchunk) : Kd;

    const int w = tid >> 6, l = tid & 63;
    const int wm = w & 1, wn = w >> 1;
    const int lr = l & 15, lg = l >> 4;

    // reg-path A staging coords
    const int ar = tid >> 1, ah = tid & 1;
    const int aw0 = (ar >> 4) * 512 + (((ah * 2) * 16 + (ar & 15)) * 8);
    const int aw1 = aw0 + 128;

    const int KP = Kd >> 5;
    const int np0 = n0 >> 4;
    const int mp0 = m0 >> 4;

    f32x4 acc[4][4];
#pragma unroll
    for (int a = 0; a < 4; ++a)
#pragma unroll
        for (int b = 0; b < 4; ++b) acc[a][b] = (f32x4){0.f, 0.f, 0.f, 0.f};

    float    xf[16];
    uint32_t xu[16];
    f16x8 sah[2], sal[2];

    auto issueA = [&](int k0) {
        if (AK == 0) {
            const float* Ap = (const float*)Av + (size_t)(m0 + ar) * lda + k0 + ah * 16;
            *(float4*)&xf[0]  = *(const float4*)(Ap + 0);
            *(float4*)&xf[4]  = *(const float4*)(Ap + 4);
            *(float4*)&xf[8]  = *(const float4*)(Ap + 8);
            *(float4*)&xf[12] = *(const float4*)(Ap + 12);
        } else if (AK == 1) {
            const uint32_t* Ap = (const uint32_t*)Av + (size_t)(m0 + ar) * lda + k0 + ah * 16;
            *(uint4*)&xu[0]  = *(const uint4*)(Ap + 0);
            *(uint4*)&xu[4]  = *(const uint4*)(Ap + 4);
            *(uint4*)&xu[8]  = *(const uint4*)(Ap + 8);
            *(uint4*)&xu[12] = *(const uint4*)(Ap + 12);
        }
    };
    auto cvtA = [&]() {
        if (AK == 0) {
#pragma unroll
            for (int c2 = 0; c2 < 2; ++c2)
#pragma unroll
                for (int j = 0; j < 8; ++j) {
                    const float xv = xf[c2 * 8 + j];
                    const _Float16 h = (_Float16)xv;
                    sah[c2][j] = h;
                    if (ASPLIT) sal[c2][j] = (_Float16)(xv - (float)h);
                }
        } else if (AK == 1) {
#pragma unroll
            for (int c2 = 0; c2 < 2; ++c2)
#pragma unroll
                for (int j = 0; j < 8; ++j) {
                    const uint32_t wv = xu[c2 * 8 + j];
                    sah[c2][j] = __builtin_bit_cast(_Float16, (unsigned short)(wv >> 16));
                    if (ASPLIT)
                        sal[c2][j] = __builtin_bit_cast(_Float16, (unsigned short)(wv & 0xffffu));
                }
        }
    };
    auto writeA = [&](int p) {
        *(f16x8*)&Sh[p][S_AH][aw0] = sah[0];
        *(f16x8*)&Sh[p][S_AH][aw1] = sah[1];
        if (ASPLIT) {
            *(f16x8*)&Sh[p][S_AL][aw0] = sal[0];
            *(f16x8*)&Sh[p][S_AL][aw1] = sal[1];
        }
    };
    auto stageGL = [&](int k0, int p) {
        const int kp = k0 >> 5;
        if (AK == 2) {
#pragma unroll
            for (int s = 0; s < 2; ++s) {
                const int st = w + s * 4;
                const size_t ga = ((size_t)(mp0 + st) * KP + kp) * 512 + (size_t)l * 8;
                gl_lds(Aph + ga, &Sh[p][S_AH][st * 512], l);
            }
        }
#pragma unroll
        for (int qq = 0; qq < 2; ++qq) {
            const int st = 2 * w + qq;
            const size_t go = ((size_t)(np0 + st) * KP + kp) * 512 + (size_t)l * 8;
            gl_lds(Bph + go, &Sh[p][S_BH][st * 512], l);
            gl_lds(Bpl + go, &Sh[p][S_BL][st * 512], l);
        }
    };
    auto domfma = [&](int b) {
        f16x8 fah[4], fal[4], fbh[4], fbl[4];
#pragma unroll
        for (int t = 0; t < 4; ++t) {
            fah[t] = *(const f16x8*)&Sh[b][S_AH][(wm * 4 + t) * 512 + l * 8];
            if (ASPLIT) fal[t] = *(const f16x8*)&Sh[b][S_AL][(wm * 4 + t) * 512 + l * 8];
            fbh[t] = *(const f16x8*)&Sh[b][S_BH][(wn * 4 + t) * 512 + l * 8];
            fbl[t] = *(const f16x8*)&Sh[b][S_BL][(wn * 4 + t) * 512 + l * 8];
        }
        __builtin_amdgcn_s_setprio(1);
#pragma unroll
        for (int mt = 0; mt < 4; ++mt)
#pragma unroll
            for (int nt = 0; nt < 4; ++nt) {
                f32x4& a = acc[mt][nt];
                a = __builtin_amdgcn_mfma_f32_16x16x32_f16(fah[mt], fbh[nt], a, 0, 0, 0);
                a = __builtin_amdgcn_mfma_f32_16x16x32_f16(fah[mt], fbl[nt], a, 0, 0, 0);
                if (ASPLIT)
                    a = __builtin_amdgcn_mfma_f32_16x16x32_f16(fal[mt], fbh[nt], a, 0, 0, 0);
            }
        __builtin_amdgcn_s_setprio(0);
    };

    if constexpr (AK == 2) {
        // ---- 3-buffer counted-vmcnt pipeline (KT >= 3 required) ----
        const int KT = (kend - kbeg) >> 5;
        stageGL(kbeg, 0);            // 6 vm
        stageGL(kbeg + 32, 1);       // 12 vm in flight
        for (int k = 0; k + 2 < KT; ++k) {
            stageGL(kbeg + (k + 2) * 32, (k + 2) % 3);   // 18 in flight
            asm volatile("s_waitcnt vmcnt(12)" ::: "memory");  // stage(k) landed
            __builtin_amdgcn_s_barrier();
            __builtin_amdgcn_sched_barrier(0);
            domfma(k % 3);
            __builtin_amdgcn_s_barrier();  // reads of buf k done before restage
        }
        asm volatile("s_waitcnt vmcnt(6)" ::: "memory");
        __builtin_amdgcn_s_barrier();
        __builtin_amdgcn_sched_barrier(0);
        domfma((KT - 2) % 3);
        __builtin_amdgcn_s_barrier();
        asm volatile("s_waitcnt vmcnt(0)" ::: "memory");
        __builtin_amdgcn_s_barrier();
        __builtin_amdgcn_sched_barrier(0);
        domfma((KT - 1) % 3);
    } else {
        // ---- 2-buffer reg-staged pipeline ----
        issueA(kbeg); cvtA(); writeA(0);
        stageGL(kbeg, 0);
        __syncthreads();
        int p = 0;
        for (int k0 = kbeg; k0 < kend; k0 += 32) {
            const bool more = (k0 + 32 < kend);
            if (more) {
                issueA(k0 + 32);
                stageGL(k0 + 32, p ^ 1);
            }
            domfma(p);
            if (more) { cvtA(); writeA(p ^ 1); }
            __syncthreads();
            p ^= 1;
        }
    }

    // epilogue
#pragma unroll
    for (int mt = 0; mt < 4; ++mt) {
        const int row = m0 + wm * 64 + mt * 16 + lg * 4;
#pragma unroll
        for (int nt = 0; nt < 4; ++nt) {
            const int col = n0 + wn * 64 + nt * 16 + lr;
            if (Ncap == 0 || col < Ncap) {
#pragma unroll
                for (int j = 0; j < 4; ++j) {
                    float v = acc[mt][nt][j];
                    if (EPI == 1) {
                        v += bias[col];
                        v = (v > 20.f) ? v : __logf(1.f + __expf(v));
                    }
                    if (ATOMIC) atomicAdd(&C[(size_t)(row + j) * ldc + col], v);
                    else        C[(size_t)(row + j) * ldc + col] = v;
                }
            }
        }
    }
}

// ---------------------------------------------------------------------------
// Pack W [Kd][Nd] fp32 -> hi/lo f16 B-panels [Nd/16][Kd/32][512].
// ---------------------------------------------------------------------------
__global__ __launch_bounds__(128) void pack_bp(
    const float* __restrict__ W, _Float16* __restrict__ Ph,
    _Float16* __restrict__ Pl, int Kd, int Nd)
{
    __shared__ float t[32][33];
    const int tid = threadIdx.x;
    const int n0 = blockIdx.x * 32, k0 = blockIdx.y * 32;
#pragma unroll
    for (int h = 0; h < 2; ++h) {
        const int qd = tid + h * 128;
        const int kk = qd >> 3, qq = qd & 7;
        *(float4*)&t[kk][qq * 4] = *(const float4*)(W + (size_t)(k0 + kk) * Nd + n0 + qq * 4);
    }
    __syncthreads();
    const int c = tid >> 5, nn = tid & 31;
    const int np = (n0 + nn) >> 4;
    const int r  = nn & 15;
    const int kp = k0 >> 5;
    const size_t base = ((size_t)np * (Kd >> 5) + kp) * 512 + (c * 16 + r) * 8;
    f16x8 vh, vl;
#pragma unroll
    for (int j = 0; j < 8; ++j) {
        const float v = t[c * 8 + j][nn];
        const _Float16 h = (_Float16)v;
        vh[j] = h;
        vl[j] = (_Float16)(v - (float)h);
    }
    *(f16x8*)&Ph[base] = vh;
    *(f16x8*)&Pl[base] = vl;
}

// ---------------------------------------------------------------------------
// Pack A fp32 [M][K] row-major -> hi f16 A-panels [M/16][K/32][512].
// ---------------------------------------------------------------------------
__global__ __launch_bounds__(256) void pack_ap(
    const float* __restrict__ A, int lda,
    _Float16* __restrict__ Ph, int Kd)
{
    const int tid = threadIdx.x;
    const int mp = blockIdx.x;
    const int r = tid >> 4, c8 = tid & 15;
    const int k0 = blockIdx.y * 128 + c8 * 8;
    const float* Ap = A + (size_t)(mp * 16 + r) * lda + k0;
    const float4 v0 = *(const float4*)Ap;
    const float4 v1 = *(const float4*)(Ap + 4);
    const float x[8] = {v0.x, v0.y, v0.z, v0.w, v1.x, v1.y, v1.z, v1.w};
    f16x8 vh;
#pragma unroll
    for (int j = 0; j < 8; ++j) vh[j] = (_Float16)x[j];
    const int kp = k0 >> 5;
    const int c  = (k0 >> 3) & 3;
    const size_t base = ((size_t)mp * (Kd >> 5) + kp) * 512 + (c * 16 + r) * 8;
    *(f16x8*)&Ph[base] = vh;
}

__global__ __launch_bounds__(256) void zero_kernel(float* __restrict__ p, int n)
{
    const int idx = blockIdx.x * 256 + threadIdx.x;
    if (idx < n) p[idx] = 0.f;
}

// ---------------------------------------------------------------------------
// Causal depthwise conv (K=4) + bias + silu, vectorized (4ch x 8t / thread).
// Also zeroes the ssm buffer (consumed later by GEMM2's atomics).
// ---------------------------------------------------------------------------
__global__ __launch_bounds__(256) void conv_silu_kernel(
    const float* __restrict__ proj,      // x-half, ld 2I
    const float* __restrict__ xtail_in,  // 3 x I
    float* __restrict__ xtail_out,       // 3 x I
    const float* __restrict__ w,         // I x 4
    const float* __restrict__ b,         // I
    float* __restrict__ xconv,           // LC x I
    float* __restrict__ ssm,             // LC x 160 (zeroed here)
    int first)
{
    const int gid = blockIdx.x * 256 + threadIdx.x;
    if (gid < (LC * 160) / 4)
        *(float4*)(ssm + (size_t)gid * 4) = make_float4(0.f, 0.f, 0.f, 0.f);

    const int i4 = gid & (I_DIM / 4 - 1);
    const int t8 = gid >> 10;
    const int i = i4 * 4;
    const int tt0 = t8 * 8;

    const float4 w0 = *(const float4*)(w + (size_t)(i + 0) * 4);
    const float4 w1 = *(const float4*)(w + (size_t)(i + 1) * 4);
    const float4 w2 = *(const float4*)(w + (size_t)(i + 2) * 4);
    const float4 w3 = *(const float4*)(w + (size_t)(i + 3) * 4);
    const float4 bb = *(const float4*)(b + i);

    float4 r[11];
    if (tt0 >= 3) {
#pragma unroll
        for (int s = 0; s < 11; ++s)
            r[s] = *(const float4*)(proj + (size_t)(tt0 - 3 + s) * (2 * I_DIM) + i);
    } else {  // tt0 == 0
#pragma unroll
        for (int s = 0; s < 3; ++s)
            r[s] = first ? make_float4(0.f, 0.f, 0.f, 0.f)
                         : *(const float4*)(xtail_in + (size_t)s * I_DIM + i);
#pragma unroll
        for (int s = 3; s < 11; ++s)
            r[s] = *(const float4*)(proj + (size_t)(tt0 - 3 + s) * (2 * I_DIM) + i);
    }

#pragma unroll
    for (int s = 0; s < 8; ++s) {
        float4 y = bb;
        y.x = fmaf(w0.x, r[s].x, y.x); y.x = fmaf(w0.y, r[s+1].x, y.x);
        y.x = fmaf(w0.z, r[s+2].x, y.x); y.x = fmaf(w0.w, r[s+3].x, y.x);
        y.y = fmaf(w1.x, r[s].y, y.y); y.y = fmaf(w1.y, r[s+1].y, y.y);
        y.y = fmaf(w1.z, r[s+2].y, y.y); y.y = fmaf(w1.w, r[s+3].y, y.y);
        y.z = fmaf(w2.x, r[s].z, y.z); y.z = fmaf(w2.y, r[s+1].z, y.z);
        y.z = fmaf(w2.z, r[s+2].z, y.z); y.z = fmaf(w2.w, r[s+3].z, y.z);
        y.w = fmaf(w3.x, r[s].w, y.w); y.w = fmaf(w3.y, r[s+1].w, y.w);
        y.w = fmaf(w3.z, r[s+2].w, y.w); y.w = fmaf(w3.w, r[s+3].w, y.w);
        y.x = y.x / (1.f + __expf(-y.x));
        y.y = y.y / (1.f + __expf(-y.y));
        y.z = y.z / (1.f + __expf(-y.z));
        y.w = y.w / (1.f + __expf(-y.w));
        *(float4*)(xconv + (size_t)(tt0 + s) * I_DIM + i) = y;
    }

    if (tt0 == LC - 8) {
#pragma unroll
        for (int qq = 0; qq < 3; ++qq)
            *(float4*)(xtail_out + (size_t)qq * I_DIM + i) = r[8 + qq];
    }
}

// ---------------------------------------------------------------------------
// Segment-parallel scan (2-deep prefetch).
// ---------------------------------------------------------------------------
__global__ __launch_bounds__(256) void scan_part1(
    const float* __restrict__ delta,
    const float* __restrict__ ssm,
    const float* __restrict__ xc,
    const float* __restrict__ A_log,
    float* __restrict__ aprod,
    float* __restrict__ hend)
{
    __shared__ float Bs[TSEG][16];
    const int tid = threadIdx.x;
    const int i = blockIdx.x * 128 + (tid >> 1);
    const int half = tid & 1;
    const int seg = blockIdx.y;
    const int t0 = seg * TSEG;

    {
        const int tt = tid >> 2, c = (tid & 3) * 4;
        *(float4*)&Bs[tt][c] = *(const float4*)&ssm[(size_t)(t0 + tt) * 160 + 128 + c];
    }
    __syncthreads();

    float Ai[8], h[8], ap[8];
    {
        const float4 a0 = *(const float4*)&A_log[(size_t)i * 16 + half * 8];
        const float4 a1 = *(const float4*)&A_log[(size_t)i * 16 + half * 8 + 4];
        const float al[8] = {a0.x, a0.y, a0.z, a0.w, a1.x, a1.y, a1.z, a1.w};
#pragma unroll
        for (int n = 0; n < 8; ++n) { Ai[n] = -expf(al[n]); h[n] = 0.f; ap[n] = 1.f; }
    }

    float d0 = delta[(size_t)t0 * (2 * I_DIM) + i];
    float u0 = xc[(size_t)t0 * I_DIM + i];
    float d1 = delta[(size_t)(t0 + 1) * (2 * I_DIM) + i];
    float u1 = xc[(size_t)(t0 + 1) * I_DIM + i];
    for (int t = 0; t < TSEG; t += 2) {
        float d2 = 0.f, u2 = 0.f, d3 = 0.f, u3 = 0.f;
        if (t + 3 < TSEG) {
            d2 = delta[(size_t)(t0 + t + 2) * (2 * I_DIM) + i];
            u2 = xc[(size_t)(t0 + t + 2) * I_DIM + i];
            d3 = delta[(size_t)(t0 + t + 3) * (2 * I_DIM) + i];
            u3 = xc[(size_t)(t0 + t + 3) * I_DIM + i];
        }
        {
            const float du = d0 * u0;
#pragma unroll
            for (int n = 0; n < 8; ++n) {
                const float a = __expf(d0 * Ai[n]);
                h[n] = fmaf(h[n], a, du * Bs[t][half * 8 + n]);
                ap[n] *= a;
            }
        }
        {
            const float du = d1 * u1;
#pragma unroll
            for (int n = 0; n < 8; ++n) {
                const float a = __expf(d1 * Ai[n]);
                h[n] = fmaf(h[n], a, du * Bs[t + 1][half * 8 + n]);
                ap[n] *= a;
            }
        }
        d0 = d2; u0 = u2; d1 = d3; u1 = u3;
    }

    const size_t base = (size_t)seg * IN_DIM + (size_t)i * 16 + half * 8;
#pragma unroll
    for (int qq = 0; qq < 2; ++qq) {
        float4 va = {ap[qq * 4 + 0], ap[qq * 4 + 1], ap[qq * 4 + 2], ap[qq * 4 + 3]};
        float4 vh = {h[qq * 4 + 0], h[qq * 4 + 1], h[qq * 4 + 2], h[qq * 4 + 3]};
        *(float4*)&aprod[base + qq * 4] = va;
        *(float4*)&hend[base + qq * 4]  = vh;
    }
}

__global__ __launch_bounds__(256) void scan_part2(
    const float* __restrict__ aprod,
    float* __restrict__ hend,
    float* __restrict__ hstate,
    int first)
{
    const int gid = blockIdx.x * 256 + threadIdx.x;
    float h = first ? 0.f : hstate[gid];
    for (int s = 0; s < SEG; ++s) {
        const int idx = s * IN_DIM + gid;
        const float ap = aprod[idx];
        const float he = hend[idx];
        hend[idx] = h;
        h = fmaf(ap, h, he);
    }
    hstate[gid] = h;
}

// Phase 3: re-run segment from exact h_start; z (f16-hi) written DIRECTLY in
// GEMM4's A-panel layout: zPh[((row/16)*KP + i/32)*512 + (((i>>3)&3)*16 +
// (row&15))*8 + (i&7)], row = seg*TSEG + t, KP = I/32.
__global__ __launch_bounds__(256) void scan_part3(
    const float* __restrict__ delta,
    const float* __restrict__ gate,
    const float* __restrict__ ssm,
    const float* __restrict__ xc,
    _Float16* __restrict__ zPh,
    const float* __restrict__ A_log,
    const float* __restrict__ Dp,
    const float* __restrict__ hstart)
{
    __shared__ float BCs[TSEG][32];
    const int tid = threadIdx.x;
    const int i = blockIdx.x * 128 + (tid >> 1);
    const int half = tid & 1;
    const int seg = blockIdx.y;
    const int t0 = seg * TSEG;

    {
        const int tt = tid >> 2, c = (tid & 3) * 8;
        *(float4*)&BCs[tt][c]     = *(const float4*)&ssm[(size_t)(t0 + tt) * 160 + 128 + c];
        *(float4*)&BCs[tt][c + 4] = *(const float4*)&ssm[(size_t)(t0 + tt) * 160 + 132 + c];
    }
    __syncthreads();

    float Ai[8], h[8];
    {
        const float4 a0 = *(const float4*)&A_log[(size_t)i * 16 + half * 8];
        const float4 a1 = *(const float4*)&A_log[(size_t)i * 16 + half * 8 + 4];
        const float al[8] = {a0.x, a0.y, a0.z, a0.w, a1.x, a1.y, a1.z, a1.w};
#pragma unroll
        for (int n = 0; n < 8; ++n) Ai[n] = -expf(al[n]);
        const size_t base = (size_t)seg * IN_DIM + (size_t)i * 16 + half * 8;
        const float4 h0 = *(const float4*)&hstart[base];
        const float4 h1 = *(const float4*)&hstart[base + 4];
        h[0] = h0.x; h[1] = h0.y; h[2] = h0.z; h[3] = h0.w;
        h[4] = h1.x; h[5] = h1.y; h[6] = h1.z; h[7] = h1.w;
    }
    const float Di = Dp[i];

    // z-panel coords for this channel i (row part varies with t)
    const int kp = i >> 5, cc = (i >> 3) & 3, jj = i & 7;
    const size_t zb = (size_t)kp * 512 + (size_t)cc * 128 + jj;

    float d0 = delta[(size_t)t0 * (2 * I_DIM) + i];
    float u0 = xc[(size_t)t0 * I_DIM + i];
    float g0 = gate[(size_t)t0 * (2 * I_DIM) + i];
    float d1 = delta[(size_t)(t0 + 1) * (2 * I_DIM) + i];
    float u1 = xc[(size_t)(t0 + 1) * I_DIM + i];
    float g1 = gate[(size_t)(t0 + 1) * (2 * I_DIM) + i];
    for (int t = 0; t < TSEG; t += 2) {
        float d2 = 0.f, u2 = 0.f, g2 = 0.f, d3 = 0.f, u3 = 0.f, g3 = 0.f;
        if (t + 3 < TSEG) {
            d2 = delta[(size_t)(t0 + t + 2) * (2 * I_DIM) + i];
            u2 = xc[(size_t)(t0 + t + 2) * I_DIM + i];
            g2 = gate[(size_t)(t0 + t + 2) * (2 * I_DIM) + i];
            d3 = delta[(size_t)(t0 + t + 3) * (2 * I_DIM) + i];
            u3 = xc[(size_t)(t0 + t + 3) * I_DIM + i];
            g3 = gate[(size_t)(t0 + t + 3) * (2 * I_DIM) + i];
        }
#pragma unroll
        for (int ss = 0; ss < 2; ++ss) {
            const float d = ss ? d1 : d0;
            const float u = ss ? u1 : u0;
            const float g = ss ? g1 : g0;
            const int tt = t + ss;
            const float du = d * u;
            float y = 0.f;
#pragma unroll
            for (int n = 0; n < 8; ++n) {
                const float a = __expf(d * Ai[n]);
                h[n] = fmaf(h[n], a, du * BCs[tt][half * 8 + n]);
                y = fmaf(h[n], BCs[tt][16 + half * 8 + n], y);
            }
            y += __shfl_xor(y, 1);
            if (half == 0) {
                const float sg = g / (1.f + __expf(-g));
                const float zv = (y + u * Di) * sg;
                const int row = t0 + tt;
                zPh[((size_t)(row >> 4) * (I_DIM >> 5)) * 512 + zb + (size_t)(row & 15) * 8]
                    = (_Float16)zv;
            }
        }
        d0 = d2; u0 = u2; g0 = g2; d1 = d3; u1 = u3; g1 = g3;
    }
}

// ---------------------------------------------------------------------------
extern "C" void kernel_launch(void* const* d_in, const int* in_sizes, int n_in,
                              void* d_out, int out_size, void* d_ws, size_t ws_size,
                              hipStream_t stream)
{
    const float* hs      = (const float*)d_in[0];
    const float* W_in    = (const float*)d_in[1];
    const float* conv_w  = (const float*)d_in[2];
    const float* conv_b  = (const float*)d_in[3];
    const float* W_x     = (const float*)d_in[4];
    const float* W_dt    = (const float*)d_in[5];
    const float* dt_bias = (const float*)d_in[6];
    const float* A_log   = (const float*)d_in[7];
    const float* Dp      = (const float*)d_in[8];
    const float* W_out   = (const float*)d_in[9];
    float* out = (float*)d_out;

    // workspace layout (~226 MB)
    char* p = (char*)d_ws;
    auto alloc = [&](size_t bytes) {
        char* r = p;
        p += (bytes + 255) & ~(size_t)255;
        return r;
    };
    float* proj   = (float*)alloc((size_t)LC * 2 * I_DIM * 4);   // 64 MB
    float* xconv  = (float*)alloc((size_t)LC * I_DIM * 4);       // 32 MB
    float* ssm    = (float*)alloc((size_t)LC * 160 * 4);
    float* xtail  = (float*)alloc((size_t)2 * 3 * I_DIM * 4);
    float* hstate = (float*)alloc((size_t)IN_DIM * 4);
    _Float16* WinPh  = (_Float16*)alloc((size_t)2 * I_DIM * H_DIM * 2);  // 32 MB
    _Float16* WinPl  = (_Float16*)alloc((size_t)2 * I_DIM * H_DIM * 2);
    _Float16* WoutPh = (_Float16*)alloc((size_t)H_DIM * I_DIM * 2);      // 16 MB
    _Float16* WoutPl = (_Float16*)alloc((size_t)H_DIM * I_DIM * 2);
    _Float16* WdtPh  = (_Float16*)alloc((size_t)I_DIM * R_DIM * 2);
    _Float16* WdtPl  = (_Float16*)alloc((size_t)I_DIM * R_DIM * 2);
    _Float16* WxPh   = (_Float16*)alloc((size_t)256 * I_DIM * 2);
    _Float16* WxPl   = (_Float16*)alloc((size_t)256 * I_DIM * 2);
    _Float16* hsPh   = (_Float16*)alloc((size_t)LC * H_DIM * 2);   // 8 MB
    _Float16* zPh    = (_Float16*)alloc((size_t)LC * I_DIM * 2);   // 16 MB

    const dim3 blk(256);
    const int NSSM = R_DIM + 2 * N_DIM;  // 160

    // ---- pack weights into panel format (once per launch) ----
    pack_bp<<<dim3(2 * I_DIM / 32, H_DIM / 32), dim3(128), 0, stream>>>(
        W_in, WinPh, WinPl, H_DIM, 2 * I_DIM);
    pack_bp<<<dim3(H_DIM / 32, I_DIM / 32), dim3(128), 0, stream>>>(
        W_out, WoutPh, WoutPl, I_DIM, H_DIM);
    pack_bp<<<dim3(I_DIM / 32, R_DIM / 32), dim3(128), 0, stream>>>(
        W_dt, WdtPh, WdtPl, R_DIM, I_DIM);
    pack_bp<<<dim3(NSSM / 32, I_DIM / 32), dim3(128), 0, stream>>>(
        W_x, WxPh, WxPl, I_DIM, NSSM);

    for (int c = 0; c < NCHUNK; ++c) {
        const int t0 = c * LC;
        const int first = (c == 0) ? 1 : 0;
        const float* hs_c = hs + (size_t)t0 * H_DIM;
        float* out_c = out + (size_t)t0 * H_DIM;
        float* aprod = out_c;                 // scan scratch in out region
        float* hend  = out_c + (size_t)SEG * IN_DIM;
        float* xtA = xtail + (size_t)(c & 1) * 3 * I_DIM;
        float* xtB = xtail + (size_t)((c & 1) ^ 1) * 3 * I_DIM;

        // 0) pack hs chunk into A panels (hi only)
        pack_ap<<<dim3(LC / 16, H_DIM / 128), blk, 0, stream>>>(
            hs_c, H_DIM, hsPh, H_DIM);

        // 1) proj = hs_c @ W_in  (pure gl_lds, 3-buf pipeline)
        gemm_p<0, 2, 0, false><<<dim3(1024, 1), blk, 0, stream>>>(
            nullptr, 0, hsPh, nullptr, WinPh, WinPl, proj, 2 * I_DIM,
            H_DIM, 0, LC / 128, H_DIM, nullptr);

        // 2) xconv = silu(dwconv(x_pre) + b); zeroes ssm; saves tail
        conv_silu_kernel<<<dim3(1024), blk, 0, stream>>>(
            proj, xtA, xtB, conv_w, conv_b, xconv, ssm, first);

        // 3) ssm = xconv @ W_x  (full split, split-K x8, atomics)
        gemm_p<0, 0, 1, true><<<dim3(32, 8), blk, 0, stream>>>(
            xconv, I_DIM, nullptr, nullptr, WxPh, WxPl, ssm, NSSM,
            I_DIM, NSSM, LC / 128, I_DIM / 8, nullptr);

        // 4) delta = softplus(ssm[:, :R] @ W_dt + dt_bias) -> proj[:, :I]
        gemm_p<1, 0, 1, false><<<dim3(512, 1), blk, 0, stream>>>(
            ssm, NSSM, nullptr, nullptr, WdtPh, WdtPl, proj, 2 * I_DIM,
            R_DIM, 0, LC / 128, R_DIM, dt_bias);

        // 5) segment-parallel scan; z (f16-hi) written into zPh panels
        scan_part1<<<dim3(I_DIM / 128, SEG), blk, 0, stream>>>(
            proj, ssm, xconv, A_log, aprod, hend);
        scan_part2<<<dim3(IN_DIM / 256), blk, 0, stream>>>(
            aprod, hend, hstate, first);
        scan_part3<<<dim3(I_DIM / 128, SEG), blk, 0, stream>>>(
            proj, proj + I_DIM, ssm, xconv, zPh, A_log, Dp, hend);

        // 6) out_c = z @ W_out  (pure gl_lds, 3-buf pipeline, split-K x2)
        zero_kernel<<<dim3((LC * H_DIM + 255) / 256), blk, 0, stream>>>(
            out_c, LC * H_DIM);
        gemm_p<0, 2, 0, true><<<dim3(256, 2), blk, 0, stream>>>(
            nullptr, 0, zPh, nullptr, WoutPh, WoutPl, out_c, H_DIM,
            I_DIM, 0, LC / 128, I_DIM / 2, nullptr);
    }
}

// Round 11
// 1393.395 us; speedup vs baseline: 3.6551x; 1.0531x over previous
//
#include <hip/hip_runtime.h>
#include <cmath>
#include <stdint.h>

#define H_DIM 2048
#define I_DIM 4096
#define N_DIM 16
#define R_DIM 128
#define K_CONV 4
#define L_DIM 8192
#define LC 2048                 // chunk length
#define NCHUNK (L_DIM / LC)
#define SEG 32                  // scan segments per chunk
#define TSEG (LC / SEG)         // 64 steps per segment
#define IN_DIM (I_DIM * N_DIM)  // 65536 recurrences

typedef _Float16 f16x8 __attribute__((ext_vector_type(8)));
typedef float    f32x4 __attribute__((ext_vector_type(4)));

// direct HBM->LDS, 16B per lane; LDS base must be wave-uniform (HW adds lane*16)
__device__ __forceinline__ void gl_lds(const _Float16* g, _Float16* lbase, int lane) {
#if __has_builtin(__builtin_amdgcn_global_load_lds)
    __builtin_amdgcn_global_load_lds(
        (const __attribute__((address_space(1))) void*)g,
        (__attribute__((address_space(3))) void*)lbase, 16, 0, 0);
#else
    *(f16x8*)&lbase[lane * 8] = *(const f16x8*)g;
#endif
}

// ---------------------------------------------------------------------------
// 256x256 panel GEMM (GEMM1): A hi-only panels, B hi/lo panels, pure gl_lds.
// 512 threads = 8 waves (4m x 2n), wave tile 64x128. BK=32, 2-buffer, 96KB.
// Per K-iter/wave: 64 MFMA (~307cy) covering 6 gl_lds staging latency.
// ---------------------------------------------------------------------------
__global__ __launch_bounds__(512, 2) void gemm_p256(
    const _Float16* __restrict__ Aph,
    const _Float16* __restrict__ Bph, const _Float16* __restrict__ Bpl,
    float* __restrict__ C, int ldc, int Kd, int gm)
{
    __shared__ __align__(16) _Float16 Sh[2][3][8192];  // [buf][Ah,Bh,Bl][16 panels]

    const int tid = threadIdx.x;
    int bid = blockIdx.x;
    const int q = gridDim.x >> 3;
    bid = (bid & 7) * q + (bid >> 3);    // bijective XCD swizzle (grid % 8 == 0)
    const int m0 = (bid % gm) * 256;
    const int n0 = (bid / gm) * 256;

    const int w = tid >> 6, l = tid & 63;
    const int wm = w & 3, wn = w >> 2;   // 4m x 2n waves
    const int lr = l & 15, lg = l >> 4;

    const int KP = Kd >> 5;
    const int np0 = n0 >> 4, mp0 = m0 >> 4;
    const int st0 = tid >> 6;            // 0..7 (wave id = panel group)

    f32x4 acc[4][8];
#pragma unroll
    for (int a = 0; a < 4; ++a)
#pragma unroll
        for (int b = 0; b < 8; ++b) acc[a][b] = (f32x4){0.f, 0.f, 0.f, 0.f};

    auto stage = [&](int k0, int p) {
        const int kp = k0 >> 5;
#pragma unroll
        for (int s = 0; s < 2; ++s) {
            const int st = st0 + s * 8;  // 16 panels per array
            gl_lds(Aph + ((size_t)(mp0 + st) * KP + kp) * 512 + (size_t)l * 8,
                   &Sh[p][0][st * 512], l);
            gl_lds(Bph + ((size_t)(np0 + st) * KP + kp) * 512 + (size_t)l * 8,
                   &Sh[p][1][st * 512], l);
            gl_lds(Bpl + ((size_t)(np0 + st) * KP + kp) * 512 + (size_t)l * 8,
                   &Sh[p][2][st * 512], l);
        }
    };

    stage(0, 0);
    __syncthreads();
    int p = 0;
    for (int k0 = 0; k0 < Kd; k0 += 32) {
        if (k0 + 32 < Kd) stage(k0 + 32, p ^ 1);  // issue next stage FIRST

        f16x8 fah[4];
#pragma unroll
        for (int t = 0; t < 4; ++t)
            fah[t] = *(const f16x8*)&Sh[p][0][(wm * 4 + t) * 512 + l * 8];

        __builtin_amdgcn_s_setprio(1);
#pragma unroll
        for (int nh = 0; nh < 2; ++nh) {
            f16x8 fbh[4], fbl[4];
#pragma unroll
            for (int t = 0; t < 4; ++t) {
                const int off = (wn * 8 + nh * 4 + t) * 512 + l * 8;
                fbh[t] = *(const f16x8*)&Sh[p][1][off];
                fbl[t] = *(const f16x8*)&Sh[p][2][off];
            }
#pragma unroll
            for (int mt = 0; mt < 4; ++mt)
#pragma unroll
                for (int nt = 0; nt < 4; ++nt) {
                    f32x4& a = acc[mt][nh * 4 + nt];
                    a = __builtin_amdgcn_mfma_f32_16x16x32_f16(fah[mt], fbh[nt], a, 0, 0, 0);
                    a = __builtin_amdgcn_mfma_f32_16x16x32_f16(fah[mt], fbl[nt], a, 0, 0, 0);
                }
        }
        __builtin_amdgcn_s_setprio(0);

        __syncthreads();   // drains vmcnt (stage k+1) + ensures reads of p done
        p ^= 1;
    }

#pragma unroll
    for (int mt = 0; mt < 4; ++mt) {
        const int row = m0 + wm * 64 + mt * 16 + lg * 4;
#pragma unroll
        for (int nt = 0; nt < 8; ++nt) {
            const int col = n0 + wn * 128 + nt * 16 + lr;
#pragma unroll
            for (int j = 0; j < 4; ++j)
                C[(size_t)(row + j) * ldc + col] = acc[mt][nt][j];
        }
    }
}

// ---------------------------------------------------------------------------
// 128x128 panel GEMM (GEMM2/3/4), 2-buffer round-9 schedule.
// AK=0 fp32 reg-split | AK=2 pre-split A panels (pure gl_lds).
// ASPLIT: 1 = A hi+lo (3 MFMA), 0 = A hi only (2 MFMA, 48KB -> 3 blocks/CU).
// ---------------------------------------------------------------------------
template <int EPI, int AK, int ASPLIT, bool ATOMIC>
__global__ __launch_bounds__(256, ASPLIT ? 2 : 3) void gemm_p(
    const void* __restrict__ Av, int lda,
    const _Float16* __restrict__ Aph,
    const _Float16* __restrict__ Bph, const _Float16* __restrict__ Bpl,
    float* __restrict__ C, int ldc,
    int Kd, int Ncap, int gm, int kchunk,
    const float* __restrict__ bias)
{
    constexpr int NSLOT = ASPLIT ? 4 : 3;
    constexpr int S_AH = 0;
    constexpr int S_AL = ASPLIT ? 1 : 0;
    constexpr int S_BH = ASPLIT ? 2 : 1;
    constexpr int S_BL = ASPLIT ? 3 : 2;
    __shared__ __align__(16) _Float16 Sh[2][NSLOT][4096];

    const int tid = threadIdx.x;
    int bid = blockIdx.x;
    const int q = gridDim.x >> 3;
    bid = (bid & 7) * q + (bid >> 3);
    const int m0 = (bid % gm) * 128;
    const int n0 = (bid / gm) * 128;

    const int kbeg = blockIdx.y * kchunk;
    const int kend = (kbeg + kchunk < Kd) ? (kbeg + kchunk) : Kd;

    const int w = tid >> 6, l = tid & 63;
    const int wm = w & 1, wn = w >> 1;
    const int lr = l & 15, lg = l >> 4;

    const int ar = tid >> 1, ah = tid & 1;
    const int aw0 = (ar >> 4) * 512 + (((ah * 2) * 16 + (ar & 15)) * 8);
    const int aw1 = aw0 + 128;

    const int KP = Kd >> 5;
    const int np0 = n0 >> 4;
    const int mp0 = m0 >> 4;

    f32x4 acc[4][4];
#pragma unroll
    for (int a = 0; a < 4; ++a)
#pragma unroll
        for (int b = 0; b < 4; ++b) acc[a][b] = (f32x4){0.f, 0.f, 0.f, 0.f};

    float xf[16];
    f16x8 sah[2], sal[2];

    auto issueA = [&](int k0) {
        if (AK == 0) {
            const float* Ap = (const float*)Av + (size_t)(m0 + ar) * lda + k0 + ah * 16;
            *(float4*)&xf[0]  = *(const float4*)(Ap + 0);
            *(float4*)&xf[4]  = *(const float4*)(Ap + 4);
            *(float4*)&xf[8]  = *(const float4*)(Ap + 8);
            *(float4*)&xf[12] = *(const float4*)(Ap + 12);
        }
    };
    auto cvtA = [&]() {
        if (AK == 0) {
#pragma unroll
            for (int c2 = 0; c2 < 2; ++c2)
#pragma unroll
                for (int j = 0; j < 8; ++j) {
                    const float xv = xf[c2 * 8 + j];
                    const _Float16 h = (_Float16)xv;
                    sah[c2][j] = h;
                    if (ASPLIT) sal[c2][j] = (_Float16)(xv - (float)h);
                }
        }
    };
    auto writeA = [&](int p) {
        *(f16x8*)&Sh[p][S_AH][aw0] = sah[0];
        *(f16x8*)&Sh[p][S_AH][aw1] = sah[1];
        if (ASPLIT) {
            *(f16x8*)&Sh[p][S_AL][aw0] = sal[0];
            *(f16x8*)&Sh[p][S_AL][aw1] = sal[1];
        }
    };
    auto stageGL = [&](int k0, int p) {
        const int kp = k0 >> 5;
        if (AK == 2) {
#pragma unroll
            for (int s = 0; s < 2; ++s) {
                const int st = w + s * 4;
                const size_t ga = ((size_t)(mp0 + st) * KP + kp) * 512 + (size_t)l * 8;
                gl_lds(Aph + ga, &Sh[p][S_AH][st * 512], l);
            }
        }
#pragma unroll
        for (int qq = 0; qq < 2; ++qq) {
            const int st = 2 * w + qq;
            const size_t go = ((size_t)(np0 + st) * KP + kp) * 512 + (size_t)l * 8;
            gl_lds(Bph + go, &Sh[p][S_BH][st * 512], l);
            gl_lds(Bpl + go, &Sh[p][S_BL][st * 512], l);
        }
    };
    auto domfma = [&](int b) {
        f16x8 fah[4], fal[4], fbh[4], fbl[4];
#pragma unroll
        for (int t = 0; t < 4; ++t) {
            fah[t] = *(const f16x8*)&Sh[b][S_AH][(wm * 4 + t) * 512 + l * 8];
            if (ASPLIT) fal[t] = *(const f16x8*)&Sh[b][S_AL][(wm * 4 + t) * 512 + l * 8];
            fbh[t] = *(const f16x8*)&Sh[b][S_BH][(wn * 4 + t) * 512 + l * 8];
            fbl[t] = *(const f16x8*)&Sh[b][S_BL][(wn * 4 + t) * 512 + l * 8];
        }
        __builtin_amdgcn_s_setprio(1);
#pragma unroll
        for (int mt = 0; mt < 4; ++mt)
#pragma unroll
            for (int nt = 0; nt < 4; ++nt) {
                f32x4& a = acc[mt][nt];
                a = __builtin_amdgcn_mfma_f32_16x16x32_f16(fah[mt], fbh[nt], a, 0, 0, 0);
                a = __builtin_amdgcn_mfma_f32_16x16x32_f16(fah[mt], fbl[nt], a, 0, 0, 0);
                if (ASPLIT)
                    a = __builtin_amdgcn_mfma_f32_16x16x32_f16(fal[mt], fbh[nt], a, 0, 0, 0);
            }
        __builtin_amdgcn_s_setprio(0);
    };

    if (AK != 2) { issueA(kbeg); cvtA(); writeA(0); }
    stageGL(kbeg, 0);
    __syncthreads();
    int p = 0;
    for (int k0 = kbeg; k0 < kend; k0 += 32) {
        const bool more = (k0 + 32 < kend);
        if (more) {
            if (AK != 2) issueA(k0 + 32);
            stageGL(k0 + 32, p ^ 1);
        }
        domfma(p);
        if (more && AK != 2) { cvtA(); writeA(p ^ 1); }
        __syncthreads();
        p ^= 1;
    }

#pragma unroll
    for (int mt = 0; mt < 4; ++mt) {
        const int row = m0 + wm * 64 + mt * 16 + lg * 4;
#pragma unroll
        for (int nt = 0; nt < 4; ++nt) {
            const int col = n0 + wn * 64 + nt * 16 + lr;
            if (Ncap == 0 || col < Ncap) {
#pragma unroll
                for (int j = 0; j < 4; ++j) {
                    float v = acc[mt][nt][j];
                    if (EPI == 1) {
                        v += bias[col];
                        v = (v > 20.f) ? v : __logf(1.f + __expf(v));
                    }
                    if (ATOMIC) atomicAdd(&C[(size_t)(row + j) * ldc + col], v);
                    else        C[(size_t)(row + j) * ldc + col] = v;
                }
            }
        }
    }
}

// ---------------------------------------------------------------------------
// Pack W [Kd][Nd] fp32 -> hi/lo f16 B-panels [Nd/16][Kd/32][512].
// ---------------------------------------------------------------------------
__global__ __launch_bounds__(128) void pack_bp(
    const float* __restrict__ W, _Float16* __restrict__ Ph,
    _Float16* __restrict__ Pl, int Kd, int Nd)
{
    __shared__ float t[32][33];
    const int tid = threadIdx.x;
    const int n0 = blockIdx.x * 32, k0 = blockIdx.y * 32;
#pragma unroll
    for (int h = 0; h < 2; ++h) {
        const int qd = tid + h * 128;
        const int kk = qd >> 3, qq = qd & 7;
        *(float4*)&t[kk][qq * 4] = *(const float4*)(W + (size_t)(k0 + kk) * Nd + n0 + qq * 4);
    }
    __syncthreads();
    const int c = tid >> 5, nn = tid & 31;
    const int np = (n0 + nn) >> 4;
    const int r  = nn & 15;
    const int kp = k0 >> 5;
    const size_t base = ((size_t)np * (Kd >> 5) + kp) * 512 + (c * 16 + r) * 8;
    f16x8 vh, vl;
#pragma unroll
    for (int j = 0; j < 8; ++j) {
        const float v = t[c * 8 + j][nn];
        const _Float16 h = (_Float16)v;
        vh[j] = h;
        vl[j] = (_Float16)(v - (float)h);
    }
    *(f16x8*)&Ph[base] = vh;
    *(f16x8*)&Pl[base] = vl;
}

// ---------------------------------------------------------------------------
// Pack A fp32 [M][K] row-major -> hi f16 A-panels [M/16][K/32][512].
// ---------------------------------------------------------------------------
__global__ __launch_bounds__(256) void pack_ap(
    const float* __restrict__ A, int lda,
    _Float16* __restrict__ Ph, int Kd)
{
    const int tid = threadIdx.x;
    const int mp = blockIdx.x;
    const int r = tid >> 4, c8 = tid & 15;
    const int k0 = blockIdx.y * 128 + c8 * 8;
    const float* Ap = A + (size_t)(mp * 16 + r) * lda + k0;
    const float4 v0 = *(const float4*)Ap;
    const float4 v1 = *(const float4*)(Ap + 4);
    const float x[8] = {v0.x, v0.y, v0.z, v0.w, v1.x, v1.y, v1.z, v1.w};
    f16x8 vh;
#pragma unroll
    for (int j = 0; j < 8; ++j) vh[j] = (_Float16)x[j];
    const int kp = k0 >> 5;
    const int c  = (k0 >> 3) & 3;
    const size_t base = ((size_t)mp * (Kd >> 5) + kp) * 512 + (c * 16 + r) * 8;
    *(f16x8*)&Ph[base] = vh;
}

// ---------------------------------------------------------------------------
// Causal depthwise conv (K=4) + bias + silu (4ch x 8t / thread); zeroes ssm.
// ---------------------------------------------------------------------------
__global__ __launch_bounds__(256) void conv_silu_kernel(
    const float* __restrict__ proj,
    const float* __restrict__ xtail_in,
    float* __restrict__ xtail_out,
    const float* __restrict__ w,
    const float* __restrict__ b,
    float* __restrict__ xconv,
    float* __restrict__ ssm,
    int first)
{
    const int gid = blockIdx.x * 256 + threadIdx.x;
    if (gid < (LC * 160) / 4)
        *(float4*)(ssm + (size_t)gid * 4) = make_float4(0.f, 0.f, 0.f, 0.f);

    const int i4 = gid & (I_DIM / 4 - 1);
    const int t8 = gid >> 10;
    const int i = i4 * 4;
    const int tt0 = t8 * 8;

    const float4 w0 = *(const float4*)(w + (size_t)(i + 0) * 4);
    const float4 w1 = *(const float4*)(w + (size_t)(i + 1) * 4);
    const float4 w2 = *(const float4*)(w + (size_t)(i + 2) * 4);
    const float4 w3 = *(const float4*)(w + (size_t)(i + 3) * 4);
    const float4 bb = *(const float4*)(b + i);

    float4 r[11];
    if (tt0 >= 3) {
#pragma unroll
        for (int s = 0; s < 11; ++s)
            r[s] = *(const float4*)(proj + (size_t)(tt0 - 3 + s) * (2 * I_DIM) + i);
    } else {
#pragma unroll
        for (int s = 0; s < 3; ++s)
            r[s] = first ? make_float4(0.f, 0.f, 0.f, 0.f)
                         : *(const float4*)(xtail_in + (size_t)s * I_DIM + i);
#pragma unroll
        for (int s = 3; s < 11; ++s)
            r[s] = *(const float4*)(proj + (size_t)(tt0 - 3 + s) * (2 * I_DIM) + i);
    }

#pragma unroll
    for (int s = 0; s < 8; ++s) {
        float4 y = bb;
        y.x = fmaf(w0.x, r[s].x, y.x); y.x = fmaf(w0.y, r[s+1].x, y.x);
        y.x = fmaf(w0.z, r[s+2].x, y.x); y.x = fmaf(w0.w, r[s+3].x, y.x);
        y.y = fmaf(w1.x, r[s].y, y.y); y.y = fmaf(w1.y, r[s+1].y, y.y);
        y.y = fmaf(w1.z, r[s+2].y, y.y); y.y = fmaf(w1.w, r[s+3].y, y.y);
        y.z = fmaf(w2.x, r[s].z, y.z); y.z = fmaf(w2.y, r[s+1].z, y.z);
        y.z = fmaf(w2.z, r[s+2].z, y.z); y.z = fmaf(w2.w, r[s+3].z, y.z);
        y.w = fmaf(w3.x, r[s].w, y.w); y.w = fmaf(w3.y, r[s+1].w, y.w);
        y.w = fmaf(w3.z, r[s+2].w, y.w); y.w = fmaf(w3.w, r[s+3].w, y.w);
        y.x = y.x / (1.f + __expf(-y.x));
        y.y = y.y / (1.f + __expf(-y.y));
        y.z = y.z / (1.f + __expf(-y.z));
        y.w = y.w / (1.f + __expf(-y.w));
        *(float4*)(xconv + (size_t)(tt0 + s) * I_DIM + i) = y;
    }

    if (tt0 == LC - 8) {
#pragma unroll
        for (int qq = 0; qq < 3; ++qq)
            *(float4*)(xtail_out + (size_t)qq * I_DIM + i) = r[8 + qq];
    }
}

// ---------------------------------------------------------------------------
// Segment-parallel scan.
// ---------------------------------------------------------------------------
__global__ __launch_bounds__(256) void scan_part1(
    const float* __restrict__ delta,
    const float* __restrict__ ssm,
    const float* __restrict__ xc,
    const float* __restrict__ A_log,
    float* __restrict__ aprod,
    float* __restrict__ hend)
{
    __shared__ float Bs[TSEG][16];
    const int tid = threadIdx.x;
    const int i = blockIdx.x * 128 + (tid >> 1);
    const int half = tid & 1;
    const int seg = blockIdx.y;
    const int t0 = seg * TSEG;

    {
        const int tt = tid >> 2, c = (tid & 3) * 4;
        *(float4*)&Bs[tt][c] = *(const float4*)&ssm[(size_t)(t0 + tt) * 160 + 128 + c];
    }
    __syncthreads();

    float Ai[8], h[8], ap[8];
    {
        const float4 a0 = *(const float4*)&A_log[(size_t)i * 16 + half * 8];
        const float4 a1 = *(const float4*)&A_log[(size_t)i * 16 + half * 8 + 4];
        const float al[8] = {a0.x, a0.y, a0.z, a0.w, a1.x, a1.y, a1.z, a1.w};
#pragma unroll
        for (int n = 0; n < 8; ++n) { Ai[n] = -expf(al[n]); h[n] = 0.f; ap[n] = 1.f; }
    }

    float d0 = delta[(size_t)t0 * (2 * I_DIM) + i];
    float u0 = xc[(size_t)t0 * I_DIM + i];
    float d1 = delta[(size_t)(t0 + 1) * (2 * I_DIM) + i];
    float u1 = xc[(size_t)(t0 + 1) * I_DIM + i];
    for (int t = 0; t < TSEG; t += 2) {
        float d2 = 0.f, u2 = 0.f, d3 = 0.f, u3 = 0.f;
        if (t + 3 < TSEG) {
            d2 = delta[(size_t)(t0 + t + 2) * (2 * I_DIM) + i];
            u2 = xc[(size_t)(t0 + t + 2) * I_DIM + i];
            d3 = delta[(size_t)(t0 + t + 3) * (2 * I_DIM) + i];
            u3 = xc[(size_t)(t0 + t + 3) * I_DIM + i];
        }
        {
            const float du = d0 * u0;
#pragma unroll
            for (int n = 0; n < 8; ++n) {
                const float a = __expf(d0 * Ai[n]);
                h[n] = fmaf(h[n], a, du * Bs[t][half * 8 + n]);
                ap[n] *= a;
            }
        }
        {
            const float du = d1 * u1;
#pragma unroll
            for (int n = 0; n < 8; ++n) {
                const float a = __expf(d1 * Ai[n]);
                h[n] = fmaf(h[n], a, du * Bs[t + 1][half * 8 + n]);
                ap[n] *= a;
            }
        }
        d0 = d2; u0 = u2; d1 = d3; u1 = u3;
    }

    const size_t base = (size_t)seg * IN_DIM + (size_t)i * 16 + half * 8;
#pragma unroll
    for (int qq = 0; qq < 2; ++qq) {
        float4 va = {ap[qq * 4 + 0], ap[qq * 4 + 1], ap[qq * 4 + 2], ap[qq * 4 + 3]};
        float4 vh = {h[qq * 4 + 0], h[qq * 4 + 1], h[qq * 4 + 2], h[qq * 4 + 3]};
        *(float4*)&aprod[base + qq * 4] = va;
        *(float4*)&hend[base + qq * 4]  = vh;
    }
}

__global__ __launch_bounds__(256) void scan_part2(
    const float* __restrict__ aprod,
    float* __restrict__ hend,
    float* __restrict__ hstate,
    int first)
{
    const int gid = blockIdx.x * 256 + threadIdx.x;
    float h = first ? 0.f : hstate[gid];
    for (int s = 0; s < SEG; ++s) {
        const int idx = s * IN_DIM + gid;
        const float ap = aprod[idx];
        const float he = hend[idx];
        hend[idx] = h;
        h = fmaf(ap, h, he);
    }
    hstate[gid] = h;
}

// Phase 3: re-run segment from h_start (in outz's hend half); z (f16-hi)
// written in GEMM4 A-panel layout. Also ZEROES out_c: each thread zeroes the
// aprod/hstart slices it alone owns (aprod dead after part2; hstart zeroed
// right after this thread reads it) -> GEMM4's atomic epilogue sees zeros.
__global__ __launch_bounds__(256) void scan_part3(
    const float* __restrict__ delta,
    const float* __restrict__ gate,
    const float* __restrict__ ssm,
    const float* __restrict__ xc,
    _Float16* __restrict__ zPh,
    const float* __restrict__ A_log,
    const float* __restrict__ Dp,
    float* __restrict__ outz)          // out_c base: [aprod | hstart]
{
    __shared__ float BCs[TSEG][32];
    const int tid = threadIdx.x;
    const int i = blockIdx.x * 128 + (tid >> 1);
    const int half = tid & 1;
    const int seg = blockIdx.y;
    const int t0 = seg * TSEG;

    {
        const int tt = tid >> 2, c = (tid & 3) * 8;
        *(float4*)&BCs[tt][c]     = *(const float4*)&ssm[(size_t)(t0 + tt) * 160 + 128 + c];
        *(float4*)&BCs[tt][c + 4] = *(const float4*)&ssm[(size_t)(t0 + tt) * 160 + 132 + c];
    }
    __syncthreads();

    const size_t base = (size_t)seg * IN_DIM + (size_t)i * 16 + half * 8;
    float* hstart = outz + (size_t)SEG * IN_DIM;

    float Ai[8], h[8];
    {
        const float4 a0 = *(const float4*)&A_log[(size_t)i * 16 + half * 8];
        const float4 a1 = *(const float4*)&A_log[(size_t)i * 16 + half * 8 + 4];
        const float al[8] = {a0.x, a0.y, a0.z, a0.w, a1.x, a1.y, a1.z, a1.w};
#pragma unroll
        for (int n = 0; n < 8; ++n) Ai[n] = -expf(al[n]);
        const float4 h0 = *(const float4*)&hstart[base];
        const float4 h1 = *(const float4*)&hstart[base + 4];
        h[0] = h0.x; h[1] = h0.y; h[2] = h0.z; h[3] = h0.w;
        h[4] = h1.x; h[5] = h1.y; h[6] = h1.z; h[7] = h1.w;
    }
    // zero own slices (out_c must be 0 before GEMM4's atomic accumulate)
    {
        const float4 z4 = {0.f, 0.f, 0.f, 0.f};
        *(float4*)&outz[base]       = z4;
        *(float4*)&outz[base + 4]   = z4;
        *(float4*)&hstart[base]     = z4;
        *(float4*)&hstart[base + 4] = z4;
    }
    const float Di = Dp[i];

    const int kp = i >> 5, cc = (i >> 3) & 3, jj = i & 7;
    const size_t zb = (size_t)kp * 512 + (size_t)cc * 128 + jj;

    float d0 = delta[(size_t)t0 * (2 * I_DIM) + i];
    float u0 = xc[(size_t)t0 * I_DIM + i];
    float g0 = gate[(size_t)t0 * (2 * I_DIM) + i];
    float d1 = delta[(size_t)(t0 + 1) * (2 * I_DIM) + i];
    float u1 = xc[(size_t)(t0 + 1) * I_DIM + i];
    float g1 = gate[(size_t)(t0 + 1) * (2 * I_DIM) + i];
    for (int t = 0; t < TSEG; t += 2) {
        float d2 = 0.f, u2 = 0.f, g2 = 0.f, d3 = 0.f, u3 = 0.f, g3 = 0.f;
        if (t + 3 < TSEG) {
            d2 = delta[(size_t)(t0 + t + 2) * (2 * I_DIM) + i];
            u2 = xc[(size_t)(t0 + t + 2) * I_DIM + i];
            g2 = gate[(size_t)(t0 + t + 2) * (2 * I_DIM) + i];
            d3 = delta[(size_t)(t0 + t + 3) * (2 * I_DIM) + i];
            u3 = xc[(size_t)(t0 + t + 3) * I_DIM + i];
            g3 = gate[(size_t)(t0 + t + 3) * (2 * I_DIM) + i];
        }
#pragma unroll
        for (int ss = 0; ss < 2; ++ss) {
            const float d = ss ? d1 : d0;
            const float u = ss ? u1 : u0;
            const float g = ss ? g1 : g0;
            const int tt = t + ss;
            const float du = d * u;
            float y = 0.f;
#pragma unroll
            for (int n = 0; n < 8; ++n) {
                const float a = __expf(d * Ai[n]);
                h[n] = fmaf(h[n], a, du * BCs[tt][half * 8 + n]);
                y = fmaf(h[n], BCs[tt][16 + half * 8 + n], y);
            }
            y += __shfl_xor(y, 1);
            if (half == 0) {
                const float sg = g / (1.f + __expf(-g));
                const float zv = (y + u * Di) * sg;
                const int row = t0 + tt;
                zPh[((size_t)(row >> 4) * (I_DIM >> 5)) * 512 + zb + (size_t)(row & 15) * 8]
                    = (_Float16)zv;
            }
        }
        d0 = d2; u0 = u2; g0 = g2; d1 = d3; u1 = u3; g1 = g3;
    }
}

// ---------------------------------------------------------------------------
extern "C" void kernel_launch(void* const* d_in, const int* in_sizes, int n_in,
                              void* d_out, int out_size, void* d_ws, size_t ws_size,
                              hipStream_t stream)
{
    const float* hs      = (const float*)d_in[0];
    const float* W_in    = (const float*)d_in[1];
    const float* conv_w  = (const float*)d_in[2];
    const float* conv_b  = (const float*)d_in[3];
    const float* W_x     = (const float*)d_in[4];
    const float* W_dt    = (const float*)d_in[5];
    const float* dt_bias = (const float*)d_in[6];
    const float* A_log   = (const float*)d_in[7];
    const float* Dp      = (const float*)d_in[8];
    const float* W_out   = (const float*)d_in[9];
    float* out = (float*)d_out;

    // workspace layout (~230 MB, known-good footprint)
    char* p = (char*)d_ws;
    auto alloc = [&](size_t bytes) {
        char* r = p;
        p += (bytes + 255) & ~(size_t)255;
        return r;
    };
    float* proj   = (float*)alloc((size_t)LC * 2 * I_DIM * 4);   // 64 MB
    float* xconv  = (float*)alloc((size_t)LC * I_DIM * 4);       // 32 MB
    float* ssm    = (float*)alloc((size_t)LC * 160 * 4);
    float* xtail  = (float*)alloc((size_t)2 * 3 * I_DIM * 4);
    float* hstate = (float*)alloc((size_t)IN_DIM * 4);
    _Float16* WinPh  = (_Float16*)alloc((size_t)2 * I_DIM * H_DIM * 2);  // 32 MB
    _Float16* WinPl  = (_Float16*)alloc((size_t)2 * I_DIM * H_DIM * 2);
    _Float16* WoutPh = (_Float16*)alloc((size_t)H_DIM * I_DIM * 2);      // 16 MB
    _Float16* WoutPl = (_Float16*)alloc((size_t)H_DIM * I_DIM * 2);
    _Float16* WdtPh  = (_Float16*)alloc((size_t)I_DIM * R_DIM * 2);
    _Float16* WdtPl  = (_Float16*)alloc((size_t)I_DIM * R_DIM * 2);
    _Float16* WxPh   = (_Float16*)alloc((size_t)256 * I_DIM * 2);
    _Float16* WxPl   = (_Float16*)alloc((size_t)256 * I_DIM * 2);
    _Float16* hsPh   = (_Float16*)alloc((size_t)LC * H_DIM * 2);   // 8 MB
    _Float16* zPh    = (_Float16*)alloc((size_t)LC * I_DIM * 2);   // 16 MB

    const dim3 blk(256);
    const int NSSM = R_DIM + 2 * N_DIM;  // 160

    // ---- pack weights into panel format (once per launch) ----
    pack_bp<<<dim3(2 * I_DIM / 32, H_DIM / 32), dim3(128), 0, stream>>>(
        W_in, WinPh, WinPl, H_DIM, 2 * I_DIM);
    pack_bp<<<dim3(H_DIM / 32, I_DIM / 32), dim3(128), 0, stream>>>(
        W_out, WoutPh, WoutPl, I_DIM, H_DIM);
    pack_bp<<<dim3(I_DIM / 32, R_DIM / 32), dim3(128), 0, stream>>>(
        W_dt, WdtPh, WdtPl, R_DIM, I_DIM);
    pack_bp<<<dim3(NSSM / 32, I_DIM / 32), dim3(128), 0, stream>>>(
        W_x, WxPh, WxPl, I_DIM, NSSM);

    for (int c = 0; c < NCHUNK; ++c) {
        const int t0 = c * LC;
        const int first = (c == 0) ? 1 : 0;
        const float* hs_c = hs + (size_t)t0 * H_DIM;
        float* out_c = out + (size_t)t0 * H_DIM;
        float* aprod = out_c;                 // scan scratch in out region
        float* hend  = out_c + (size_t)SEG * IN_DIM;
        float* xtA = xtail + (size_t)(c & 1) * 3 * I_DIM;
        float* xtB = xtail + (size_t)((c & 1) ^ 1) * 3 * I_DIM;

        // 0) pack hs chunk into A panels (hi only)
        pack_ap<<<dim3(LC / 16, H_DIM / 128), blk, 0, stream>>>(
            hs_c, H_DIM, hsPh, H_DIM);

        // 1) proj = hs_c @ W_in  (256x256 tile, pure gl_lds) -> 256 blocks
        gemm_p256<<<dim3(256), dim3(512), 0, stream>>>(
            hsPh, WinPh, WinPl, proj, 2 * I_DIM, H_DIM, LC / 256);

        // 2) xconv = silu(dwconv(x_pre) + b); zeroes ssm; saves tail
        conv_silu_kernel<<<dim3(1024), blk, 0, stream>>>(
            proj, xtA, xtB, conv_w, conv_b, xconv, ssm, first);

        // 3) ssm = xconv @ W_x  (full split, split-K x8, atomics)
        gemm_p<0, 0, 1, true><<<dim3(32, 8), blk, 0, stream>>>(
            xconv, I_DIM, nullptr, WxPh, WxPl, ssm, NSSM,
            I_DIM, NSSM, LC / 128, I_DIM / 8, nullptr);

        // 4) delta = softplus(ssm[:, :R] @ W_dt + dt_bias) -> proj[:, :I]
        gemm_p<1, 0, 1, false><<<dim3(512, 1), blk, 0, stream>>>(
            ssm, NSSM, nullptr, WdtPh, WdtPl, proj, 2 * I_DIM,
            R_DIM, 0, LC / 128, R_DIM, dt_bias);

        // 5) segment-parallel scan; z -> zPh panels; part3 zeroes out_c
        scan_part1<<<dim3(I_DIM / 128, SEG), blk, 0, stream>>>(
            proj, ssm, xconv, A_log, aprod, hend);
        scan_part2<<<dim3(IN_DIM / 256), blk, 0, stream>>>(
            aprod, hend, hstate, first);
        scan_part3<<<dim3(I_DIM / 128, SEG), blk, 0, stream>>>(
            proj, proj + I_DIM, ssm, xconv, zPh, A_log, Dp, out_c);

        // 6) out_c = z @ W_out  (pure gl_lds, split-K x2, atomics)
        gemm_p<0, 2, 0, true><<<dim3(256, 2), blk, 0, stream>>>(
            nullptr, 0, zPh, WoutPh, WoutPl, out_c, H_DIM,
            I_DIM, 0, LC / 128, I_DIM / 2, nullptr);
    }
}

// Round 12
// 1219.740 us; speedup vs baseline: 4.1754x; 1.1424x over previous
//
#include <hip/hip_runtime.h>
#include <cmath>
#include <stdint.h>

#define H_DIM 2048
#define I_DIM 4096
#define N_DIM 16
#define R_DIM 128
#define K_CONV 4
#define L_DIM 8192
#define LC 2048                 // chunk length
#define NCHUNK (L_DIM / LC)
#define SEG 32                  // scan segments per chunk
#define TSEG (LC / SEG)         // 64 steps per segment
#define IN_DIM (I_DIM * N_DIM)  // 65536 recurrences

typedef _Float16 f16x8 __attribute__((ext_vector_type(8)));
typedef float    f32x4 __attribute__((ext_vector_type(4)));

// direct HBM->LDS, 16B per lane; LDS base must be wave-uniform (HW adds lane*16)
__device__ __forceinline__ void gl_lds(const _Float16* g, _Float16* lbase, int lane) {
#if __has_builtin(__builtin_amdgcn_global_load_lds)
    __builtin_amdgcn_global_load_lds(
        (const __attribute__((address_space(1))) void*)g,
        (__attribute__((address_space(3))) void*)lbase, 16, 0, 0);
#else
    *(f16x8*)&lbase[lane * 8] = *(const f16x8*)g;
#endif
}

// ---------------------------------------------------------------------------
// 256x256 panel GEMM (GEMM1): A hi panels x B hi panels (1 MFMA/pair).
// 512 threads = 8 waves (4m x 2n), wave tile 64x128. BK=32, 2-buffer, 64KB.
// ---------------------------------------------------------------------------
__global__ __launch_bounds__(512, 1) void gemm_p256(
    const _Float16* __restrict__ Aph,
    const _Float16* __restrict__ Bph,
    float* __restrict__ C, int ldc, int Kd, int gm)
{
    __shared__ __align__(16) _Float16 Sh[2][2][8192];  // [buf][Ah,Bh][16 panels]

    const int tid = threadIdx.x;
    int bid = blockIdx.x;
    const int q = gridDim.x >> 3;
    bid = (bid & 7) * q + (bid >> 3);    // bijective XCD swizzle (grid % 8 == 0)
    const int m0 = (bid % gm) * 256;
    const int n0 = (bid / gm) * 256;

    const int w = tid >> 6, l = tid & 63;
    const int wm = w & 3, wn = w >> 2;   // 4m x 2n waves
    const int lr = l & 15, lg = l >> 4;

    const int KP = Kd >> 5;
    const int np0 = n0 >> 4, mp0 = m0 >> 4;
    const int st0 = tid >> 6;            // 0..7 (wave id = panel group)

    f32x4 acc[4][8];
#pragma unroll
    for (int a = 0; a < 4; ++a)
#pragma unroll
        for (int b = 0; b < 8; ++b) acc[a][b] = (f32x4){0.f, 0.f, 0.f, 0.f};

    auto stage = [&](int k0, int p) {
        const int kp = k0 >> 5;
#pragma unroll
        for (int s = 0; s < 2; ++s) {
            const int st = st0 + s * 8;  // 16 panels per array
            gl_lds(Aph + ((size_t)(mp0 + st) * KP + kp) * 512 + (size_t)l * 8,
                   &Sh[p][0][st * 512], l);
            gl_lds(Bph + ((size_t)(np0 + st) * KP + kp) * 512 + (size_t)l * 8,
                   &Sh[p][1][st * 512], l);
        }
    };

    stage(0, 0);
    __syncthreads();
    int p = 0;
    for (int k0 = 0; k0 < Kd; k0 += 32) {
        if (k0 + 32 < Kd) stage(k0 + 32, p ^ 1);  // issue next stage FIRST

        f16x8 fah[4];
#pragma unroll
        for (int t = 0; t < 4; ++t)
            fah[t] = *(const f16x8*)&Sh[p][0][(wm * 4 + t) * 512 + l * 8];

        __builtin_amdgcn_s_setprio(1);
#pragma unroll
        for (int nh = 0; nh < 2; ++nh) {
            f16x8 fbh[4];
#pragma unroll
            for (int t = 0; t < 4; ++t)
                fbh[t] = *(const f16x8*)&Sh[p][1][(wn * 8 + nh * 4 + t) * 512 + l * 8];
#pragma unroll
            for (int mt = 0; mt < 4; ++mt)
#pragma unroll
                for (int nt = 0; nt < 4; ++nt)
                    acc[mt][nh * 4 + nt] = __builtin_amdgcn_mfma_f32_16x16x32_f16(
                        fah[mt], fbh[nt], acc[mt][nh * 4 + nt], 0, 0, 0);
        }
        __builtin_amdgcn_s_setprio(0);

        __syncthreads();   // drains vmcnt (stage k+1) + ensures reads of p done
        p ^= 1;
    }

#pragma unroll
    for (int mt = 0; mt < 4; ++mt) {
        const int row = m0 + wm * 64 + mt * 16 + lg * 4;
#pragma unroll
        for (int nt = 0; nt < 8; ++nt) {
            const int col = n0 + wn * 128 + nt * 16 + lr;
#pragma unroll
            for (int j = 0; j < 4; ++j)
                C[(size_t)(row + j) * ldc + col] = acc[mt][nt][j];
        }
    }
}

// ---------------------------------------------------------------------------
// 128x128 panel GEMM, 2-buffer schedule.
// AK=0 fp32 reg-split | AK=2 pre-split A panels (pure gl_lds).
// ASPLIT/BSPLIT: include lo-correction MFMA for A/B side.
// ---------------------------------------------------------------------------
template <int EPI, int AK, int ASPLIT, int BSPLIT, bool ATOMIC>
__global__ __launch_bounds__(256, ASPLIT ? 2 : (BSPLIT ? 3 : 4)) void gemm_p(
    const void* __restrict__ Av, int lda,
    const _Float16* __restrict__ Aph,
    const _Float16* __restrict__ Bph, const _Float16* __restrict__ Bpl,
    float* __restrict__ C, int ldc,
    int Kd, int Ncap, int gm, int kchunk,
    const float* __restrict__ bias)
{
    constexpr int S_AH = 0;
    constexpr int S_AL = ASPLIT ? 1 : 0;
    constexpr int S_BH = ASPLIT ? 2 : 1;
    constexpr int S_BL = S_BH + 1;           // valid only if BSPLIT
    constexpr int NSLOT = S_BH + 1 + BSPLIT;
    __shared__ __align__(16) _Float16 Sh[2][NSLOT][4096];

    const int tid = threadIdx.x;
    int bid = blockIdx.x;
    const int q = gridDim.x >> 3;
    bid = (bid & 7) * q + (bid >> 3);
    const int m0 = (bid % gm) * 128;
    const int n0 = (bid / gm) * 128;

    const int kbeg = blockIdx.y * kchunk;
    const int kend = (kbeg + kchunk < Kd) ? (kbeg + kchunk) : Kd;

    const int w = tid >> 6, l = tid & 63;
    const int wm = w & 1, wn = w >> 1;
    const int lr = l & 15, lg = l >> 4;

    const int ar = tid >> 1, ah = tid & 1;
    const int aw0 = (ar >> 4) * 512 + (((ah * 2) * 16 + (ar & 15)) * 8);
    const int aw1 = aw0 + 128;

    const int KP = Kd >> 5;
    const int np0 = n0 >> 4;
    const int mp0 = m0 >> 4;

    f32x4 acc[4][4];
#pragma unroll
    for (int a = 0; a < 4; ++a)
#pragma unroll
        for (int b = 0; b < 4; ++b) acc[a][b] = (f32x4){0.f, 0.f, 0.f, 0.f};

    float xf[16];
    f16x8 sah[2], sal[2];

    auto issueA = [&](int k0) {
        if (AK == 0) {
            const float* Ap = (const float*)Av + (size_t)(m0 + ar) * lda + k0 + ah * 16;
            *(float4*)&xf[0]  = *(const float4*)(Ap + 0);
            *(float4*)&xf[4]  = *(const float4*)(Ap + 4);
            *(float4*)&xf[8]  = *(const float4*)(Ap + 8);
            *(float4*)&xf[12] = *(const float4*)(Ap + 12);
        }
    };
    auto cvtA = [&]() {
        if (AK == 0) {
#pragma unroll
            for (int c2 = 0; c2 < 2; ++c2)
#pragma unroll
                for (int j = 0; j < 8; ++j) {
                    const float xv = xf[c2 * 8 + j];
                    const _Float16 h = (_Float16)xv;
                    sah[c2][j] = h;
                    if (ASPLIT) sal[c2][j] = (_Float16)(xv - (float)h);
                }
        }
    };
    auto writeA = [&](int p) {
        *(f16x8*)&Sh[p][S_AH][aw0] = sah[0];
        *(f16x8*)&Sh[p][S_AH][aw1] = sah[1];
        if (ASPLIT) {
            *(f16x8*)&Sh[p][S_AL][aw0] = sal[0];
            *(f16x8*)&Sh[p][S_AL][aw1] = sal[1];
        }
    };
    auto stageGL = [&](int k0, int p) {
        const int kp = k0 >> 5;
        if (AK == 2) {
#pragma unroll
            for (int s = 0; s < 2; ++s) {
                const int st = w + s * 4;
                const size_t ga = ((size_t)(mp0 + st) * KP + kp) * 512 + (size_t)l * 8;
                gl_lds(Aph + ga, &Sh[p][S_AH][st * 512], l);
            }
        }
#pragma unroll
        for (int qq = 0; qq < 2; ++qq) {
            const int st = 2 * w + qq;
            const size_t go = ((size_t)(np0 + st) * KP + kp) * 512 + (size_t)l * 8;
            gl_lds(Bph + go, &Sh[p][S_BH][st * 512], l);
            if (BSPLIT) gl_lds(Bpl + go, &Sh[p][S_BL][st * 512], l);
        }
    };
    auto domfma = [&](int b) {
        f16x8 fah[4], fal[4], fbh[4], fbl[4];
#pragma unroll
        for (int t = 0; t < 4; ++t) {
            fah[t] = *(const f16x8*)&Sh[b][S_AH][(wm * 4 + t) * 512 + l * 8];
            if (ASPLIT) fal[t] = *(const f16x8*)&Sh[b][S_AL][(wm * 4 + t) * 512 + l * 8];
            fbh[t] = *(const f16x8*)&Sh[b][S_BH][(wn * 4 + t) * 512 + l * 8];
            if (BSPLIT) fbl[t] = *(const f16x8*)&Sh[b][S_BL][(wn * 4 + t) * 512 + l * 8];
        }
        __builtin_amdgcn_s_setprio(1);
#pragma unroll
        for (int mt = 0; mt < 4; ++mt)
#pragma unroll
            for (int nt = 0; nt < 4; ++nt) {
                f32x4& a = acc[mt][nt];
                a = __builtin_amdgcn_mfma_f32_16x16x32_f16(fah[mt], fbh[nt], a, 0, 0, 0);
                if (BSPLIT)
                    a = __builtin_amdgcn_mfma_f32_16x16x32_f16(fah[mt], fbl[nt], a, 0, 0, 0);
                if (ASPLIT)
                    a = __builtin_amdgcn_mfma_f32_16x16x32_f16(fal[mt], fbh[nt], a, 0, 0, 0);
            }
        __builtin_amdgcn_s_setprio(0);
    };

    if (AK != 2) { issueA(kbeg); cvtA(); writeA(0); }
    stageGL(kbeg, 0);
    __syncthreads();
    int p = 0;
    for (int k0 = kbeg; k0 < kend; k0 += 32) {
        const bool more = (k0 + 32 < kend);
        if (more) {
            if (AK != 2) issueA(k0 + 32);
            stageGL(k0 + 32, p ^ 1);
        }
        domfma(p);
        if (more && AK != 2) { cvtA(); writeA(p ^ 1); }
        __syncthreads();
        p ^= 1;
    }

#pragma unroll
    for (int mt = 0; mt < 4; ++mt) {
        const int row = m0 + wm * 64 + mt * 16 + lg * 4;
#pragma unroll
        for (int nt = 0; nt < 4; ++nt) {
            const int col = n0 + wn * 64 + nt * 16 + lr;
            if (Ncap == 0 || col < Ncap) {
#pragma unroll
                for (int j = 0; j < 4; ++j) {
                    float v = acc[mt][nt][j];
                    if (EPI == 1) {
                        v += bias[col];
                        v = (v > 20.f) ? v : __logf(1.f + __expf(v));
                    }
                    if (ATOMIC) atomicAdd(&C[(size_t)(row + j) * ldc + col], v);
                    else        C[(size_t)(row + j) * ldc + col] = v;
                }
            }
        }
    }
}

// ---------------------------------------------------------------------------
// Pack W [Kd][Nd] fp32 -> hi/lo f16 B-panels [Nd/16][Kd/32][512].
// ---------------------------------------------------------------------------
__global__ __launch_bounds__(128) void pack_bp(
    const float* __restrict__ W, _Float16* __restrict__ Ph,
    _Float16* __restrict__ Pl, int Kd, int Nd)
{
    __shared__ float t[32][33];
    const int tid = threadIdx.x;
    const int n0 = blockIdx.x * 32, k0 = blockIdx.y * 32;
#pragma unroll
    for (int h = 0; h < 2; ++h) {
        const int qd = tid + h * 128;
        const int kk = qd >> 3, qq = qd & 7;
        *(float4*)&t[kk][qq * 4] = *(const float4*)(W + (size_t)(k0 + kk) * Nd + n0 + qq * 4);
    }
    __syncthreads();
    const int c = tid >> 5, nn = tid & 31;
    const int np = (n0 + nn) >> 4;
    const int r  = nn & 15;
    const int kp = k0 >> 5;
    const size_t base = ((size_t)np * (Kd >> 5) + kp) * 512 + (c * 16 + r) * 8;
    f16x8 vh, vl;
#pragma unroll
    for (int j = 0; j < 8; ++j) {
        const float v = t[c * 8 + j][nn];
        const _Float16 h = (_Float16)v;
        vh[j] = h;
        vl[j] = (_Float16)(v - (float)h);
    }
    *(f16x8*)&Ph[base] = vh;
    *(f16x8*)&Pl[base] = vl;
}

// ---------------------------------------------------------------------------
// Pack A fp32 [M][K] row-major -> hi f16 A-panels [M/16][K/32][512].
// ---------------------------------------------------------------------------
__global__ __launch_bounds__(256) void pack_ap(
    const float* __restrict__ A, int lda,
    _Float16* __restrict__ Ph, int Kd)
{
    const int tid = threadIdx.x;
    const int mp = blockIdx.x;
    const int r = tid >> 4, c8 = tid & 15;
    const int k0 = blockIdx.y * 128 + c8 * 8;
    const float* Ap = A + (size_t)(mp * 16 + r) * lda + k0;
    const float4 v0 = *(const float4*)Ap;
    const float4 v1 = *(const float4*)(Ap + 4);
    const float x[8] = {v0.x, v0.y, v0.z, v0.w, v1.x, v1.y, v1.z, v1.w};
    f16x8 vh;
#pragma unroll
    for (int j = 0; j < 8; ++j) vh[j] = (_Float16)x[j];
    const int kp = k0 >> 5;
    const int c  = (k0 >> 3) & 3;
    const size_t base = ((size_t)mp * (Kd >> 5) + kp) * 512 + (c * 16 + r) * 8;
    *(f16x8*)&Ph[base] = vh;
}

// ---------------------------------------------------------------------------
// Causal depthwise conv (K=4) + bias + silu (4ch x 8t / thread); zeroes ssm.
// ---------------------------------------------------------------------------
__global__ __launch_bounds__(256) void conv_silu_kernel(
    const float* __restrict__ proj,
    const float* __restrict__ xtail_in,
    float* __restrict__ xtail_out,
    const float* __restrict__ w,
    const float* __restrict__ b,
    float* __restrict__ xconv,
    float* __restrict__ ssm,
    int first)
{
    const int gid = blockIdx.x * 256 + threadIdx.x;
    if (gid < (LC * 160) / 4)
        *(float4*)(ssm + (size_t)gid * 4) = make_float4(0.f, 0.f, 0.f, 0.f);

    const int i4 = gid & (I_DIM / 4 - 1);
    const int t8 = gid >> 10;
    const int i = i4 * 4;
    const int tt0 = t8 * 8;

    const float4 w0 = *(const float4*)(w + (size_t)(i + 0) * 4);
    const float4 w1 = *(const float4*)(w + (size_t)(i + 1) * 4);
    const float4 w2 = *(const float4*)(w + (size_t)(i + 2) * 4);
    const float4 w3 = *(const float4*)(w + (size_t)(i + 3) * 4);
    const float4 bb = *(const float4*)(b + i);

    float4 r[11];
    if (tt0 >= 3) {
#pragma unroll
        for (int s = 0; s < 11; ++s)
            r[s] = *(const float4*)(proj + (size_t)(tt0 - 3 + s) * (2 * I_DIM) + i);
    } else {
#pragma unroll
        for (int s = 0; s < 3; ++s)
            r[s] = first ? make_float4(0.f, 0.f, 0.f, 0.f)
                         : *(const float4*)(xtail_in + (size_t)s * I_DIM + i);
#pragma unroll
        for (int s = 3; s < 11; ++s)
            r[s] = *(const float4*)(proj + (size_t)(tt0 - 3 + s) * (2 * I_DIM) + i);
    }

#pragma unroll
    for (int s = 0; s < 8; ++s) {
        float4 y = bb;
        y.x = fmaf(w0.x, r[s].x, y.x); y.x = fmaf(w0.y, r[s+1].x, y.x);
        y.x = fmaf(w0.z, r[s+2].x, y.x); y.x = fmaf(w0.w, r[s+3].x, y.x);
        y.y = fmaf(w1.x, r[s].y, y.y); y.y = fmaf(w1.y, r[s+1].y, y.y);
        y.y = fmaf(w1.z, r[s+2].y, y.y); y.y = fmaf(w1.w, r[s+3].y, y.y);
        y.z = fmaf(w2.x, r[s].z, y.z); y.z = fmaf(w2.y, r[s+1].z, y.z);
        y.z = fmaf(w2.z, r[s+2].z, y.z); y.z = fmaf(w2.w, r[s+3].z, y.z);
        y.w = fmaf(w3.x, r[s].w, y.w); y.w = fmaf(w3.y, r[s+1].w, y.w);
        y.w = fmaf(w3.z, r[s+2].w, y.w); y.w = fmaf(w3.w, r[s+3].w, y.w);
        y.x = y.x / (1.f + __expf(-y.x));
        y.y = y.y / (1.f + __expf(-y.y));
        y.z = y.z / (1.f + __expf(-y.z));
        y.w = y.w / (1.f + __expf(-y.w));
        *(float4*)(xconv + (size_t)(tt0 + s) * I_DIM + i) = y;
    }

    if (tt0 == LC - 8) {
#pragma unroll
        for (int qq = 0; qq < 3; ++qq)
            *(float4*)(xtail_out + (size_t)qq * I_DIM + i) = r[8 + qq];
    }
}

// ---------------------------------------------------------------------------
// Segment-parallel scan.
// ---------------------------------------------------------------------------
__global__ __launch_bounds__(256) void scan_part1(
    const float* __restrict__ delta,
    const float* __restrict__ ssm,
    const float* __restrict__ xc,
    const float* __restrict__ A_log,
    float* __restrict__ aprod,
    float* __restrict__ hend)
{
    __shared__ float Bs[TSEG][16];
    const int tid = threadIdx.x;
    const int i = blockIdx.x * 128 + (tid >> 1);
    const int half = tid & 1;
    const int seg = blockIdx.y;
    const int t0 = seg * TSEG;

    {
        const int tt = tid >> 2, c = (tid & 3) * 4;
        *(float4*)&Bs[tt][c] = *(const float4*)&ssm[(size_t)(t0 + tt) * 160 + 128 + c];
    }
    __syncthreads();

    float Ai[8], h[8], ap[8];
    {
        const float4 a0 = *(const float4*)&A_log[(size_t)i * 16 + half * 8];
        const float4 a1 = *(const float4*)&A_log[(size_t)i * 16 + half * 8 + 4];
        const float al[8] = {a0.x, a0.y, a0.z, a0.w, a1.x, a1.y, a1.z, a1.w};
#pragma unroll
        for (int n = 0; n < 8; ++n) { Ai[n] = -expf(al[n]); h[n] = 0.f; ap[n] = 1.f; }
    }

    float d0 = delta[(size_t)t0 * (2 * I_DIM) + i];
    float u0 = xc[(size_t)t0 * I_DIM + i];
    float d1 = delta[(size_t)(t0 + 1) * (2 * I_DIM) + i];
    float u1 = xc[(size_t)(t0 + 1) * I_DIM + i];
    for (int t = 0; t < TSEG; t += 2) {
        float d2 = 0.f, u2 = 0.f, d3 = 0.f, u3 = 0.f;
        if (t + 3 < TSEG) {
            d2 = delta[(size_t)(t0 + t + 2) * (2 * I_DIM) + i];
            u2 = xc[(size_t)(t0 + t + 2) * I_DIM + i];
            d3 = delta[(size_t)(t0 + t + 3) * (2 * I_DIM) + i];
            u3 = xc[(size_t)(t0 + t + 3) * I_DIM + i];
        }
        {
            const float du = d0 * u0;
#pragma unroll
            for (int n = 0; n < 8; ++n) {
                const float a = __expf(d0 * Ai[n]);
                h[n] = fmaf(h[n], a, du * Bs[t][half * 8 + n]);
                ap[n] *= a;
            }
        }
        {
            const float du = d1 * u1;
#pragma unroll
            for (int n = 0; n < 8; ++n) {
                const float a = __expf(d1 * Ai[n]);
                h[n] = fmaf(h[n], a, du * Bs[t + 1][half * 8 + n]);
                ap[n] *= a;
            }
        }
        d0 = d2; u0 = u2; d1 = d3; u1 = u3;
    }

    const size_t base = (size_t)seg * IN_DIM + (size_t)i * 16 + half * 8;
#pragma unroll
    for (int qq = 0; qq < 2; ++qq) {
        float4 va = {ap[qq * 4 + 0], ap[qq * 4 + 1], ap[qq * 4 + 2], ap[qq * 4 + 3]};
        float4 vh = {h[qq * 4 + 0], h[qq * 4 + 1], h[qq * 4 + 2], h[qq * 4 + 3]};
        *(float4*)&aprod[base + qq * 4] = va;
        *(float4*)&hend[base + qq * 4]  = vh;
    }
}

__global__ __launch_bounds__(256) void scan_part2(
    const float* __restrict__ aprod,
    float* __restrict__ hend,
    float* __restrict__ hstate,
    int first)
{
    const int gid = blockIdx.x * 256 + threadIdx.x;
    float h = first ? 0.f : hstate[gid];
    for (int s = 0; s < SEG; ++s) {
        const int idx = s * IN_DIM + gid;
        const float ap = aprod[idx];
        const float he = hend[idx];
        hend[idx] = h;
        h = fmaf(ap, h, he);
    }
    hstate[gid] = h;
}

// Phase 3: re-run segment from h_start; z (f16-hi) written in GEMM4 A-panel
// layout; also zeroes out_c (aprod/hstart slices this thread owns).
__global__ __launch_bounds__(256) void scan_part3(
    const float* __restrict__ delta,
    const float* __restrict__ gate,
    const float* __restrict__ ssm,
    const float* __restrict__ xc,
    _Float16* __restrict__ zPh,
    const float* __restrict__ A_log,
    const float* __restrict__ Dp,
    float* __restrict__ outz)          // out_c base: [aprod | hstart]
{
    __shared__ float BCs[TSEG][32];
    const int tid = threadIdx.x;
    const int i = blockIdx.x * 128 + (tid >> 1);
    const int half = tid & 1;
    const int seg = blockIdx.y;
    const int t0 = seg * TSEG;

    {
        const int tt = tid >> 2, c = (tid & 3) * 8;
        *(float4*)&BCs[tt][c]     = *(const float4*)&ssm[(size_t)(t0 + tt) * 160 + 128 + c];
        *(float4*)&BCs[tt][c + 4] = *(const float4*)&ssm[(size_t)(t0 + tt) * 160 + 132 + c];
    }
    __syncthreads();

    const size_t base = (size_t)seg * IN_DIM + (size_t)i * 16 + half * 8;
    float* hstart = outz + (size_t)SEG * IN_DIM;

    float Ai[8], h[8];
    {
        const float4 a0 = *(const float4*)&A_log[(size_t)i * 16 + half * 8];
        const float4 a1 = *(const float4*)&A_log[(size_t)i * 16 + half * 8 + 4];
        const float al[8] = {a0.x, a0.y, a0.z, a0.w, a1.x, a1.y, a1.z, a1.w};
#pragma unroll
        for (int n = 0; n < 8; ++n) Ai[n] = -expf(al[n]);
        const float4 h0 = *(const float4*)&hstart[base];
        const float4 h1 = *(const float4*)&hstart[base + 4];
        h[0] = h0.x; h[1] = h0.y; h[2] = h0.z; h[3] = h0.w;
        h[4] = h1.x; h[5] = h1.y; h[6] = h1.z; h[7] = h1.w;
    }
    {
        const float4 z4 = {0.f, 0.f, 0.f, 0.f};
        *(float4*)&outz[base]       = z4;
        *(float4*)&outz[base + 4]   = z4;
        *(float4*)&hstart[base]     = z4;
        *(float4*)&hstart[base + 4] = z4;
    }
    const float Di = Dp[i];

    const int kp = i >> 5, cc = (i >> 3) & 3, jj = i & 7;
    const size_t zb = (size_t)kp * 512 + (size_t)cc * 128 + jj;

    float d0 = delta[(size_t)t0 * (2 * I_DIM) + i];
    float u0 = xc[(size_t)t0 * I_DIM + i];
    float g0 = gate[(size_t)t0 * (2 * I_DIM) + i];
    float d1 = delta[(size_t)(t0 + 1) * (2 * I_DIM) + i];
    float u1 = xc[(size_t)(t0 + 1) * I_DIM + i];
    float g1 = gate[(size_t)(t0 + 1) * (2 * I_DIM) + i];
    for (int t = 0; t < TSEG; t += 2) {
        float d2 = 0.f, u2 = 0.f, g2 = 0.f, d3 = 0.f, u3 = 0.f, g3 = 0.f;
        if (t + 3 < TSEG) {
            d2 = delta[(size_t)(t0 + t + 2) * (2 * I_DIM) + i];
            u2 = xc[(size_t)(t0 + t + 2) * I_DIM + i];
            g2 = gate[(size_t)(t0 + t + 2) * (2 * I_DIM) + i];
            d3 = delta[(size_t)(t0 + t + 3) * (2 * I_DIM) + i];
            u3 = xc[(size_t)(t0 + t + 3) * I_DIM + i];
            g3 = gate[(size_t)(t0 + t + 3) * (2 * I_DIM) + i];
        }
#pragma unroll
        for (int ss = 0; ss < 2; ++ss) {
            const float d = ss ? d1 : d0;
            const float u = ss ? u1 : u0;
            const float g = ss ? g1 : g0;
            const int tt = t + ss;
            const float du = d * u;
            float y = 0.f;
#pragma unroll
            for (int n = 0; n < 8; ++n) {
                const float a = __expf(d * Ai[n]);
                h[n] = fmaf(h[n], a, du * BCs[tt][half * 8 + n]);
                y = fmaf(h[n], BCs[tt][16 + half * 8 + n], y);
            }
            y += __shfl_xor(y, 1);
            if (half == 0) {
                const float sg = g / (1.f + __expf(-g));
                const float zv = (y + u * Di) * sg;
                const int row = t0 + tt;
                zPh[((size_t)(row >> 4) * (I_DIM >> 5)) * 512 + zb + (size_t)(row & 15) * 8]
                    = (_Float16)zv;
            }
        }
        d0 = d2; u0 = u2; g0 = g2; d1 = d3; u1 = u3; g1 = g3;
    }
}

// ---------------------------------------------------------------------------
extern "C" void kernel_launch(void* const* d_in, const int* in_sizes, int n_in,
                              void* d_out, int out_size, void* d_ws, size_t ws_size,
                              hipStream_t stream)
{
    const float* hs      = (const float*)d_in[0];
    const float* W_in    = (const float*)d_in[1];
    const float* conv_w  = (const float*)d_in[2];
    const float* conv_b  = (const float*)d_in[3];
    const float* W_x     = (const float*)d_in[4];
    const float* W_dt    = (const float*)d_in[5];
    const float* dt_bias = (const float*)d_in[6];
    const float* A_log   = (const float*)d_in[7];
    const float* Dp      = (const float*)d_in[8];
    const float* W_out   = (const float*)d_in[9];
    float* out = (float*)d_out;

    // workspace layout (~230 MB, known-good footprint)
    char* p = (char*)d_ws;
    auto alloc = [&](size_t bytes) {
        char* r = p;
        p += (bytes + 255) & ~(size_t)255;
        return r;
    };
    float* proj   = (float*)alloc((size_t)LC * 2 * I_DIM * 4);   // 64 MB
    float* xconv  = (float*)alloc((size_t)LC * I_DIM * 4);       // 32 MB
    float* ssm    = (float*)alloc((size_t)LC * 160 * 4);
    float* xtail  = (float*)alloc((size_t)2 * 3 * I_DIM * 4);
    float* hstate = (float*)alloc((size_t)IN_DIM * 4);
    _Float16* WinPh  = (_Float16*)alloc((size_t)2 * I_DIM * H_DIM * 2);  // 32 MB
    _Float16* WinPl  = (_Float16*)alloc((size_t)2 * I_DIM * H_DIM * 2);
    _Float16* WoutPh = (_Float16*)alloc((size_t)H_DIM * I_DIM * 2);      // 16 MB
    _Float16* WoutPl = (_Float16*)alloc((size_t)H_DIM * I_DIM * 2);
    _Float16* WdtPh  = (_Float16*)alloc((size_t)I_DIM * R_DIM * 2);
    _Float16* WdtPl  = (_Float16*)alloc((size_t)I_DIM * R_DIM * 2);
    _Float16* WxPh   = (_Float16*)alloc((size_t)256 * I_DIM * 2);
    _Float16* WxPl   = (_Float16*)alloc((size_t)256 * I_DIM * 2);
    _Float16* hsPh   = (_Float16*)alloc((size_t)LC * H_DIM * 2);   // 8 MB
    _Float16* zPh    = (_Float16*)alloc((size_t)LC * I_DIM * 2);   // 16 MB

    const dim3 blk(256);
    const int NSSM = R_DIM + 2 * N_DIM;  // 160

    // ---- pack weights into panel format (once per launch) ----
    pack_bp<<<dim3(2 * I_DIM / 32, H_DIM / 32), dim3(128), 0, stream>>>(
        W_in, WinPh, WinPl, H_DIM, 2 * I_DIM);
    pack_bp<<<dim3(H_DIM / 32, I_DIM / 32), dim3(128), 0, stream>>>(
        W_out, WoutPh, WoutPl, I_DIM, H_DIM);
    pack_bp<<<dim3(I_DIM / 32, R_DIM / 32), dim3(128), 0, stream>>>(
        W_dt, WdtPh, WdtPl, R_DIM, I_DIM);
    pack_bp<<<dim3(NSSM / 32, I_DIM / 32), dim3(128), 0, stream>>>(
        W_x, WxPh, WxPl, I_DIM, NSSM);

    for (int c = 0; c < NCHUNK; ++c) {
        const int t0 = c * LC;
        const int first = (c == 0) ? 1 : 0;
        const float* hs_c = hs + (size_t)t0 * H_DIM;
        float* out_c = out + (size_t)t0 * H_DIM;
        float* aprod = out_c;                 // scan scratch in out region
        float* hend  = out_c + (size_t)SEG * IN_DIM;
        float* xtA = xtail + (size_t)(c & 1) * 3 * I_DIM;
        float* xtB = xtail + (size_t)((c & 1) ^ 1) * 3 * I_DIM;

        // 0) pack hs chunk into A panels (hi only)
        pack_ap<<<dim3(LC / 16, H_DIM / 128), blk, 0, stream>>>(
            hs_c, H_DIM, hsPh, H_DIM);

        // 1) proj = hs_c @ W_in  (256x256 tile, A-hi x B-hi) -> 256 blocks
        gemm_p256<<<dim3(256), dim3(512), 0, stream>>>(
            hsPh, WinPh, proj, 2 * I_DIM, H_DIM, LC / 256);

        // 2) xconv = silu(dwconv(x_pre) + b); zeroes ssm; saves tail
        conv_silu_kernel<<<dim3(1024), blk, 0, stream>>>(
            proj, xtA, xtB, conv_w, conv_b, xconv, ssm, first);

        // 3) ssm = xconv @ W_x  (full split, split-K x8, atomics)
        gemm_p<0, 0, 1, 1, true><<<dim3(32, 8), blk, 0, stream>>>(
            xconv, I_DIM, nullptr, WxPh, WxPl, ssm, NSSM,
            I_DIM, NSSM, LC / 128, I_DIM / 8, nullptr);

        // 4) delta = softplus(ssm[:, :R] @ W_dt + dt_bias) -> proj[:, :I]
        gemm_p<1, 0, 1, 1, false><<<dim3(512, 1), blk, 0, stream>>>(
            ssm, NSSM, nullptr, WdtPh, WdtPl, proj, 2 * I_DIM,
            R_DIM, 0, LC / 128, R_DIM, dt_bias);

        // 5) segment-parallel scan; z -> zPh panels; part3 zeroes out_c
        scan_part1<<<dim3(I_DIM / 128, SEG), blk, 0, stream>>>(
            proj, ssm, xconv, A_log, aprod, hend);
        scan_part2<<<dim3(IN_DIM / 256), blk, 0, stream>>>(
            aprod, hend, hstate, first);
        scan_part3<<<dim3(I_DIM / 128, SEG), blk, 0, stream>>>(
            proj, proj + I_DIM, ssm, xconv, zPh, A_log, Dp, out_c);

        // 6) out_c = z @ W_out  (A-hi x B-hi, pure gl_lds, split-K x4)
        gemm_p<0, 2, 0, 0, true><<<dim3(256, 4), blk, 0, stream>>>(
            nullptr, 0, zPh, WoutPh, nullptr, out_c, H_DIM,
            I_DIM, 0, LC / 128, I_DIM / 4, nullptr);
    }
}

// Round 13
// 1117.313 us; speedup vs baseline: 4.5582x; 1.0917x over previous
//
#include <hip/hip_runtime.h>
#include <cmath>
#include <stdint.h>

#define H_DIM 2048
#define I_DIM 4096
#define N_DIM 16
#define R_DIM 128
#define K_CONV 4
#define L_DIM 8192
#define LC 2048                 // chunk length
#define NCHUNK (L_DIM / LC)
#define SEG 32                  // scan segments per chunk
#define TSEG (LC / SEG)         // 64 steps per segment
#define IN_DIM (I_DIM * N_DIM)  // 65536 recurrences

typedef _Float16 f16x8 __attribute__((ext_vector_type(8)));
typedef float    f32x4 __attribute__((ext_vector_type(4)));

// direct HBM->LDS, 16B per lane; LDS base must be wave-uniform (HW adds lane*16)
__device__ __forceinline__ void gl_lds(const _Float16* g, _Float16* lbase, int lane) {
#if __has_builtin(__builtin_amdgcn_global_load_lds)
    __builtin_amdgcn_global_load_lds(
        (const __attribute__((address_space(1))) void*)g,
        (__attribute__((address_space(3))) void*)lbase, 16, 0, 0);
#else
    *(f16x8*)&lbase[lane * 8] = *(const f16x8*)g;
#endif
}

// ---------------------------------------------------------------------------
// 256x256 panel GEMM (GEMM1 & GEMM4): A hi panels x B hi panels (1 MFMA/pair).
// 512 threads = 8 waves (4m x 2n), wave tile 64x128. BK=32.
// 3-buffer counted-vmcnt pipeline (96KB LDS, 1 block/CU): stage k+2 in
// flight; vmcnt(8) = own stage-k loads landed; barrier = all waves' landed.
// Split-K via blockIdx.y*kchunk, partial output at C + y*partStride (plain
// stores, no atomics).
// ---------------------------------------------------------------------------
__global__ __launch_bounds__(512, 1) void gemm_p256(
    const _Float16* __restrict__ Aph,
    const _Float16* __restrict__ Bph,
    float* __restrict__ C, int ldc, int Kd, int gm,
    int kchunk, size_t partStride)
{
    __shared__ __align__(16) _Float16 Sh[3][2][8192];  // [buf][Ah,Bh][16 panels]

    const int tid = threadIdx.x;
    int bid = blockIdx.x;
    const int q = gridDim.x >> 3;
    bid = (bid & 7) * q + (bid >> 3);    // bijective XCD swizzle (grid % 8 == 0)
    const int m0 = (bid % gm) * 256;
    const int n0 = (bid / gm) * 256;

    const int kbeg = blockIdx.y * kchunk;
    C += (size_t)blockIdx.y * partStride;

    const int w = tid >> 6, l = tid & 63;
    const int wm = w & 3, wn = w >> 2;   // 4m x 2n waves
    const int lr = l & 15, lg = l >> 4;

    const int KP = Kd >> 5;
    const int np0 = n0 >> 4, mp0 = m0 >> 4;
    const int st0 = w;                   // wave id = panel group

    f32x4 acc[4][8];
#pragma unroll
    for (int a = 0; a < 4; ++a)
#pragma unroll
        for (int b = 0; b < 8; ++b) acc[a][b] = (f32x4){0.f, 0.f, 0.f, 0.f};

    auto stage = [&](int k0, int p) {    // 4 gl_lds / thread
        const int kp = k0 >> 5;
#pragma unroll
        for (int s = 0; s < 2; ++s) {
            const int st = st0 + s * 8;  // 16 panels per array
            gl_lds(Aph + ((size_t)(mp0 + st) * KP + kp) * 512 + (size_t)l * 8,
                   &Sh[p][0][st * 512], l);
            gl_lds(Bph + ((size_t)(np0 + st) * KP + kp) * 512 + (size_t)l * 8,
                   &Sh[p][1][st * 512], l);
        }
    };
    auto domfma = [&](int b) {
        f16x8 fah[4];
#pragma unroll
        for (int t = 0; t < 4; ++t)
            fah[t] = *(const f16x8*)&Sh[b][0][(wm * 4 + t) * 512 + l * 8];
        __builtin_amdgcn_s_setprio(1);
#pragma unroll
        for (int nh = 0; nh < 2; ++nh) {
            f16x8 fbh[4];
#pragma unroll
            for (int t = 0; t < 4; ++t)
                fbh[t] = *(const f16x8*)&Sh[b][1][(wn * 8 + nh * 4 + t) * 512 + l * 8];
#pragma unroll
            for (int mt = 0; mt < 4; ++mt)
#pragma unroll
                for (int nt = 0; nt < 4; ++nt)
                    acc[mt][nh * 4 + nt] = __builtin_amdgcn_mfma_f32_16x16x32_f16(
                        fah[mt], fbh[nt], acc[mt][nh * 4 + nt], 0, 0, 0);
        }
        __builtin_amdgcn_s_setprio(0);
    };

    const int KT = kchunk >> 5;          // >= 2 required
    stage(kbeg, 0);
    stage(kbeg + 32, 1);
    for (int k = 0; k + 2 < KT; ++k) {
        stage(kbeg + (k + 2) * 32, (k + 2) % 3);        // 12 in flight
        asm volatile("s_waitcnt vmcnt(8)" ::: "memory"); // own stage-k landed
        __builtin_amdgcn_s_barrier();                    // all waves' landed
        __builtin_amdgcn_sched_barrier(0);
        domfma(k % 3);
        __builtin_amdgcn_s_barrier();                    // reads done before restage
    }
    asm volatile("s_waitcnt vmcnt(4)" ::: "memory");
    __builtin_amdgcn_s_barrier();
    __builtin_amdgcn_sched_barrier(0);
    domfma((KT - 2) % 3);
    __builtin_amdgcn_s_barrier();
    asm volatile("s_waitcnt vmcnt(0)" ::: "memory");
    __builtin_amdgcn_s_barrier();
    __builtin_amdgcn_sched_barrier(0);
    domfma((KT - 1) % 3);

#pragma unroll
    for (int mt = 0; mt < 4; ++mt) {
        const int row = m0 + wm * 64 + mt * 16 + lg * 4;
#pragma unroll
        for (int nt = 0; nt < 8; ++nt) {
            const int col = n0 + wn * 128 + nt * 16 + lr;
#pragma unroll
            for (int j = 0; j < 4; ++j)
                C[(size_t)(row + j) * ldc + col] = acc[mt][nt][j];
        }
    }
}

// ---------------------------------------------------------------------------
// out = P0 + P1 + P2 + P3  (4 partial LC x H buffers, float4 vectorized)
// ---------------------------------------------------------------------------
__global__ __launch_bounds__(256) void reduce4_kernel(
    const float* __restrict__ P, float* __restrict__ out)
{
    const size_t idx = ((size_t)blockIdx.x * 256 + threadIdx.x) * 4;
    const size_t S = (size_t)LC * H_DIM;
    const float4 a = *(const float4*)(P + idx);
    const float4 b = *(const float4*)(P + S + idx);
    const float4 c = *(const float4*)(P + 2 * S + idx);
    const float4 d = *(const float4*)(P + 3 * S + idx);
    float4 r;
    r.x = (a.x + b.x) + (c.x + d.x);
    r.y = (a.y + b.y) + (c.y + d.y);
    r.z = (a.z + b.z) + (c.z + d.z);
    r.w = (a.w + b.w) + (c.w + d.w);
    *(float4*)(out + idx) = r;
}

// ---------------------------------------------------------------------------
// 128x128 panel GEMM (GEMM2/3), 2-buffer schedule.
// AK=0 fp32 reg-split. ASPLIT/BSPLIT: include lo-correction MFMA for A/B.
// ---------------------------------------------------------------------------
template <int EPI, int AK, int ASPLIT, int BSPLIT, bool ATOMIC>
__global__ __launch_bounds__(256, ASPLIT ? 2 : (BSPLIT ? 3 : 4)) void gemm_p(
    const void* __restrict__ Av, int lda,
    const _Float16* __restrict__ Aph,
    const _Float16* __restrict__ Bph, const _Float16* __restrict__ Bpl,
    float* __restrict__ C, int ldc,
    int Kd, int Ncap, int gm, int kchunk,
    const float* __restrict__ bias)
{
    constexpr int S_AH = 0;
    constexpr int S_AL = ASPLIT ? 1 : 0;
    constexpr int S_BH = ASPLIT ? 2 : 1;
    constexpr int S_BL = S_BH + 1;           // valid only if BSPLIT
    constexpr int NSLOT = S_BH + 1 + BSPLIT;
    __shared__ __align__(16) _Float16 Sh[2][NSLOT][4096];

    const int tid = threadIdx.x;
    int bid = blockIdx.x;
    const int q = gridDim.x >> 3;
    bid = (bid & 7) * q + (bid >> 3);
    const int m0 = (bid % gm) * 128;
    const int n0 = (bid / gm) * 128;

    const int kbeg = blockIdx.y * kchunk;
    const int kend = (kbeg + kchunk < Kd) ? (kbeg + kchunk) : Kd;

    const int w = tid >> 6, l = tid & 63;
    const int wm = w & 1, wn = w >> 1;
    const int lr = l & 15, lg = l >> 4;

    const int ar = tid >> 1, ah = tid & 1;
    const int aw0 = (ar >> 4) * 512 + (((ah * 2) * 16 + (ar & 15)) * 8);
    const int aw1 = aw0 + 128;

    const int KP = Kd >> 5;
    const int np0 = n0 >> 4;
    const int mp0 = m0 >> 4;

    f32x4 acc[4][4];
#pragma unroll
    for (int a = 0; a < 4; ++a)
#pragma unroll
        for (int b = 0; b < 4; ++b) acc[a][b] = (f32x4){0.f, 0.f, 0.f, 0.f};

    float xf[16];
    f16x8 sah[2], sal[2];

    auto issueA = [&](int k0) {
        if (AK == 0) {
            const float* Ap = (const float*)Av + (size_t)(m0 + ar) * lda + k0 + ah * 16;
            *(float4*)&xf[0]  = *(const float4*)(Ap + 0);
            *(float4*)&xf[4]  = *(const float4*)(Ap + 4);
            *(float4*)&xf[8]  = *(const float4*)(Ap + 8);
            *(float4*)&xf[12] = *(const float4*)(Ap + 12);
        }
    };
    auto cvtA = [&]() {
        if (AK == 0) {
#pragma unroll
            for (int c2 = 0; c2 < 2; ++c2)
#pragma unroll
                for (int j = 0; j < 8; ++j) {
                    const float xv = xf[c2 * 8 + j];
                    const _Float16 h = (_Float16)xv;
                    sah[c2][j] = h;
                    if (ASPLIT) sal[c2][j] = (_Float16)(xv - (float)h);
                }
        }
    };
    auto writeA = [&](int p) {
        *(f16x8*)&Sh[p][S_AH][aw0] = sah[0];
        *(f16x8*)&Sh[p][S_AH][aw1] = sah[1];
        if (ASPLIT) {
            *(f16x8*)&Sh[p][S_AL][aw0] = sal[0];
            *(f16x8*)&Sh[p][S_AL][aw1] = sal[1];
        }
    };
    auto stageGL = [&](int k0, int p) {
        const int kp = k0 >> 5;
        if (AK == 2) {
#pragma unroll
            for (int s = 0; s < 2; ++s) {
                const int st = w + s * 4;
                const size_t ga = ((size_t)(mp0 + st) * KP + kp) * 512 + (size_t)l * 8;
                gl_lds(Aph + ga, &Sh[p][S_AH][st * 512], l);
            }
        }
#pragma unroll
        for (int qq = 0; qq < 2; ++qq) {
            const int st = 2 * w + qq;
            const size_t go = ((size_t)(np0 + st) * KP + kp) * 512 + (size_t)l * 8;
            gl_lds(Bph + go, &Sh[p][S_BH][st * 512], l);
            if (BSPLIT) gl_lds(Bpl + go, &Sh[p][S_BL][st * 512], l);
        }
    };
    auto domfma = [&](int b) {
        f16x8 fah[4], fal[4], fbh[4], fbl[4];
#pragma unroll
        for (int t = 0; t < 4; ++t) {
            fah[t] = *(const f16x8*)&Sh[b][S_AH][(wm * 4 + t) * 512 + l * 8];
            if (ASPLIT) fal[t] = *(const f16x8*)&Sh[b][S_AL][(wm * 4 + t) * 512 + l * 8];
            fbh[t] = *(const f16x8*)&Sh[b][S_BH][(wn * 4 + t) * 512 + l * 8];
            if (BSPLIT) fbl[t] = *(const f16x8*)&Sh[b][S_BL][(wn * 4 + t) * 512 + l * 8];
        }
        __builtin_amdgcn_s_setprio(1);
#pragma unroll
        for (int mt = 0; mt < 4; ++mt)
#pragma unroll
            for (int nt = 0; nt < 4; ++nt) {
                f32x4& a = acc[mt][nt];
                a = __builtin_amdgcn_mfma_f32_16x16x32_f16(fah[mt], fbh[nt], a, 0, 0, 0);
                if (BSPLIT)
                    a = __builtin_amdgcn_mfma_f32_16x16x32_f16(fah[mt], fbl[nt], a, 0, 0, 0);
                if (ASPLIT)
                    a = __builtin_amdgcn_mfma_f32_16x16x32_f16(fal[mt], fbh[nt], a, 0, 0, 0);
            }
        __builtin_amdgcn_s_setprio(0);
    };

    if (AK != 2) { issueA(kbeg); cvtA(); writeA(0); }
    stageGL(kbeg, 0);
    __syncthreads();
    int p = 0;
    for (int k0 = kbeg; k0 < kend; k0 += 32) {
        const bool more = (k0 + 32 < kend);
        if (more) {
            if (AK != 2) issueA(k0 + 32);
            stageGL(k0 + 32, p ^ 1);
        }
        domfma(p);
        if (more && AK != 2) { cvtA(); writeA(p ^ 1); }
        __syncthreads();
        p ^= 1;
    }

#pragma unroll
    for (int mt = 0; mt < 4; ++mt) {
        const int row = m0 + wm * 64 + mt * 16 + lg * 4;
#pragma unroll
        for (int nt = 0; nt < 4; ++nt) {
            const int col = n0 + wn * 64 + nt * 16 + lr;
            if (Ncap == 0 || col < Ncap) {
#pragma unroll
                for (int j = 0; j < 4; ++j) {
                    float v = acc[mt][nt][j];
                    if (EPI == 1) {
                        v += bias[col];
                        v = (v > 20.f) ? v : __logf(1.f + __expf(v));
                    }
                    if (ATOMIC) atomicAdd(&C[(size_t)(row + j) * ldc + col], v);
                    else        C[(size_t)(row + j) * ldc + col] = v;
                }
            }
        }
    }
}

// ---------------------------------------------------------------------------
// Pack W [Kd][Nd] fp32 -> f16 B-panels [Nd/16][Kd/32][512]; lo only if Pl.
// ---------------------------------------------------------------------------
__global__ __launch_bounds__(128) void pack_bp(
    const float* __restrict__ W, _Float16* __restrict__ Ph,
    _Float16* __restrict__ Pl, int Kd, int Nd)
{
    __shared__ float t[32][33];
    const int tid = threadIdx.x;
    const int n0 = blockIdx.x * 32, k0 = blockIdx.y * 32;
#pragma unroll
    for (int h = 0; h < 2; ++h) {
        const int qd = tid + h * 128;
        const int kk = qd >> 3, qq = qd & 7;
        *(float4*)&t[kk][qq * 4] = *(const float4*)(W + (size_t)(k0 + kk) * Nd + n0 + qq * 4);
    }
    __syncthreads();
    const int c = tid >> 5, nn = tid & 31;
    const int np = (n0 + nn) >> 4;
    const int r  = nn & 15;
    const int kp = k0 >> 5;
    const size_t base = ((size_t)np * (Kd >> 5) + kp) * 512 + (c * 16 + r) * 8;
    f16x8 vh, vl;
#pragma unroll
    for (int j = 0; j < 8; ++j) {
        const float v = t[c * 8 + j][nn];
        const _Float16 h = (_Float16)v;
        vh[j] = h;
        vl[j] = (_Float16)(v - (float)h);
    }
    *(f16x8*)&Ph[base] = vh;
    if (Pl) *(f16x8*)&Pl[base] = vl;
}

// ---------------------------------------------------------------------------
// Pack A fp32 [M][K] row-major -> hi f16 A-panels [M/16][K/32][512].
// ---------------------------------------------------------------------------
__global__ __launch_bounds__(256) void pack_ap(
    const float* __restrict__ A, int lda,
    _Float16* __restrict__ Ph, int Kd)
{
    const int tid = threadIdx.x;
    const int mp = blockIdx.x;
    const int r = tid >> 4, c8 = tid & 15;
    const int k0 = blockIdx.y * 128 + c8 * 8;
    const float* Ap = A + (size_t)(mp * 16 + r) * lda + k0;
    const float4 v0 = *(const float4*)Ap;
    const float4 v1 = *(const float4*)(Ap + 4);
    const float x[8] = {v0.x, v0.y, v0.z, v0.w, v1.x, v1.y, v1.z, v1.w};
    f16x8 vh;
#pragma unroll
    for (int j = 0; j < 8; ++j) vh[j] = (_Float16)x[j];
    const int kp = k0 >> 5;
    const int c  = (k0 >> 3) & 3;
    const size_t base = ((size_t)mp * (Kd >> 5) + kp) * 512 + (c * 16 + r) * 8;
    *(f16x8*)&Ph[base] = vh;
}

// ---------------------------------------------------------------------------
// Causal depthwise conv (K=4) + bias + silu (4ch x 8t / thread); zeroes ssm.
// ---------------------------------------------------------------------------
__global__ __launch_bounds__(256) void conv_silu_kernel(
    const float* __restrict__ proj,
    const float* __restrict__ xtail_in,
    float* __restrict__ xtail_out,
    const float* __restrict__ w,
    const float* __restrict__ b,
    float* __restrict__ xconv,
    float* __restrict__ ssm,
    int first)
{
    const int gid = blockIdx.x * 256 + threadIdx.x;
    if (gid < (LC * 160) / 4)
        *(float4*)(ssm + (size_t)gid * 4) = make_float4(0.f, 0.f, 0.f, 0.f);

    const int i4 = gid & (I_DIM / 4 - 1);
    const int t8 = gid >> 10;
    const int i = i4 * 4;
    const int tt0 = t8 * 8;

    const float4 w0 = *(const float4*)(w + (size_t)(i + 0) * 4);
    const float4 w1 = *(const float4*)(w + (size_t)(i + 1) * 4);
    const float4 w2 = *(const float4*)(w + (size_t)(i + 2) * 4);
    const float4 w3 = *(const float4*)(w + (size_t)(i + 3) * 4);
    const float4 bb = *(const float4*)(b + i);

    float4 r[11];
    if (tt0 >= 3) {
#pragma unroll
        for (int s = 0; s < 11; ++s)
            r[s] = *(const float4*)(proj + (size_t)(tt0 - 3 + s) * (2 * I_DIM) + i);
    } else {
#pragma unroll
        for (int s = 0; s < 3; ++s)
            r[s] = first ? make_float4(0.f, 0.f, 0.f, 0.f)
                         : *(const float4*)(xtail_in + (size_t)s * I_DIM + i);
#pragma unroll
        for (int s = 3; s < 11; ++s)
            r[s] = *(const float4*)(proj + (size_t)(tt0 - 3 + s) * (2 * I_DIM) + i);
    }

#pragma unroll
    for (int s = 0; s < 8; ++s) {
        float4 y = bb;
        y.x = fmaf(w0.x, r[s].x, y.x); y.x = fmaf(w0.y, r[s+1].x, y.x);
        y.x = fmaf(w0.z, r[s+2].x, y.x); y.x = fmaf(w0.w, r[s+3].x, y.x);
        y.y = fmaf(w1.x, r[s].y, y.y); y.y = fmaf(w1.y, r[s+1].y, y.y);
        y.y = fmaf(w1.z, r[s+2].y, y.y); y.y = fmaf(w1.w, r[s+3].y, y.y);
        y.z = fmaf(w2.x, r[s].z, y.z); y.z = fmaf(w2.y, r[s+1].z, y.z);
        y.z = fmaf(w2.z, r[s+2].z, y.z); y.z = fmaf(w2.w, r[s+3].z, y.z);
        y.w = fmaf(w3.x, r[s].w, y.w); y.w = fmaf(w3.y, r[s+1].w, y.w);
        y.w = fmaf(w3.z, r[s+2].w, y.w); y.w = fmaf(w3.w, r[s+3].w, y.w);
        y.x = y.x / (1.f + __expf(-y.x));
        y.y = y.y / (1.f + __expf(-y.y));
        y.z = y.z / (1.f + __expf(-y.z));
        y.w = y.w / (1.f + __expf(-y.w));
        *(float4*)(xconv + (size_t)(tt0 + s) * I_DIM + i) = y;
    }

    if (tt0 == LC - 8) {
#pragma unroll
        for (int qq = 0; qq < 3; ++qq)
            *(float4*)(xtail_out + (size_t)qq * I_DIM + i) = r[8 + qq];
    }
}

// ---------------------------------------------------------------------------
// Segment-parallel scan.
// ---------------------------------------------------------------------------
__global__ __launch_bounds__(256) void scan_part1(
    const float* __restrict__ delta,
    const float* __restrict__ ssm,
    const float* __restrict__ xc,
    const float* __restrict__ A_log,
    float* __restrict__ aprod,
    float* __restrict__ hend)
{
    __shared__ float Bs[TSEG][16];
    const int tid = threadIdx.x;
    const int i = blockIdx.x * 128 + (tid >> 1);
    const int half = tid & 1;
    const int seg = blockIdx.y;
    const int t0 = seg * TSEG;

    {
        const int tt = tid >> 2, c = (tid & 3) * 4;
        *(float4*)&Bs[tt][c] = *(const float4*)&ssm[(size_t)(t0 + tt) * 160 + 128 + c];
    }
    __syncthreads();

    float Ai[8], h[8], ap[8];
    {
        const float4 a0 = *(const float4*)&A_log[(size_t)i * 16 + half * 8];
        const float4 a1 = *(const float4*)&A_log[(size_t)i * 16 + half * 8 + 4];
        const float al[8] = {a0.x, a0.y, a0.z, a0.w, a1.x, a1.y, a1.z, a1.w};
#pragma unroll
        for (int n = 0; n < 8; ++n) { Ai[n] = -expf(al[n]); h[n] = 0.f; ap[n] = 1.f; }
    }

    float d0 = delta[(size_t)t0 * (2 * I_DIM) + i];
    float u0 = xc[(size_t)t0 * I_DIM + i];
    float d1 = delta[(size_t)(t0 + 1) * (2 * I_DIM) + i];
    float u1 = xc[(size_t)(t0 + 1) * I_DIM + i];
    for (int t = 0; t < TSEG; t += 2) {
        float d2 = 0.f, u2 = 0.f, d3 = 0.f, u3 = 0.f;
        if (t + 3 < TSEG) {
            d2 = delta[(size_t)(t0 + t + 2) * (2 * I_DIM) + i];
            u2 = xc[(size_t)(t0 + t + 2) * I_DIM + i];
            d3 = delta[(size_t)(t0 + t + 3) * (2 * I_DIM) + i];
            u3 = xc[(size_t)(t0 + t + 3) * I_DIM + i];
        }
        {
            const float du = d0 * u0;
#pragma unroll
            for (int n = 0; n < 8; ++n) {
                const float a = __expf(d0 * Ai[n]);
                h[n] = fmaf(h[n], a, du * Bs[t][half * 8 + n]);
                ap[n] *= a;
            }
        }
        {
            const float du = d1 * u1;
#pragma unroll
            for (int n = 0; n < 8; ++n) {
                const float a = __expf(d1 * Ai[n]);
                h[n] = fmaf(h[n], a, du * Bs[t + 1][half * 8 + n]);
                ap[n] *= a;
            }
        }
        d0 = d2; u0 = u2; d1 = d3; u1 = u3;
    }

    const size_t base = (size_t)seg * IN_DIM + (size_t)i * 16 + half * 8;
#pragma unroll
    for (int qq = 0; qq < 2; ++qq) {
        float4 va = {ap[qq * 4 + 0], ap[qq * 4 + 1], ap[qq * 4 + 2], ap[qq * 4 + 3]};
        float4 vh = {h[qq * 4 + 0], h[qq * 4 + 1], h[qq * 4 + 2], h[qq * 4 + 3]};
        *(float4*)&aprod[base + qq * 4] = va;
        *(float4*)&hend[base + qq * 4]  = vh;
    }
}

__global__ __launch_bounds__(256) void scan_part2(
    const float* __restrict__ aprod,
    float* __restrict__ hend,
    float* __restrict__ hstate,
    int first)
{
    const int gid = blockIdx.x * 256 + threadIdx.x;
    float h = first ? 0.f : hstate[gid];
    for (int s = 0; s < SEG; ++s) {
        const int idx = s * IN_DIM + gid;
        const float ap = aprod[idx];
        const float he = hend[idx];
        hend[idx] = h;
        h = fmaf(ap, h, he);
    }
    hstate[gid] = h;
}

// Phase 3: re-run segment from h_start; z (f16-hi) written in GEMM4 A-panel
// layout.
__global__ __launch_bounds__(256) void scan_part3(
    const float* __restrict__ delta,
    const float* __restrict__ gate,
    const float* __restrict__ ssm,
    const float* __restrict__ xc,
    _Float16* __restrict__ zPh,
    const float* __restrict__ A_log,
    const float* __restrict__ Dp,
    const float* __restrict__ hstart)  // [SEG][I][N]
{
    __shared__ float BCs[TSEG][32];
    const int tid = threadIdx.x;
    const int i = blockIdx.x * 128 + (tid >> 1);
    const int half = tid & 1;
    const int seg = blockIdx.y;
    const int t0 = seg * TSEG;

    {
        const int tt = tid >> 2, c = (tid & 3) * 8;
        *(float4*)&BCs[tt][c]     = *(const float4*)&ssm[(size_t)(t0 + tt) * 160 + 128 + c];
        *(float4*)&BCs[tt][c + 4] = *(const float4*)&ssm[(size_t)(t0 + tt) * 160 + 132 + c];
    }
    __syncthreads();

    float Ai[8], h[8];
    {
        const float4 a0 = *(const float4*)&A_log[(size_t)i * 16 + half * 8];
        const float4 a1 = *(const float4*)&A_log[(size_t)i * 16 + half * 8 + 4];
        const float al[8] = {a0.x, a0.y, a0.z, a0.w, a1.x, a1.y, a1.z, a1.w};
#pragma unroll
        for (int n = 0; n < 8; ++n) Ai[n] = -expf(al[n]);
        const size_t base = (size_t)seg * IN_DIM + (size_t)i * 16 + half * 8;
        const float4 h0 = *(const float4*)&hstart[base];
        const float4 h1 = *(const float4*)&hstart[base + 4];
        h[0] = h0.x; h[1] = h0.y; h[2] = h0.z; h[3] = h0.w;
        h[4] = h1.x; h[5] = h1.y; h[6] = h1.z; h[7] = h1.w;
    }
    const float Di = Dp[i];

    const int kp = i >> 5, cc = (i >> 3) & 3, jj = i & 7;
    const size_t zb = (size_t)kp * 512 + (size_t)cc * 128 + jj;

    float d0 = delta[(size_t)t0 * (2 * I_DIM) + i];
    float u0 = xc[(size_t)t0 * I_DIM + i];
    float g0 = gate[(size_t)t0 * (2 * I_DIM) + i];
    float d1 = delta[(size_t)(t0 + 1) * (2 * I_DIM) + i];
    float u1 = xc[(size_t)(t0 + 1) * I_DIM + i];
    float g1 = gate[(size_t)(t0 + 1) * (2 * I_DIM) + i];
    for (int t = 0; t < TSEG; t += 2) {
        float d2 = 0.f, u2 = 0.f, g2 = 0.f, d3 = 0.f, u3 = 0.f, g3 = 0.f;
        if (t + 3 < TSEG) {
            d2 = delta[(size_t)(t0 + t + 2) * (2 * I_DIM) + i];
            u2 = xc[(size_t)(t0 + t + 2) * I_DIM + i];
            g2 = gate[(size_t)(t0 + t + 2) * (2 * I_DIM) + i];
            d3 = delta[(size_t)(t0 + t + 3) * (2 * I_DIM) + i];
            u3 = xc[(size_t)(t0 + t + 3) * I_DIM + i];
            g3 = gate[(size_t)(t0 + t + 3) * (2 * I_DIM) + i];
        }
#pragma unroll
        for (int ss = 0; ss < 2; ++ss) {
            const float d = ss ? d1 : d0;
            const float u = ss ? u1 : u0;
            const float g = ss ? g1 : g0;
            const int tt = t + ss;
            const float du = d * u;
            float y = 0.f;
#pragma unroll
            for (int n = 0; n < 8; ++n) {
                const float a = __expf(d * Ai[n]);
                h[n] = fmaf(h[n], a, du * BCs[tt][half * 8 + n]);
                y = fmaf(h[n], BCs[tt][16 + half * 8 + n], y);
            }
            y += __shfl_xor(y, 1);
            if (half == 0) {
                const float sg = g / (1.f + __expf(-g));
                const float zv = (y + u * Di) * sg;
                const int row = t0 + tt;
                zPh[((size_t)(row >> 4) * (I_DIM >> 5)) * 512 + zb + (size_t)(row & 15) * 8]
                    = (_Float16)zv;
            }
        }
        d0 = d2; u0 = u2; g0 = g2; d1 = d3; u1 = u3; g1 = g3;
    }
}

// ---------------------------------------------------------------------------
extern "C" void kernel_launch(void* const* d_in, const int* in_sizes, int n_in,
                              void* d_out, int out_size, void* d_ws, size_t ws_size,
                              hipStream_t stream)
{
    const float* hs      = (const float*)d_in[0];
    const float* W_in    = (const float*)d_in[1];
    const float* conv_w  = (const float*)d_in[2];
    const float* conv_b  = (const float*)d_in[3];
    const float* W_x     = (const float*)d_in[4];
    const float* W_dt    = (const float*)d_in[5];
    const float* dt_bias = (const float*)d_in[6];
    const float* A_log   = (const float*)d_in[7];
    const float* Dp      = (const float*)d_in[8];
    const float* W_out   = (const float*)d_in[9];
    float* out = (float*)d_out;

    // workspace layout (~210 MB)
    char* p = (char*)d_ws;
    auto alloc = [&](size_t bytes) {
        char* r = p;
        p += (bytes + 255) & ~(size_t)255;
        return r;
    };
    float* proj   = (float*)alloc((size_t)LC * 2 * I_DIM * 4);   // 64 MB (also GEMM4 partials)
    float* xconv  = (float*)alloc((size_t)LC * I_DIM * 4);       // 32 MB
    float* ssm    = (float*)alloc((size_t)LC * 160 * 4);
    float* xtail  = (float*)alloc((size_t)2 * 3 * I_DIM * 4);
    float* hstate = (float*)alloc((size_t)IN_DIM * 4);
    _Float16* WinPh  = (_Float16*)alloc((size_t)2 * I_DIM * H_DIM * 2);  // 32 MB
    _Float16* WoutPh = (_Float16*)alloc((size_t)H_DIM * I_DIM * 2);      // 16 MB
    _Float16* WdtPh  = (_Float16*)alloc((size_t)I_DIM * R_DIM * 2);
    _Float16* WdtPl  = (_Float16*)alloc((size_t)I_DIM * R_DIM * 2);
    _Float16* WxPh   = (_Float16*)alloc((size_t)256 * I_DIM * 2);
    _Float16* WxPl   = (_Float16*)alloc((size_t)256 * I_DIM * 2);
    _Float16* hsPh   = (_Float16*)alloc((size_t)L_DIM * H_DIM * 2);  // 33.5 MB (full L)
    _Float16* zPh    = (_Float16*)alloc((size_t)LC * I_DIM * 2);     // 16 MB

    const dim3 blk(256);
    const int NSSM = R_DIM + 2 * N_DIM;  // 160

    // ---- pack weights + full hs into panel format (once per launch) ----
    pack_bp<<<dim3(2 * I_DIM / 32, H_DIM / 32), dim3(128), 0, stream>>>(
        W_in, WinPh, nullptr, H_DIM, 2 * I_DIM);
    pack_bp<<<dim3(H_DIM / 32, I_DIM / 32), dim3(128), 0, stream>>>(
        W_out, WoutPh, nullptr, I_DIM, H_DIM);
    pack_bp<<<dim3(I_DIM / 32, R_DIM / 32), dim3(128), 0, stream>>>(
        W_dt, WdtPh, WdtPl, R_DIM, I_DIM);
    pack_bp<<<dim3(NSSM / 32, I_DIM / 32), dim3(128), 0, stream>>>(
        W_x, WxPh, WxPl, I_DIM, NSSM);
    pack_ap<<<dim3(L_DIM / 16, H_DIM / 128), blk, 0, stream>>>(
        hs, H_DIM, hsPh, H_DIM);

    for (int c = 0; c < NCHUNK; ++c) {
        const int t0 = c * LC;
        const int first = (c == 0) ? 1 : 0;
        float* out_c = out + (size_t)t0 * H_DIM;
        float* aprod = out_c;                 // scan scratch in out region
        float* hend  = out_c + (size_t)SEG * IN_DIM;
        float* xtA = xtail + (size_t)(c & 1) * 3 * I_DIM;
        float* xtB = xtail + (size_t)((c & 1) ^ 1) * 3 * I_DIM;
        const _Float16* hsPh_c = hsPh + (size_t)(t0 >> 4) * (H_DIM >> 5) * 512;

        // 1) proj = hs_c @ W_in  (256x256, 3-buf counted-vmcnt) -> 256 blocks
        gemm_p256<<<dim3(256, 1), dim3(512), 0, stream>>>(
            hsPh_c, WinPh, proj, 2 * I_DIM, H_DIM, LC / 256, H_DIM, 0);

        // 2) xconv = silu(dwconv(x_pre) + b); zeroes ssm; saves tail
        conv_silu_kernel<<<dim3(1024), blk, 0, stream>>>(
            proj, xtA, xtB, conv_w, conv_b, xconv, ssm, first);

        // 3) ssm = xconv @ W_x  (full split, split-K x8, atomics; ssm L2-small)
        gemm_p<0, 0, 1, 1, true><<<dim3(32, 8), blk, 0, stream>>>(
            xconv, I_DIM, nullptr, WxPh, WxPl, ssm, NSSM,
            I_DIM, NSSM, LC / 128, I_DIM / 8, nullptr);

        // 4) delta = softplus(ssm[:, :R] @ W_dt + dt_bias) -> proj[:, :I]
        gemm_p<1, 0, 1, 1, false><<<dim3(512, 1), blk, 0, stream>>>(
            ssm, NSSM, nullptr, WdtPh, WdtPl, proj, 2 * I_DIM,
            R_DIM, 0, LC / 128, R_DIM, dt_bias);

        // 5) segment-parallel scan; z -> zPh panels
        scan_part1<<<dim3(I_DIM / 128, SEG), blk, 0, stream>>>(
            proj, ssm, xconv, A_log, aprod, hend);
        scan_part2<<<dim3(IN_DIM / 256), blk, 0, stream>>>(
            aprod, hend, hstate, first);
        scan_part3<<<dim3(I_DIM / 128, SEG), blk, 0, stream>>>(
            proj, proj + I_DIM, ssm, xconv, zPh, A_log, Dp, hend);

        // 6) GEMM4 partials: 4 k-slices of z @ W_out into proj (plain stores)
        gemm_p256<<<dim3(64, 4), dim3(512), 0, stream>>>(
            zPh, WoutPh, proj, H_DIM, I_DIM, H_DIM / 256,
            I_DIM / 4, (size_t)LC * H_DIM);

        // 7) out_c = P0+P1+P2+P3
        reduce4_kernel<<<dim3(LC * H_DIM / 1024), blk, 0, stream>>>(proj, out_c);
    }
}

// Round 14
// 1070.542 us; speedup vs baseline: 4.7573x; 1.0437x over previous
//
#include <hip/hip_runtime.h>
#include <cmath>
#include <stdint.h>

#define H_DIM 2048
#define I_DIM 4096
#define N_DIM 16
#define R_DIM 128
#define K_CONV 4
#define L_DIM 8192
#define LC 2048                 // chunk length
#define NCHUNK (L_DIM / LC)
#define SEG 32                  // scan segments per chunk
#define TSEG (LC / SEG)         // 64 steps per segment
#define IN_DIM (I_DIM * N_DIM)  // 65536 recurrences

typedef _Float16 f16x8 __attribute__((ext_vector_type(8)));
typedef _Float16 f16x4v __attribute__((ext_vector_type(4)));
typedef float    f32x4 __attribute__((ext_vector_type(4)));

// direct HBM->LDS, 16B per lane; LDS base must be wave-uniform (HW adds lane*16)
__device__ __forceinline__ void gl_lds(const _Float16* g, _Float16* lbase, int lane) {
#if __has_builtin(__builtin_amdgcn_global_load_lds)
    __builtin_amdgcn_global_load_lds(
        (const __attribute__((address_space(1))) void*)g,
        (__attribute__((address_space(3))) void*)lbase, 16, 0, 0);
#else
    *(f16x8*)&lbase[lane * 8] = *(const f16x8*)g;
#endif
}

// ---------------------------------------------------------------------------
// 256x256 panel GEMM (GEMM1 & GEMM4): A hi panels x B hi panels.
// 512 threads = 8 waves (4m x 2n), wave tile 64x128. BK=32.
// 3-buffer counted-vmcnt pipeline (96KB LDS). Split-K via blockIdx.y*kchunk,
// partial output at C + y*partStride (plain stores). OUTF16: store f16.
// ---------------------------------------------------------------------------
template <int OUTF16>
__global__ __launch_bounds__(512, 1) void gemm_p256(
    const _Float16* __restrict__ Aph,
    const _Float16* __restrict__ Bph,
    void* __restrict__ Cv, int ldc, int Kd, int gm,
    int kchunk, size_t partStride)
{
    __shared__ __align__(16) _Float16 Sh[3][2][8192];  // [buf][Ah,Bh][16 panels]

    const int tid = threadIdx.x;
    int bid = blockIdx.x;
    const int q = gridDim.x >> 3;
    bid = (bid & 7) * q + (bid >> 3);    // bijective XCD swizzle (grid % 8 == 0)
    const int m0 = (bid % gm) * 256;
    const int n0 = (bid / gm) * 256;

    const int kbeg = blockIdx.y * kchunk;

    const int w = tid >> 6, l = tid & 63;
    const int wm = w & 3, wn = w >> 2;   // 4m x 2n waves
    const int lr = l & 15, lg = l >> 4;

    const int KP = Kd >> 5;
    const int np0 = n0 >> 4, mp0 = m0 >> 4;
    const int st0 = w;

    f32x4 acc[4][8];
#pragma unroll
    for (int a = 0; a < 4; ++a)
#pragma unroll
        for (int b = 0; b < 8; ++b) acc[a][b] = (f32x4){0.f, 0.f, 0.f, 0.f};

    auto stage = [&](int k0, int p) {    // 4 gl_lds / thread
        const int kp = k0 >> 5;
#pragma unroll
        for (int s = 0; s < 2; ++s) {
            const int st = st0 + s * 8;
            gl_lds(Aph + ((size_t)(mp0 + st) * KP + kp) * 512 + (size_t)l * 8,
                   &Sh[p][0][st * 512], l);
            gl_lds(Bph + ((size_t)(np0 + st) * KP + kp) * 512 + (size_t)l * 8,
                   &Sh[p][1][st * 512], l);
        }
    };
    auto domfma = [&](int b) {
        f16x8 fah[4];
#pragma unroll
        for (int t = 0; t < 4; ++t)
            fah[t] = *(const f16x8*)&Sh[b][0][(wm * 4 + t) * 512 + l * 8];
        __builtin_amdgcn_s_setprio(1);
#pragma unroll
        for (int nh = 0; nh < 2; ++nh) {
            f16x8 fbh[4];
#pragma unroll
            for (int t = 0; t < 4; ++t)
                fbh[t] = *(const f16x8*)&Sh[b][1][(wn * 8 + nh * 4 + t) * 512 + l * 8];
#pragma unroll
            for (int mt = 0; mt < 4; ++mt)
#pragma unroll
                for (int nt = 0; nt < 4; ++nt)
                    acc[mt][nh * 4 + nt] = __builtin_amdgcn_mfma_f32_16x16x32_f16(
                        fah[mt], fbh[nt], acc[mt][nh * 4 + nt], 0, 0, 0);
        }
        __builtin_amdgcn_s_setprio(0);
    };

    const int KT = kchunk >> 5;          // >= 2 required
    stage(kbeg, 0);
    stage(kbeg + 32, 1);
    for (int k = 0; k + 2 < KT; ++k) {
        stage(kbeg + (k + 2) * 32, (k + 2) % 3);         // 12 in flight
        asm volatile("s_waitcnt vmcnt(8)" ::: "memory"); // own stage-k landed
        __builtin_amdgcn_s_barrier();
        __builtin_amdgcn_sched_barrier(0);
        domfma(k % 3);
        __builtin_amdgcn_s_barrier();                    // reads done before restage
    }
    asm volatile("s_waitcnt vmcnt(4)" ::: "memory");
    __builtin_amdgcn_s_barrier();
    __builtin_amdgcn_sched_barrier(0);
    domfma((KT - 2) % 3);
    __builtin_amdgcn_s_barrier();
    asm volatile("s_waitcnt vmcnt(0)" ::: "memory");
    __builtin_amdgcn_s_barrier();
    __builtin_amdgcn_sched_barrier(0);
    domfma((KT - 1) % 3);

#pragma unroll
    for (int mt = 0; mt < 4; ++mt) {
        const int row = m0 + wm * 64 + mt * 16 + lg * 4;
#pragma unroll
        for (int nt = 0; nt < 8; ++nt) {
            const int col = n0 + wn * 128 + nt * 16 + lr;
#pragma unroll
            for (int j = 0; j < 4; ++j) {
                if (OUTF16) {
                    _Float16* C = (_Float16*)Cv + (size_t)blockIdx.y * partStride;
                    C[(size_t)(row + j) * ldc + col] = (_Float16)acc[mt][nt][j];
                } else {
                    float* C = (float*)Cv + (size_t)blockIdx.y * partStride;
                    C[(size_t)(row + j) * ldc + col] = acc[mt][nt][j];
                }
            }
        }
    }
}

// ---------------------------------------------------------------------------
// out = P0+P1+P2+P3 (f16 partials, f32 out), 8 elems / thread.
// ---------------------------------------------------------------------------
__global__ __launch_bounds__(256) void reduce4_f16_kernel(
    const _Float16* __restrict__ P, float* __restrict__ out)
{
    const size_t idx = ((size_t)blockIdx.x * 256 + threadIdx.x) * 8;
    const size_t S = (size_t)LC * H_DIM;
    const f16x8 a = *(const f16x8*)(P + idx);
    const f16x8 b = *(const f16x8*)(P + S + idx);
    const f16x8 c = *(const f16x8*)(P + 2 * S + idx);
    const f16x8 d = *(const f16x8*)(P + 3 * S + idx);
    float r[8];
#pragma unroll
    for (int j = 0; j < 8; ++j)
        r[j] = ((float)a[j] + (float)b[j]) + ((float)c[j] + (float)d[j]);
    *(float4*)(out + idx)     = *(float4*)&r[0];
    *(float4*)(out + idx + 4) = *(float4*)&r[4];
}

// ---------------------------------------------------------------------------
// 128x128 panel GEMM (GEMM2/3), 2-buffer schedule. AK=0 fp32 reg-split.
// ASPLIT/BSPLIT lo-correction; OUTF16: store f16 (non-atomic only).
// ---------------------------------------------------------------------------
template <int EPI, int AK, int ASPLIT, int BSPLIT, bool ATOMIC, int OUTF16>
__global__ __launch_bounds__(256, ASPLIT ? 2 : (BSPLIT ? 3 : 4)) void gemm_p(
    const void* __restrict__ Av, int lda,
    const _Float16* __restrict__ Aph,
    const _Float16* __restrict__ Bph, const _Float16* __restrict__ Bpl,
    void* __restrict__ Cv, int ldc,
    int Kd, int Ncap, int gm, int kchunk,
    const float* __restrict__ bias)
{
    constexpr int S_AH = 0;
    constexpr int S_AL = ASPLIT ? 1 : 0;
    constexpr int S_BH = ASPLIT ? 2 : 1;
    constexpr int S_BL = S_BH + 1;
    constexpr int NSLOT = S_BH + 1 + BSPLIT;
    __shared__ __align__(16) _Float16 Sh[2][NSLOT][4096];

    const int tid = threadIdx.x;
    int bid = blockIdx.x;
    const int q = gridDim.x >> 3;
    bid = (bid & 7) * q + (bid >> 3);
    const int m0 = (bid % gm) * 128;
    const int n0 = (bid / gm) * 128;

    const int kbeg = blockIdx.y * kchunk;
    const int kend = (kbeg + kchunk < Kd) ? (kbeg + kchunk) : Kd;

    const int w = tid >> 6, l = tid & 63;
    const int wm = w & 1, wn = w >> 1;
    const int lr = l & 15, lg = l >> 4;

    const int ar = tid >> 1, ah = tid & 1;
    const int aw0 = (ar >> 4) * 512 + (((ah * 2) * 16 + (ar & 15)) * 8);
    const int aw1 = aw0 + 128;

    const int KP = Kd >> 5;
    const int np0 = n0 >> 4;
    const int mp0 = m0 >> 4;

    f32x4 acc[4][4];
#pragma unroll
    for (int a = 0; a < 4; ++a)
#pragma unroll
        for (int b = 0; b < 4; ++b) acc[a][b] = (f32x4){0.f, 0.f, 0.f, 0.f};

    float xf[16];
    f16x8 sah[2], sal[2];

    auto issueA = [&](int k0) {
        if (AK == 0) {
            const float* Ap = (const float*)Av + (size_t)(m0 + ar) * lda + k0 + ah * 16;
            *(float4*)&xf[0]  = *(const float4*)(Ap + 0);
            *(float4*)&xf[4]  = *(const float4*)(Ap + 4);
            *(float4*)&xf[8]  = *(const float4*)(Ap + 8);
            *(float4*)&xf[12] = *(const float4*)(Ap + 12);
        }
    };
    auto cvtA = [&]() {
        if (AK == 0) {
#pragma unroll
            for (int c2 = 0; c2 < 2; ++c2)
#pragma unroll
                for (int j = 0; j < 8; ++j) {
                    const float xv = xf[c2 * 8 + j];
                    const _Float16 h = (_Float16)xv;
                    sah[c2][j] = h;
                    if (ASPLIT) sal[c2][j] = (_Float16)(xv - (float)h);
                }
        }
    };
    auto writeA = [&](int p) {
        *(f16x8*)&Sh[p][S_AH][aw0] = sah[0];
        *(f16x8*)&Sh[p][S_AH][aw1] = sah[1];
        if (ASPLIT) {
            *(f16x8*)&Sh[p][S_AL][aw0] = sal[0];
            *(f16x8*)&Sh[p][S_AL][aw1] = sal[1];
        }
    };
    auto stageGL = [&](int k0, int p) {
        const int kp = k0 >> 5;
        if (AK == 2) {
#pragma unroll
            for (int s = 0; s < 2; ++s) {
                const int st = w + s * 4;
                const size_t ga = ((size_t)(mp0 + st) * KP + kp) * 512 + (size_t)l * 8;
                gl_lds(Aph + ga, &Sh[p][S_AH][st * 512], l);
            }
        }
#pragma unroll
        for (int qq = 0; qq < 2; ++qq) {
            const int st = 2 * w + qq;
            const size_t go = ((size_t)(np0 + st) * KP + kp) * 512 + (size_t)l * 8;
            gl_lds(Bph + go, &Sh[p][S_BH][st * 512], l);
            if (BSPLIT) gl_lds(Bpl + go, &Sh[p][S_BL][st * 512], l);
        }
    };
    auto domfma = [&](int b) {
        f16x8 fah[4], fal[4], fbh[4], fbl[4];
#pragma unroll
        for (int t = 0; t < 4; ++t) {
            fah[t] = *(const f16x8*)&Sh[b][S_AH][(wm * 4 + t) * 512 + l * 8];
            if (ASPLIT) fal[t] = *(const f16x8*)&Sh[b][S_AL][(wm * 4 + t) * 512 + l * 8];
            fbh[t] = *(const f16x8*)&Sh[b][S_BH][(wn * 4 + t) * 512 + l * 8];
            if (BSPLIT) fbl[t] = *(const f16x8*)&Sh[b][S_BL][(wn * 4 + t) * 512 + l * 8];
        }
        __builtin_amdgcn_s_setprio(1);
#pragma unroll
        for (int mt = 0; mt < 4; ++mt)
#pragma unroll
            for (int nt = 0; nt < 4; ++nt) {
                f32x4& a = acc[mt][nt];
                a = __builtin_amdgcn_mfma_f32_16x16x32_f16(fah[mt], fbh[nt], a, 0, 0, 0);
                if (BSPLIT)
                    a = __builtin_amdgcn_mfma_f32_16x16x32_f16(fah[mt], fbl[nt], a, 0, 0, 0);
                if (ASPLIT)
                    a = __builtin_amdgcn_mfma_f32_16x16x32_f16(fal[mt], fbh[nt], a, 0, 0, 0);
            }
        __builtin_amdgcn_s_setprio(0);
    };

    if (AK != 2) { issueA(kbeg); cvtA(); writeA(0); }
    stageGL(kbeg, 0);
    __syncthreads();
    int p = 0;
    for (int k0 = kbeg; k0 < kend; k0 += 32) {
        const bool more = (k0 + 32 < kend);
        if (more) {
            if (AK != 2) issueA(k0 + 32);
            stageGL(k0 + 32, p ^ 1);
        }
        domfma(p);
        if (more && AK != 2) { cvtA(); writeA(p ^ 1); }
        __syncthreads();
        p ^= 1;
    }

#pragma unroll
    for (int mt = 0; mt < 4; ++mt) {
        const int row = m0 + wm * 64 + mt * 16 + lg * 4;
#pragma unroll
        for (int nt = 0; nt < 4; ++nt) {
            const int col = n0 + wn * 64 + nt * 16 + lr;
            if (Ncap == 0 || col < Ncap) {
#pragma unroll
                for (int j = 0; j < 4; ++j) {
                    float v = acc[mt][nt][j];
                    if (EPI == 1) {
                        v += bias[col];
                        v = (v > 20.f) ? v : __logf(1.f + __expf(v));
                    }
                    const size_t off = (size_t)(row + j) * ldc + col;
                    if (ATOMIC)      atomicAdd(&((float*)Cv)[off], v);
                    else if (OUTF16) ((_Float16*)Cv)[off] = (_Float16)v;
                    else             ((float*)Cv)[off] = v;
                }
            }
        }
    }
}

// ---------------------------------------------------------------------------
// Pack W [Kd][Nd] fp32 -> f16 B-panels [Nd/16][Kd/32][512]; lo only if Pl.
// ---------------------------------------------------------------------------
__global__ __launch_bounds__(128) void pack_bp(
    const float* __restrict__ W, _Float16* __restrict__ Ph,
    _Float16* __restrict__ Pl, int Kd, int Nd)
{
    __shared__ float t[32][33];
    const int tid = threadIdx.x;
    const int n0 = blockIdx.x * 32, k0 = blockIdx.y * 32;
#pragma unroll
    for (int h = 0; h < 2; ++h) {
        const int qd = tid + h * 128;
        const int kk = qd >> 3, qq = qd & 7;
        *(float4*)&t[kk][qq * 4] = *(const float4*)(W + (size_t)(k0 + kk) * Nd + n0 + qq * 4);
    }
    __syncthreads();
    const int c = tid >> 5, nn = tid & 31;
    const int np = (n0 + nn) >> 4;
    const int r  = nn & 15;
    const int kp = k0 >> 5;
    const size_t base = ((size_t)np * (Kd >> 5) + kp) * 512 + (c * 16 + r) * 8;
    f16x8 vh, vl;
#pragma unroll
    for (int j = 0; j < 8; ++j) {
        const float v = t[c * 8 + j][nn];
        const _Float16 h = (_Float16)v;
        vh[j] = h;
        vl[j] = (_Float16)(v - (float)h);
    }
    *(f16x8*)&Ph[base] = vh;
    if (Pl) *(f16x8*)&Pl[base] = vl;
}

// ---------------------------------------------------------------------------
// Pack A fp32 [M][K] row-major -> hi f16 A-panels [M/16][K/32][512].
// ---------------------------------------------------------------------------
__global__ __launch_bounds__(256) void pack_ap(
    const float* __restrict__ A, int lda,
    _Float16* __restrict__ Ph, int Kd)
{
    const int tid = threadIdx.x;
    const int mp = blockIdx.x;
    const int r = tid >> 4, c8 = tid & 15;
    const int k0 = blockIdx.y * 128 + c8 * 8;
    const float* Ap = A + (size_t)(mp * 16 + r) * lda + k0;
    const float4 v0 = *(const float4*)Ap;
    const float4 v1 = *(const float4*)(Ap + 4);
    const float x[8] = {v0.x, v0.y, v0.z, v0.w, v1.x, v1.y, v1.z, v1.w};
    f16x8 vh;
#pragma unroll
    for (int j = 0; j < 8; ++j) vh[j] = (_Float16)x[j];
    const int kp = k0 >> 5;
    const int c  = (k0 >> 3) & 3;
    const size_t base = ((size_t)mp * (Kd >> 5) + kp) * 512 + (c * 16 + r) * 8;
    *(f16x8*)&Ph[base] = vh;
}

// ---------------------------------------------------------------------------
// Causal depthwise conv (K=4) + bias + silu (4ch x 8t / thread); zeroes ssm.
// proj (x-half) is f16, ld 2I. Tail saved f32.
// ---------------------------------------------------------------------------
__global__ __launch_bounds__(256) void conv_silu_kernel(
    const _Float16* __restrict__ proj,
    const float* __restrict__ xtail_in,
    float* __restrict__ xtail_out,
    const float* __restrict__ w,
    const float* __restrict__ b,
    float* __restrict__ xconv,
    float* __restrict__ ssm,
    int first)
{
    const int gid = blockIdx.x * 256 + threadIdx.x;
    if (gid < (LC * 160) / 4)
        *(float4*)(ssm + (size_t)gid * 4) = make_float4(0.f, 0.f, 0.f, 0.f);

    const int i4 = gid & (I_DIM / 4 - 1);
    const int t8 = gid >> 10;
    const int i = i4 * 4;
    const int tt0 = t8 * 8;

    const float4 w0 = *(const float4*)(w + (size_t)(i + 0) * 4);
    const float4 w1 = *(const float4*)(w + (size_t)(i + 1) * 4);
    const float4 w2 = *(const float4*)(w + (size_t)(i + 2) * 4);
    const float4 w3 = *(const float4*)(w + (size_t)(i + 3) * 4);
    const float4 bb = *(const float4*)(b + i);

    auto ldrow = [&](int row) -> float4 {
        const f16x4v v = *(const f16x4v*)(proj + (size_t)row * (2 * I_DIM) + i);
        return make_float4((float)v[0], (float)v[1], (float)v[2], (float)v[3]);
    };

    float4 r[11];
    if (tt0 >= 3) {
#pragma unroll
        for (int s = 0; s < 11; ++s) r[s] = ldrow(tt0 - 3 + s);
    } else {
#pragma unroll
        for (int s = 0; s < 3; ++s)
            r[s] = first ? make_float4(0.f, 0.f, 0.f, 0.f)
                         : *(const float4*)(xtail_in + (size_t)s * I_DIM + i);
#pragma unroll
        for (int s = 3; s < 11; ++s) r[s] = ldrow(tt0 - 3 + s);
    }

#pragma unroll
    for (int s = 0; s < 8; ++s) {
        float4 y = bb;
        y.x = fmaf(w0.x, r[s].x, y.x); y.x = fmaf(w0.y, r[s+1].x, y.x);
        y.x = fmaf(w0.z, r[s+2].x, y.x); y.x = fmaf(w0.w, r[s+3].x, y.x);
        y.y = fmaf(w1.x, r[s].y, y.y); y.y = fmaf(w1.y, r[s+1].y, y.y);
        y.y = fmaf(w1.z, r[s+2].y, y.y); y.y = fmaf(w1.w, r[s+3].y, y.y);
        y.z = fmaf(w2.x, r[s].z, y.z); y.z = fmaf(w2.y, r[s+1].z, y.z);
        y.z = fmaf(w2.z, r[s+2].z, y.z); y.z = fmaf(w2.w, r[s+3].z, y.z);
        y.w = fmaf(w3.x, r[s].w, y.w); y.w = fmaf(w3.y, r[s+1].w, y.w);
        y.w = fmaf(w3.z, r[s+2].w, y.w); y.w = fmaf(w3.w, r[s+3].w, y.w);
        y.x = y.x / (1.f + __expf(-y.x));
        y.y = y.y / (1.f + __expf(-y.y));
        y.z = y.z / (1.f + __expf(-y.z));
        y.w = y.w / (1.f + __expf(-y.w));
        *(float4*)(xconv + (size_t)(tt0 + s) * I_DIM + i) = y;
    }

    if (tt0 == LC - 8) {
#pragma unroll
        for (int qq = 0; qq < 3; ++qq)
            *(float4*)(xtail_out + (size_t)qq * I_DIM + i) = r[8 + qq];
    }
}

// ---------------------------------------------------------------------------
// Segment-parallel scan. delta/gate now f16 (ld 2I).
// ---------------------------------------------------------------------------
__global__ __launch_bounds__(256) void scan_part1(
    const _Float16* __restrict__ delta,
    const float* __restrict__ ssm,
    const float* __restrict__ xc,
    const float* __restrict__ A_log,
    float* __restrict__ aprod,
    float* __restrict__ hend)
{
    __shared__ float Bs[TSEG][16];
    const int tid = threadIdx.x;
    const int i = blockIdx.x * 128 + (tid >> 1);
    const int half = tid & 1;
    const int seg = blockIdx.y;
    const int t0 = seg * TSEG;

    {
        const int tt = tid >> 2, c = (tid & 3) * 4;
        *(float4*)&Bs[tt][c] = *(const float4*)&ssm[(size_t)(t0 + tt) * 160 + 128 + c];
    }
    __syncthreads();

    float Ai[8], h[8], ap[8];
    {
        const float4 a0 = *(const float4*)&A_log[(size_t)i * 16 + half * 8];
        const float4 a1 = *(const float4*)&A_log[(size_t)i * 16 + half * 8 + 4];
        const float al[8] = {a0.x, a0.y, a0.z, a0.w, a1.x, a1.y, a1.z, a1.w};
#pragma unroll
        for (int n = 0; n < 8; ++n) { Ai[n] = -expf(al[n]); h[n] = 0.f; ap[n] = 1.f; }
    }

    float d0 = (float)delta[(size_t)t0 * (2 * I_DIM) + i];
    float u0 = xc[(size_t)t0 * I_DIM + i];
    float d1 = (float)delta[(size_t)(t0 + 1) * (2 * I_DIM) + i];
    float u1 = xc[(size_t)(t0 + 1) * I_DIM + i];
    for (int t = 0; t < TSEG; t += 2) {
        float d2 = 0.f, u2 = 0.f, d3 = 0.f, u3 = 0.f;
        if (t + 3 < TSEG) {
            d2 = (float)delta[(size_t)(t0 + t + 2) * (2 * I_DIM) + i];
            u2 = xc[(size_t)(t0 + t + 2) * I_DIM + i];
            d3 = (float)delta[(size_t)(t0 + t + 3) * (2 * I_DIM) + i];
            u3 = xc[(size_t)(t0 + t + 3) * I_DIM + i];
        }
        {
            const float du = d0 * u0;
#pragma unroll
            for (int n = 0; n < 8; ++n) {
                const float a = __expf(d0 * Ai[n]);
                h[n] = fmaf(h[n], a, du * Bs[t][half * 8 + n]);
                ap[n] *= a;
            }
        }
        {
            const float du = d1 * u1;
#pragma unroll
            for (int n = 0; n < 8; ++n) {
                const float a = __expf(d1 * Ai[n]);
                h[n] = fmaf(h[n], a, du * Bs[t + 1][half * 8 + n]);
                ap[n] *= a;
            }
        }
        d0 = d2; u0 = u2; d1 = d3; u1 = u3;
    }

    const size_t base = (size_t)seg * IN_DIM + (size_t)i * 16 + half * 8;
#pragma unroll
    for (int qq = 0; qq < 2; ++qq) {
        float4 va = {ap[qq * 4 + 0], ap[qq * 4 + 1], ap[qq * 4 + 2], ap[qq * 4 + 3]};
        float4 vh = {h[qq * 4 + 0], h[qq * 4 + 1], h[qq * 4 + 2], h[qq * 4 + 3]};
        *(float4*)&aprod[base + qq * 4] = va;
        *(float4*)&hend[base + qq * 4]  = vh;
    }
}

__global__ __launch_bounds__(256) void scan_part2(
    const float* __restrict__ aprod,
    float* __restrict__ hend,
    float* __restrict__ hstate,
    int first)
{
    const int gid = blockIdx.x * 256 + threadIdx.x;
    float h = first ? 0.f : hstate[gid];
    for (int s = 0; s < SEG; ++s) {
        const int idx = s * IN_DIM + gid;
        const float ap = aprod[idx];
        const float he = hend[idx];
        hend[idx] = h;
        h = fmaf(ap, h, he);
    }
    hstate[gid] = h;
}

// Phase 3: re-run segment from h_start; z (f16) written in GEMM4 A-panel layout.
__global__ __launch_bounds__(256) void scan_part3(
    const _Float16* __restrict__ delta,
    const _Float16* __restrict__ gate,
    const float* __restrict__ ssm,
    const float* __restrict__ xc,
    _Float16* __restrict__ zPh,
    const float* __restrict__ A_log,
    const float* __restrict__ Dp,
    const float* __restrict__ hstart)  // [SEG][I][N]
{
    __shared__ float BCs[TSEG][32];
    const int tid = threadIdx.x;
    const int i = blockIdx.x * 128 + (tid >> 1);
    const int half = tid & 1;
    const int seg = blockIdx.y;
    const int t0 = seg * TSEG;

    {
        const int tt = tid >> 2, c = (tid & 3) * 8;
        *(float4*)&BCs[tt][c]     = *(const float4*)&ssm[(size_t)(t0 + tt) * 160 + 128 + c];
        *(float4*)&BCs[tt][c + 4] = *(const float4*)&ssm[(size_t)(t0 + tt) * 160 + 132 + c];
    }
    __syncthreads();

    float Ai[8], h[8];
    {
        const float4 a0 = *(const float4*)&A_log[(size_t)i * 16 + half * 8];
        const float4 a1 = *(const float4*)&A_log[(size_t)i * 16 + half * 8 + 4];
        const float al[8] = {a0.x, a0.y, a0.z, a0.w, a1.x, a1.y, a1.z, a1.w};
#pragma unroll
        for (int n = 0; n < 8; ++n) Ai[n] = -expf(al[n]);
        const size_t base = (size_t)seg * IN_DIM + (size_t)i * 16 + half * 8;
        const float4 h0 = *(const float4*)&hstart[base];
        const float4 h1 = *(const float4*)&hstart[base + 4];
        h[0] = h0.x; h[1] = h0.y; h[2] = h0.z; h[3] = h0.w;
        h[4] = h1.x; h[5] = h1.y; h[6] = h1.z; h[7] = h1.w;
    }
    const float Di = Dp[i];

    const int kp = i >> 5, cc = (i >> 3) & 3, jj = i & 7;
    const size_t zb = (size_t)kp * 512 + (size_t)cc * 128 + jj;

    float d0 = (float)delta[(size_t)t0 * (2 * I_DIM) + i];
    float u0 = xc[(size_t)t0 * I_DIM + i];
    float g0 = (float)gate[(size_t)t0 * (2 * I_DIM) + i];
    float d1 = (float)delta[(size_t)(t0 + 1) * (2 * I_DIM) + i];
    float u1 = xc[(size_t)(t0 + 1) * I_DIM + i];
    float g1 = (float)gate[(size_t)(t0 + 1) * (2 * I_DIM) + i];
    for (int t = 0; t < TSEG; t += 2) {
        float d2 = 0.f, u2 = 0.f, g2 = 0.f, d3 = 0.f, u3 = 0.f, g3 = 0.f;
        if (t + 3 < TSEG) {
            d2 = (float)delta[(size_t)(t0 + t + 2) * (2 * I_DIM) + i];
            u2 = xc[(size_t)(t0 + t + 2) * I_DIM + i];
            g2 = (float)gate[(size_t)(t0 + t + 2) * (2 * I_DIM) + i];
            d3 = (float)delta[(size_t)(t0 + t + 3) * (2 * I_DIM) + i];
            u3 = xc[(size_t)(t0 + t + 3) * I_DIM + i];
            g3 = (float)gate[(size_t)(t0 + t + 3) * (2 * I_DIM) + i];
        }
#pragma unroll
        for (int ss = 0; ss < 2; ++ss) {
            const float d = ss ? d1 : d0;
            const float u = ss ? u1 : u0;
            const float g = ss ? g1 : g0;
            const int tt = t + ss;
            const float du = d * u;
            float y = 0.f;
#pragma unroll
            for (int n = 0; n < 8; ++n) {
                const float a = __expf(d * Ai[n]);
                h[n] = fmaf(h[n], a, du * BCs[tt][half * 8 + n]);
                y = fmaf(h[n], BCs[tt][16 + half * 8 + n], y);
            }
            y += __shfl_xor(y, 1);
            if (half == 0) {
                const float sg = g / (1.f + __expf(-g));
                const float zv = (y + u * Di) * sg;
                const int row = t0 + tt;
                zPh[((size_t)(row >> 4) * (I_DIM >> 5)) * 512 + zb + (size_t)(row & 15) * 8]
                    = (_Float16)zv;
            }
        }
        d0 = d2; u0 = u2; g0 = g2; d1 = d3; u1 = u3; g1 = g3;
    }
}

// ---------------------------------------------------------------------------
extern "C" void kernel_launch(void* const* d_in, const int* in_sizes, int n_in,
                              void* d_out, int out_size, void* d_ws, size_t ws_size,
                              hipStream_t stream)
{
    const float* hs      = (const float*)d_in[0];
    const float* W_in    = (const float*)d_in[1];
    const float* conv_w  = (const float*)d_in[2];
    const float* conv_b  = (const float*)d_in[3];
    const float* W_x     = (const float*)d_in[4];
    const float* W_dt    = (const float*)d_in[5];
    const float* dt_bias = (const float*)d_in[6];
    const float* A_log   = (const float*)d_in[7];
    const float* Dp      = (const float*)d_in[8];
    const float* W_out   = (const float*)d_in[9];
    float* out = (float*)d_out;

    // workspace layout (~180 MB)
    char* p = (char*)d_ws;
    auto alloc = [&](size_t bytes) {
        char* r = p;
        p += (bytes + 255) & ~(size_t)255;
        return r;
    };
    // proj region: f16 LC x 2I (32 MB) for proj data; also reused for GEMM4
    // f16 partials (4 x LC x H x 2B = 33.5 MB) -> allocate 36 MB.
    _Float16* proj16 = (_Float16*)alloc((size_t)36 * 1024 * 1024);
    float* xconv  = (float*)alloc((size_t)LC * I_DIM * 4);       // 32 MB
    float* ssm    = (float*)alloc((size_t)LC * 160 * 4);
    float* xtail  = (float*)alloc((size_t)2 * 3 * I_DIM * 4);
    float* hstate = (float*)alloc((size_t)IN_DIM * 4);
    _Float16* WinPh  = (_Float16*)alloc((size_t)2 * I_DIM * H_DIM * 2);  // 32 MB
    _Float16* WoutPh = (_Float16*)alloc((size_t)H_DIM * I_DIM * 2);      // 16 MB
    _Float16* WdtPh  = (_Float16*)alloc((size_t)I_DIM * R_DIM * 2);
    _Float16* WdtPl  = (_Float16*)alloc((size_t)I_DIM * R_DIM * 2);
    _Float16* WxPh   = (_Float16*)alloc((size_t)256 * I_DIM * 2);
    _Float16* WxPl   = (_Float16*)alloc((size_t)256 * I_DIM * 2);
    _Float16* hsPh   = (_Float16*)alloc((size_t)L_DIM * H_DIM * 2);  // 33.5 MB
    _Float16* zPh    = (_Float16*)alloc((size_t)LC * I_DIM * 2);     // 16 MB

    const dim3 blk(256);
    const int NSSM = R_DIM + 2 * N_DIM;  // 160

    // ---- pack weights + full hs into panel format (once per launch) ----
    pack_bp<<<dim3(2 * I_DIM / 32, H_DIM / 32), dim3(128), 0, stream>>>(
        W_in, WinPh, nullptr, H_DIM, 2 * I_DIM);
    pack_bp<<<dim3(H_DIM / 32, I_DIM / 32), dim3(128), 0, stream>>>(
        W_out, WoutPh, nullptr, I_DIM, H_DIM);
    pack_bp<<<dim3(I_DIM / 32, R_DIM / 32), dim3(128), 0, stream>>>(
        W_dt, WdtPh, WdtPl, R_DIM, I_DIM);
    pack_bp<<<dim3(NSSM / 32, I_DIM / 32), dim3(128), 0, stream>>>(
        W_x, WxPh, WxPl, I_DIM, NSSM);
    pack_ap<<<dim3(L_DIM / 16, H_DIM / 128), blk, 0, stream>>>(
        hs, H_DIM, hsPh, H_DIM);

    for (int c = 0; c < NCHUNK; ++c) {
        const int t0 = c * LC;
        const int first = (c == 0) ? 1 : 0;
        float* out_c = out + (size_t)t0 * H_DIM;
        float* aprod = out_c;                 // scan scratch in out region
        float* hend  = out_c + (size_t)SEG * IN_DIM;
        float* xtA = xtail + (size_t)(c & 1) * 3 * I_DIM;
        float* xtB = xtail + (size_t)((c & 1) ^ 1) * 3 * I_DIM;
        const _Float16* hsPh_c = hsPh + (size_t)(t0 >> 4) * (H_DIM >> 5) * 512;

        // 1) proj(f16) = hs_c @ W_in  (256x256, 3-buf counted-vmcnt)
        gemm_p256<1><<<dim3(256, 1), dim3(512), 0, stream>>>(
            hsPh_c, WinPh, proj16, 2 * I_DIM, H_DIM, LC / 256, H_DIM, 0);

        // 2) xconv = silu(dwconv(x_pre) + b); zeroes ssm; saves tail
        conv_silu_kernel<<<dim3(1024), blk, 0, stream>>>(
            proj16, xtA, xtB, conv_w, conv_b, xconv, ssm, first);

        // 3) ssm = xconv @ W_x  (full split, split-K x8, atomics)
        gemm_p<0, 0, 1, 1, true, 0><<<dim3(32, 8), blk, 0, stream>>>(
            xconv, I_DIM, nullptr, WxPh, WxPl, ssm, NSSM,
            I_DIM, NSSM, LC / 128, I_DIM / 8, nullptr);

        // 4) delta(f16) = softplus(ssm[:, :R] @ W_dt + dt_bias) -> proj x-half
        gemm_p<1, 0, 1, 1, false, 1><<<dim3(512, 1), blk, 0, stream>>>(
            ssm, NSSM, nullptr, WdtPh, WdtPl, proj16, 2 * I_DIM,
            R_DIM, 0, LC / 128, R_DIM, dt_bias);

        // 5) segment-parallel scan; z -> zPh panels
        scan_part1<<<dim3(I_DIM / 128, SEG), blk, 0, stream>>>(
            proj16, ssm, xconv, A_log, aprod, hend);
        scan_part2<<<dim3(IN_DIM / 256), blk, 0, stream>>>(
            aprod, hend, hstate, first);
        scan_part3<<<dim3(I_DIM / 128, SEG), blk, 0, stream>>>(
            proj16, proj16 + I_DIM, ssm, xconv, zPh, A_log, Dp, hend);

        // 6) GEMM4 partials (f16): 4 k-slices of z @ W_out into proj region
        gemm_p256<1><<<dim3(64, 4), dim3(512), 0, stream>>>(
            zPh, WoutPh, proj16, H_DIM, I_DIM, H_DIM / 256,
            I_DIM / 4, (size_t)LC * H_DIM);

        // 7) out_c = P0+P1+P2+P3
        reduce4_f16_kernel<<<dim3(LC * H_DIM / 2048), blk, 0, stream>>>(
            proj16, out_c);
    }
}